// Round 1
// baseline (1105.783 us; speedup 1.0000x reference)
//
#include <hip/hip_runtime.h>

typedef unsigned short u16;
typedef __attribute__((ext_vector_type(8))) __bf16 bf16x8;
typedef __attribute__((ext_vector_type(4))) float f32x4;

#define B_ 2
#define L_ 1024
#define DIM_ 512
#define DINNER_ 1024
#define DSTATE_ 16
#define DTRANK_ 32
#define VOCAB_ 32000

__device__ __forceinline__ u16 f2bf(float f) {
    union { float f; unsigned u; } x; x.f = f;
    unsigned r = x.u + 0x7FFFu + ((x.u >> 16) & 1u);
    return (u16)(r >> 16);
}

// ---------------- f32 -> bf16 convert ----------------
__global__ __launch_bounds__(256) void f32_to_bf16(const float* __restrict__ in,
                                                   u16* __restrict__ out, int n) {
    int i = (blockIdx.x * 256 + threadIdx.x) * 4;
    if (i + 3 < n) {
        float4 v = *(const float4*)(in + i);
        ushort4 o;
        o.x = f2bf(v.x); o.y = f2bf(v.y); o.z = f2bf(v.z); o.w = f2bf(v.w);
        *(ushort4*)(out + i) = o;
    } else {
        for (; i < n; ++i) out[i] = f2bf(in[i]);
    }
}

// ---------------- embedding gather ----------------
__global__ __launch_bounds__(256) void embed_gather(const int* __restrict__ x,
                                                    const float* __restrict__ embed,
                                                    float* __restrict__ h) {
    int wave = threadIdx.x >> 6, lane = threadIdx.x & 63;
    int row = blockIdx.x * 4 + wave;           // 0..2047
    int tok = x[row];
    const float4* s = (const float4*)(embed + (size_t)tok * DIM_);
    float4* d = (float4*)(h + (size_t)row * DIM_);
    d[lane] = s[lane];
    d[lane + 64] = s[lane + 64];
}

// ---------------- RMSNorm -> bf16 ----------------
__global__ __launch_bounds__(256) void rmsnorm_bf16(const float* __restrict__ h,
                                                    const float* __restrict__ w,
                                                    u16* __restrict__ out) {
    int wave = threadIdx.x >> 6, lane = threadIdx.x & 63;
    int row = blockIdx.x * 4 + wave;
    const float4* r4 = (const float4*)(h + (size_t)row * DIM_);
    float4 v0 = r4[lane], v1 = r4[lane + 64];
    float ss = v0.x*v0.x + v0.y*v0.y + v0.z*v0.z + v0.w*v0.w
             + v1.x*v1.x + v1.y*v1.y + v1.z*v1.z + v1.w*v1.w;
    for (int m = 1; m < 64; m <<= 1) ss += __shfl_xor(ss, m);
    float rms = rsqrtf(ss * (1.0f / DIM_) + 1e-5f);
    const float4* w4 = (const float4*)w;
    float4 w0 = w4[lane], w1 = w4[lane + 64];
    u16* o = out + (size_t)row * DIM_;
    ushort4 a, b;
    a.x = f2bf(v0.x * rms * w0.x); a.y = f2bf(v0.y * rms * w0.y);
    a.z = f2bf(v0.z * rms * w0.z); a.w = f2bf(v0.w * rms * w0.w);
    b.x = f2bf(v1.x * rms * w1.x); b.y = f2bf(v1.y * rms * w1.y);
    b.z = f2bf(v1.z * rms * w1.z); b.w = f2bf(v1.w * rms * w1.w);
    *(ushort4*)(o + lane * 4) = a;
    *(ushort4*)(o + 256 + lane * 4) = b;
}

// ---------------- LayerNorm -> bf16 ----------------
__global__ __launch_bounds__(256) void layernorm_bf16(const float* __restrict__ h,
                                                      const float* __restrict__ g,
                                                      const float* __restrict__ bta,
                                                      u16* __restrict__ out) {
    int wave = threadIdx.x >> 6, lane = threadIdx.x & 63;
    int row = blockIdx.x * 4 + wave;
    const float4* r4 = (const float4*)(h + (size_t)row * DIM_);
    float4 v0 = r4[lane], v1 = r4[lane + 64];
    float s = v0.x + v0.y + v0.z + v0.w + v1.x + v1.y + v1.z + v1.w;
    float ss = v0.x*v0.x + v0.y*v0.y + v0.z*v0.z + v0.w*v0.w
             + v1.x*v1.x + v1.y*v1.y + v1.z*v1.z + v1.w*v1.w;
    for (int m = 1; m < 64; m <<= 1) { s += __shfl_xor(s, m); ss += __shfl_xor(ss, m); }
    float mu = s * (1.0f / DIM_);
    float var = ss * (1.0f / DIM_) - mu * mu;
    float rs = rsqrtf(var + 1e-5f);
    const float4* g4 = (const float4*)g;
    const float4* b4 = (const float4*)bta;
    float4 g0 = g4[lane], g1 = g4[lane + 64];
    float4 b0 = b4[lane], b1 = b4[lane + 64];
    u16* o = out + (size_t)row * DIM_;
    ushort4 a, b;
    a.x = f2bf((v0.x - mu) * rs * g0.x + b0.x); a.y = f2bf((v0.y - mu) * rs * g0.y + b0.y);
    a.z = f2bf((v0.z - mu) * rs * g0.z + b0.z); a.w = f2bf((v0.w - mu) * rs * g0.w + b0.w);
    b.x = f2bf((v1.x - mu) * rs * g1.x + b1.x); b.y = f2bf((v1.y - mu) * rs * g1.y + b1.y);
    b.z = f2bf((v1.z - mu) * rs * g1.z + b1.z); b.w = f2bf((v1.w - mu) * rs * g1.w + b1.w);
    *(ushort4*)(o + lane * 4) = a;
    *(ushort4*)(o + 256 + lane * 4) = b;
}

// ---------------- MFMA GEMM: C(MxN) = A(MxK,bf16) * B(NxK,bf16)^T ----------------
// MODE 0: C = acc ; MODE 1: C += acc ; MODE 2: C = acc + bias[col]
#define BM 128
#define BN 128
#define BK 32
template <int MODE>
__global__ __launch_bounds__(256) void gemm_bt(const u16* __restrict__ A,
                                               const u16* __restrict__ B,
                                               float* __restrict__ C,
                                               const float* __restrict__ bias,
                                               int M, int N, int K) {
    __shared__ u16 As[BM * BK];
    __shared__ u16 Bs[BN * BK];
    const int tid = threadIdx.x;
    const int wave = tid >> 6;
    const int lane = tid & 63;
    const int m0 = blockIdx.x * BM;   // x = M tiles (consecutive blocks share B tile)
    const int n0 = blockIdx.y * BN;   // y = N tiles
    const int wr = wave >> 1, wc = wave & 1;
    f32x4 acc[4][4] = {};

    const int sub = lane >> 2;        // 0..15 : row within chunk
    const int koff = (lane & 3) * 8;  // element offset within 32-wide K slab

    for (int k0 = 0; k0 < K; k0 += BK) {
        // stage: 16 chunks of 1KB; wave w issues chunks 4w..4w+3
        #pragma unroll
        for (int i = 0; i < 4; ++i) {
            int c = wave * 4 + i;
            const u16* src;
            u16* dst;
            if (c < 8) {
                int row = c * 16 + sub;
                src = A + (size_t)(m0 + row) * K + k0 + koff;
                dst = As + c * 512;
            } else {
                int cc = c - 8;
                int row = cc * 16 + sub;
                src = B + (size_t)(n0 + row) * K + k0 + koff;
                dst = Bs + cc * 512;
            }
            __builtin_amdgcn_global_load_lds((const __attribute__((address_space(1))) void*)src,
                                             (__attribute__((address_space(3))) void*)dst,
                                             16, 0, 0);
        }
        __syncthreads();
        bf16x8 a[4], b[4];
        const int fr = lane & 15;
        const int fk = (lane >> 4) * 8;
        #pragma unroll
        for (int mi = 0; mi < 4; ++mi) {
            int row = wr * 64 + mi * 16 + fr;
            a[mi] = *(const bf16x8*)(As + row * BK + fk);
        }
        #pragma unroll
        for (int ni = 0; ni < 4; ++ni) {
            int row = wc * 64 + ni * 16 + fr;
            b[ni] = *(const bf16x8*)(Bs + row * BK + fk);
        }
        #pragma unroll
        for (int mi = 0; mi < 4; ++mi)
            #pragma unroll
            for (int ni = 0; ni < 4; ++ni)
                acc[mi][ni] = __builtin_amdgcn_mfma_f32_16x16x32_bf16(a[mi], b[ni], acc[mi][ni], 0, 0, 0);
        __syncthreads();
    }

    // epilogue: D col = lane&15, row = (lane>>4)*4 + reg
    const int cl = lane & 15;
    const int rq = (lane >> 4) * 4;
    #pragma unroll
    for (int mi = 0; mi < 4; ++mi) {
        #pragma unroll
        for (int ni = 0; ni < 4; ++ni) {
            int col = n0 + wc * 64 + ni * 16 + cl;
            #pragma unroll
            for (int rr = 0; rr < 4; ++rr) {
                int row = m0 + wr * 64 + mi * 16 + rq + rr;
                size_t idx = (size_t)row * N + col;
                float v = acc[mi][ni][rr];
                if (MODE == 1)      C[idx] += v;
                else if (MODE == 2) C[idx] = v + bias[col];
                else                C[idx] = v;
            }
        }
    }
}

// ---------------- causal depthwise conv (width 4) + silu ----------------
__global__ __launch_bounds__(256) void conv_silu(const float* __restrict__ xz,
                                                 const float* __restrict__ cw,
                                                 const float* __restrict__ cb,
                                                 float* __restrict__ xc) {
    int idx = blockIdx.x * 256 + threadIdx.x;   // over 2048*1024
    int d = idx & (DINNER_ - 1);
    int m = idx >> 10;
    int l = m & (L_ - 1);
    float acc = cb[d];
    #pragma unroll
    for (int j = 0; j < 4; ++j) {
        int ll = l - 3 + j;
        if (ll >= 0) acc = fmaf(cw[d * 4 + j], xz[(size_t)(m - 3 + j) * (2 * DINNER_) + d], acc);
    }
    float sv = acc / (1.0f + __expf(-acc));
    xc[idx] = sv;
}

// ---------------- x-projection: dbc(2048x64) = xc(2048x1024) * xproj_w(64x1024)^T ----------------
__global__ __launch_bounds__(256) void xproj_kernel(const float* __restrict__ xc,
                                                    const float* __restrict__ xw,
                                                    float* __restrict__ dbc) {
    int t = threadIdx.x;
    int n = t & 63;
    int mi = t >> 6;
    int m = blockIdx.x * 4 + mi;
    const float4* xr = (const float4*)(xc + (size_t)m * DINNER_);
    const float4* wr = (const float4*)(xw + (size_t)n * DINNER_);
    float acc = 0.f;
    #pragma unroll 4
    for (int i = 0; i < DINNER_ / 4; ++i) {
        float4 a = xr[i], b = wr[i];
        acc += a.x * b.x + a.y * b.y + a.z * b.z + a.w * b.w;
    }
    dbc[(size_t)m * 64 + n] = acc;
}

// ---------------- dt projection + softplus: delta(2048x1024) ----------------
__global__ __launch_bounds__(256) void dt_softplus(const float* __restrict__ dbc,
                                                   const float* __restrict__ dtw,
                                                   const float* __restrict__ dtb,
                                                   float* __restrict__ delta) {
    __shared__ float sdbc[8][32];
    int t = threadIdx.x;
    int d = blockIdx.x * 256 + t;     // blockIdx.x 0..3
    int m0 = blockIdx.y * 8;          // blockIdx.y 0..255
    {
        int mi = t >> 5, r = t & 31;
        sdbc[mi][r] = dbc[(size_t)(m0 + mi) * 64 + r];
    }
    float w[32];
    const float4* wr = (const float4*)(dtw + (size_t)d * 32);
    #pragma unroll
    for (int i = 0; i < 8; ++i) {
        float4 v = wr[i];
        w[i * 4] = v.x; w[i * 4 + 1] = v.y; w[i * 4 + 2] = v.z; w[i * 4 + 3] = v.w;
    }
    float bias = dtb[d];
    __syncthreads();
    #pragma unroll
    for (int mi = 0; mi < 8; ++mi) {
        float acc = bias;
        #pragma unroll
        for (int r = 0; r < 32; ++r) acc = fmaf(sdbc[mi][r], w[r], acc);
        float sp = (acc > 20.f) ? acc : log1pf(__expf(acc));
        delta[(size_t)(m0 + mi) * DINNER_ + d] = sp;
    }
}

// ---------------- SSM selective scan + gate -> ys (bf16) ----------------
// block: 128 threads = 8 d x 16 s ; grid (128 dblocks, 2 batches)
__global__ __launch_bounds__(128) void ssm_scan(const float* __restrict__ delta,
                                                const float* __restrict__ xc,
                                                const float* __restrict__ dbc,
                                                const float* __restrict__ xz,
                                                const float* __restrict__ A_log,
                                                const float* __restrict__ Dp,
                                                u16* __restrict__ ys) {
    int t = threadIdx.x;
    int s = t & 15;
    int dl = t >> 4;                 // 0..7
    int b = blockIdx.y;
    int d0 = blockIdx.x * 8;
    int d = d0 + dl;
    float Aval = -__expf(A_log[d * DSTATE_ + s]);
    float Dval = Dp[d];
    __shared__ float sd[64][8], sx[64][8], szl[64][8], sBm[64][16], sCm[64][16], sy[64][8];
    float h = 0.f;
    for (int c = 0; c < 16; ++c) {
        size_t mbase = (size_t)b * L_ + c * 64;
        #pragma unroll
        for (int i = 0; i < 4; ++i) {
            int e = t + i * 128;
            int ll = e >> 3, dd = e & 7;
            size_t m = mbase + ll;
            sd[ll][dd]  = delta[m * DINNER_ + d0 + dd];
            sx[ll][dd]  = xc[m * DINNER_ + d0 + dd];
            szl[ll][dd] = xz[m * (2 * DINNER_) + DINNER_ + d0 + dd];
        }
        #pragma unroll
        for (int i = 0; i < 8; ++i) {
            int e = t + i * 128;
            int ll = e >> 4, s_ = e & 15;
            size_t m = mbase + ll;
            sBm[ll][s_] = dbc[m * 64 + DTRANK_ + s_];
            sCm[ll][s_] = dbc[m * 64 + DTRANK_ + DSTATE_ + s_];
        }
        __syncthreads();
        for (int ll = 0; ll < 64; ++ll) {
            float dv = sd[ll][dl], xv = sx[ll][dl];
            h = __expf(dv * Aval) * h + dv * xv * sBm[ll][s];
            float p = h * sCm[ll][s];
            p += __shfl_xor(p, 1);
            p += __shfl_xor(p, 2);
            p += __shfl_xor(p, 4);
            p += __shfl_xor(p, 8);
            if (s == 0) {
                float y = p + Dval * xv;
                float zz = szl[ll][dl];
                sy[ll][dl] = y * (zz / (1.0f + __expf(-zz)));
            }
        }
        __syncthreads();
        #pragma unroll
        for (int i = 0; i < 4; ++i) {
            int e = t + i * 128;
            int ll = e >> 3, dd = e & 7;
            size_t m = mbase + ll;
            ys[m * DINNER_ + d0 + dd] = f2bf(sy[ll][dd]);
        }
        __syncthreads();
    }
}

extern "C" void kernel_launch(void* const* d_in, const int* in_sizes, int n_in,
                              void* d_out, int out_size, void* d_ws, size_t ws_size,
                              hipStream_t stream) {
    const int*   x       = (const int*)d_in[0];
    const float* embed   = (const float*)d_in[1];
    const float* rms_w   = (const float*)d_in[2];
    const float* in_w    = (const float*)d_in[3];
    const float* conv_w  = (const float*)d_in[4];
    const float* conv_b  = (const float*)d_in[5];
    const float* xproj_w = (const float*)d_in[6];
    const float* dt_w    = (const float*)d_in[7];
    const float* dt_b    = (const float*)d_in[8];
    const float* A_log   = (const float*)d_in[9];
    const float* Dp      = (const float*)d_in[10];
    const float* out_w   = (const float*)d_in[11];
    const float* ln_g    = (const float*)d_in[12];
    const float* ln_b    = (const float*)d_in[13];
    const float* head_w  = (const float*)d_in[14];
    const float* head_b  = (const float*)d_in[15];
    float* out = (float*)d_out;

    char* p = (char*)d_ws;
    auto take = [&](size_t n) { char* q = p; p += (n + 255) & ~(size_t)255; return q; };
    float* h    = (float*)take(2048ull * 512 * 4);
    u16*   r_bf = (u16*)  take(2048ull * 512 * 2);
    float* xz   = (float*)take(2048ull * 2048 * 4);
    float* xc   = (float*)take(2048ull * 1024 * 4);
    float* dbc  = (float*)take(2048ull * 64 * 4);
    float* dlt  = (float*)take(2048ull * 1024 * 4);
    u16*   ys   = (u16*)  take(2048ull * 1024 * 2);
    u16*   hn   = (u16*)  take(2048ull * 512 * 2);
    u16*   win  = (u16*)  take(2048ull * 512 * 2);
    u16*   wout = (u16*)  take(512ull * 1024 * 2);
    u16*   whd  = (u16*)  take(32000ull * 512 * 2);

    embed_gather<<<512, 256, 0, stream>>>(x, embed, h);
    f32_to_bf16<<<(VOCAB_ * DIM_ / 4 + 255) / 256, 256, 0, stream>>>(head_w, whd, VOCAB_ * DIM_);

    for (int l = 0; l < 2; ++l) {
        f32_to_bf16<<<(2048 * 512 / 4 + 255) / 256, 256, 0, stream>>>(in_w + (size_t)l * 2048 * 512, win, 2048 * 512);
        f32_to_bf16<<<(512 * 1024 / 4 + 255) / 256, 256, 0, stream>>>(out_w + (size_t)l * 512 * 1024, wout, 512 * 1024);
        rmsnorm_bf16<<<512, 256, 0, stream>>>(h, rms_w + l * DIM_, r_bf);
        gemm_bt<0><<<dim3(16, 16), 256, 0, stream>>>(r_bf, win, xz, nullptr, 2048, 2048, 512);
        conv_silu<<<2048 * 1024 / 256, 256, 0, stream>>>(xz, conv_w + l * DINNER_ * 4, conv_b + l * DINNER_, xc);
        xproj_kernel<<<512, 256, 0, stream>>>(xc, xproj_w + (size_t)l * 64 * 1024, dbc);
        dt_softplus<<<dim3(4, 256), 256, 0, stream>>>(dbc, dt_w + (size_t)l * 1024 * 32, dt_b + l * DINNER_, dlt);
        ssm_scan<<<dim3(128, 2), 128, 0, stream>>>(dlt, xc, dbc, xz, A_log + (size_t)l * DINNER_ * DSTATE_, Dp + l * DINNER_, ys);
        gemm_bt<1><<<dim3(16, 4), 256, 0, stream>>>(ys, wout, h, nullptr, 2048, 512, 1024);
    }

    layernorm_bf16<<<512, 256, 0, stream>>>(h, ln_g, ln_b, hn);
    gemm_bt<2><<<dim3(16, 250), 256, 0, stream>>>(hn, whd, out, head_b, 2048, VOCAB_, 512);
}

// Round 2
// 527.845 us; speedup vs baseline: 2.0949x; 2.0949x over previous
//
#include <hip/hip_runtime.h>

typedef unsigned short u16;
typedef __attribute__((ext_vector_type(8))) __bf16 bf16x8;
typedef __attribute__((ext_vector_type(4))) float f32x4;

#define B_ 2
#define L_ 1024
#define DIM_ 512
#define DINNER_ 1024
#define DSTATE_ 16
#define DTRANK_ 32
#define VOCAB_ 32000
#define NCHUNK 64
#define CLEN 16

__device__ __forceinline__ u16 f2bf(float f) {
    union { float f; unsigned u; } x; x.f = f;
    unsigned r = x.u + 0x7FFFu + ((x.u >> 16) & 1u);
    return (u16)(r >> 16);
}

// ---------------- f32 -> bf16 convert ----------------
__global__ __launch_bounds__(256) void f32_to_bf16(const float* __restrict__ in,
                                                   u16* __restrict__ out, int n) {
    int i = (blockIdx.x * 256 + threadIdx.x) * 4;
    if (i + 3 < n) {
        float4 v = *(const float4*)(in + i);
        ushort4 o;
        o.x = f2bf(v.x); o.y = f2bf(v.y); o.z = f2bf(v.z); o.w = f2bf(v.w);
        *(ushort4*)(out + i) = o;
    } else {
        for (; i < n; ++i) out[i] = f2bf(in[i]);
    }
}

// ---------------- embedding gather ----------------
__global__ __launch_bounds__(256) void embed_gather(const int* __restrict__ x,
                                                    const float* __restrict__ embed,
                                                    float* __restrict__ h) {
    int wave = threadIdx.x >> 6, lane = threadIdx.x & 63;
    int row = blockIdx.x * 4 + wave;           // 0..2047
    int tok = x[row];
    const float4* s = (const float4*)(embed + (size_t)tok * DIM_);
    float4* d = (float4*)(h + (size_t)row * DIM_);
    d[lane] = s[lane];
    d[lane + 64] = s[lane + 64];
}

// ---------------- RMSNorm -> bf16 ----------------
__global__ __launch_bounds__(256) void rmsnorm_bf16(const float* __restrict__ h,
                                                    const float* __restrict__ w,
                                                    u16* __restrict__ out) {
    int wave = threadIdx.x >> 6, lane = threadIdx.x & 63;
    int row = blockIdx.x * 4 + wave;
    const float4* r4 = (const float4*)(h + (size_t)row * DIM_);
    float4 v0 = r4[lane], v1 = r4[lane + 64];
    float ss = v0.x*v0.x + v0.y*v0.y + v0.z*v0.z + v0.w*v0.w
             + v1.x*v1.x + v1.y*v1.y + v1.z*v1.z + v1.w*v1.w;
    for (int m = 1; m < 64; m <<= 1) ss += __shfl_xor(ss, m);
    float rms = rsqrtf(ss * (1.0f / DIM_) + 1e-5f);
    const float4* w4 = (const float4*)w;
    float4 w0 = w4[lane], w1 = w4[lane + 64];
    u16* o = out + (size_t)row * DIM_;
    ushort4 a, b;
    a.x = f2bf(v0.x * rms * w0.x); a.y = f2bf(v0.y * rms * w0.y);
    a.z = f2bf(v0.z * rms * w0.z); a.w = f2bf(v0.w * rms * w0.w);
    b.x = f2bf(v1.x * rms * w1.x); b.y = f2bf(v1.y * rms * w1.y);
    b.z = f2bf(v1.z * rms * w1.z); b.w = f2bf(v1.w * rms * w1.w);
    *(ushort4*)(o + lane * 4) = a;
    *(ushort4*)(o + 256 + lane * 4) = b;
}

// ---------------- LayerNorm -> bf16 ----------------
__global__ __launch_bounds__(256) void layernorm_bf16(const float* __restrict__ h,
                                                      const float* __restrict__ g,
                                                      const float* __restrict__ bta,
                                                      u16* __restrict__ out) {
    int wave = threadIdx.x >> 6, lane = threadIdx.x & 63;
    int row = blockIdx.x * 4 + wave;
    const float4* r4 = (const float4*)(h + (size_t)row * DIM_);
    float4 v0 = r4[lane], v1 = r4[lane + 64];
    float s = v0.x + v0.y + v0.z + v0.w + v1.x + v1.y + v1.z + v1.w;
    float ss = v0.x*v0.x + v0.y*v0.y + v0.z*v0.z + v0.w*v0.w
             + v1.x*v1.x + v1.y*v1.y + v1.z*v1.z + v1.w*v1.w;
    for (int m = 1; m < 64; m <<= 1) { s += __shfl_xor(s, m); ss += __shfl_xor(ss, m); }
    float mu = s * (1.0f / DIM_);
    float var = ss * (1.0f / DIM_) - mu * mu;
    float rs = rsqrtf(var + 1e-5f);
    const float4* g4 = (const float4*)g;
    const float4* b4 = (const float4*)bta;
    float4 g0 = g4[lane], g1 = g4[lane + 64];
    float4 b0 = b4[lane], b1 = b4[lane + 64];
    u16* o = out + (size_t)row * DIM_;
    ushort4 a, b;
    a.x = f2bf((v0.x - mu) * rs * g0.x + b0.x); a.y = f2bf((v0.y - mu) * rs * g0.y + b0.y);
    a.z = f2bf((v0.z - mu) * rs * g0.z + b0.z); a.w = f2bf((v0.w - mu) * rs * g0.w + b0.w);
    b.x = f2bf((v1.x - mu) * rs * g1.x + b1.x); b.y = f2bf((v1.y - mu) * rs * g1.y + b1.y);
    b.z = f2bf((v1.z - mu) * rs * g1.z + b1.z); b.w = f2bf((v1.w - mu) * rs * g1.w + b1.w);
    *(ushort4*)(o + lane * 4) = a;
    *(ushort4*)(o + 256 + lane * 4) = b;
}

// ---------------- MFMA GEMM: C(MxN) = A(MxK,bf16) * B(NxK,bf16)^T ----------------
// MODE 0: C = acc ; MODE 1: C += acc ; MODE 2: C = acc + bias[col]
#define BM 128
#define BN 128
#define BK 32
template <int MODE>
__global__ __launch_bounds__(256) void gemm_bt(const u16* __restrict__ A,
                                               const u16* __restrict__ B,
                                               float* __restrict__ C,
                                               const float* __restrict__ bias,
                                               int M, int N, int K) {
    __shared__ u16 As[BM * BK];
    __shared__ u16 Bs[BN * BK];
    const int tid = threadIdx.x;
    const int wave = tid >> 6;
    const int lane = tid & 63;
    const int m0 = blockIdx.x * BM;
    const int n0 = blockIdx.y * BN;
    const int wr = wave >> 1, wc = wave & 1;
    f32x4 acc[4][4] = {};

    const int sub = lane >> 2;
    const int koff = (lane & 3) * 8;

    for (int k0 = 0; k0 < K; k0 += BK) {
        #pragma unroll
        for (int i = 0; i < 4; ++i) {
            int c = wave * 4 + i;
            const u16* src;
            u16* dst;
            if (c < 8) {
                int row = c * 16 + sub;
                src = A + (size_t)(m0 + row) * K + k0 + koff;
                dst = As + c * 512;
            } else {
                int cc = c - 8;
                int row = cc * 16 + sub;
                src = B + (size_t)(n0 + row) * K + k0 + koff;
                dst = Bs + cc * 512;
            }
            __builtin_amdgcn_global_load_lds((const __attribute__((address_space(1))) void*)src,
                                             (__attribute__((address_space(3))) void*)dst,
                                             16, 0, 0);
        }
        __syncthreads();
        bf16x8 a[4], b[4];
        const int fr = lane & 15;
        const int fk = (lane >> 4) * 8;
        #pragma unroll
        for (int mi = 0; mi < 4; ++mi) {
            int row = wr * 64 + mi * 16 + fr;
            a[mi] = *(const bf16x8*)(As + row * BK + fk);
        }
        #pragma unroll
        for (int ni = 0; ni < 4; ++ni) {
            int row = wc * 64 + ni * 16 + fr;
            b[ni] = *(const bf16x8*)(Bs + row * BK + fk);
        }
        #pragma unroll
        for (int mi = 0; mi < 4; ++mi)
            #pragma unroll
            for (int ni = 0; ni < 4; ++ni)
                acc[mi][ni] = __builtin_amdgcn_mfma_f32_16x16x32_bf16(a[mi], b[ni], acc[mi][ni], 0, 0, 0);
        __syncthreads();
    }

    const int cl = lane & 15;
    const int rq = (lane >> 4) * 4;
    #pragma unroll
    for (int mi = 0; mi < 4; ++mi) {
        #pragma unroll
        for (int ni = 0; ni < 4; ++ni) {
            int col = n0 + wc * 64 + ni * 16 + cl;
            #pragma unroll
            for (int rr = 0; rr < 4; ++rr) {
                int row = m0 + wr * 64 + mi * 16 + rq + rr;
                size_t idx = (size_t)row * N + col;
                float v = acc[mi][ni][rr];
                if (MODE == 1)      C[idx] += v;
                else if (MODE == 2) C[idx] = v + bias[col];
                else                C[idx] = v;
            }
        }
    }
}

// ---------------- causal depthwise conv (width 4) + silu ----------------
__global__ __launch_bounds__(256) void conv_silu(const float* __restrict__ xz,
                                                 const float* __restrict__ cw,
                                                 const float* __restrict__ cb,
                                                 float* __restrict__ xc) {
    int idx = blockIdx.x * 256 + threadIdx.x;
    int d = idx & (DINNER_ - 1);
    int m = idx >> 10;
    int l = m & (L_ - 1);
    float acc = cb[d];
    #pragma unroll
    for (int j = 0; j < 4; ++j) {
        int ll = l - 3 + j;
        if (ll >= 0) acc = fmaf(cw[d * 4 + j], xz[(size_t)(m - 3 + j) * (2 * DINNER_) + d], acc);
    }
    float sv = acc / (1.0f + __expf(-acc));
    xc[idx] = sv;
}

// ---------------- x-projection: dbc(2048x64) = xc(2048x1024) * xproj_w(64x1024)^T ----------------
__global__ __launch_bounds__(256) void xproj_kernel(const float* __restrict__ xc,
                                                    const float* __restrict__ xw,
                                                    float* __restrict__ dbc) {
    int t = threadIdx.x;
    int n = t & 63;
    int mi = t >> 6;
    int m = blockIdx.x * 4 + mi;
    const float4* xr = (const float4*)(xc + (size_t)m * DINNER_);
    const float4* wr = (const float4*)(xw + (size_t)n * DINNER_);
    float acc = 0.f;
    #pragma unroll 4
    for (int i = 0; i < DINNER_ / 4; ++i) {
        float4 a = xr[i], b = wr[i];
        acc += a.x * b.x + a.y * b.y + a.z * b.z + a.w * b.w;
    }
    dbc[(size_t)m * 64 + n] = acc;
}

// ---------------- dt projection + softplus: delta(2048x1024) ----------------
__global__ __launch_bounds__(256) void dt_softplus(const float* __restrict__ dbc,
                                                   const float* __restrict__ dtw,
                                                   const float* __restrict__ dtb,
                                                   float* __restrict__ delta) {
    __shared__ float sdbc[8][32];
    int t = threadIdx.x;
    int d = blockIdx.x * 256 + t;
    int m0 = blockIdx.y * 8;
    {
        int mi = t >> 5, r = t & 31;
        sdbc[mi][r] = dbc[(size_t)(m0 + mi) * 64 + r];
    }
    float w[32];
    const float4* wr = (const float4*)(dtw + (size_t)d * 32);
    #pragma unroll
    for (int i = 0; i < 8; ++i) {
        float4 v = wr[i];
        w[i * 4] = v.x; w[i * 4 + 1] = v.y; w[i * 4 + 2] = v.z; w[i * 4 + 3] = v.w;
    }
    float bias = dtb[d];
    __syncthreads();
    #pragma unroll
    for (int mi = 0; mi < 8; ++mi) {
        float acc = bias;
        #pragma unroll
        for (int r = 0; r < 32; ++r) acc = fmaf(sdbc[mi][r], w[r], acc);
        float sp = (acc > 20.f) ? acc : log1pf(__expf(acc));
        delta[(size_t)(m0 + mi) * DINNER_ + d] = sp;
    }
}

// ---------------- SSM pass 1: per-chunk local scan (h0=0) ----------------
__global__ __launch_bounds__(256) void ssm_part1(const float* __restrict__ delta,
                                                 const float* __restrict__ xc,
                                                 const float* __restrict__ dbc,
                                                 const float* __restrict__ A_log,
                                                 float* __restrict__ hfin,
                                                 float* __restrict__ sumd) {
    int tid = threadIdx.x;
    int d = blockIdx.x * 256 + tid;
    int c = blockIdx.y;
    int b = blockIdx.z;
    __shared__ float sB[CLEN][DSTATE_];
    {
        int l = tid >> 4, s = tid & 15;
        sB[l][s] = dbc[((size_t)(b * L_ + c * CLEN + l)) * 64 + DTRANK_ + s];
    }
    float A[16], h[16];
    {
        const float4* Ar = (const float4*)(A_log + (size_t)d * DSTATE_);
        #pragma unroll
        for (int i = 0; i < 4; ++i) {
            float4 al = Ar[i];
            A[i * 4 + 0] = -__expf(al.x); A[i * 4 + 1] = -__expf(al.y);
            A[i * 4 + 2] = -__expf(al.z); A[i * 4 + 3] = -__expf(al.w);
        }
    }
    #pragma unroll
    for (int s = 0; s < 16; ++s) h[s] = 0.f;
    __syncthreads();
    float sd = 0.f;
    size_t base = ((size_t)b * L_ + c * CLEN) * DINNER_ + d;
    #pragma unroll
    for (int l = 0; l < CLEN; ++l) {
        float dv = delta[base + (size_t)l * DINNER_];
        float xv = xc[base + (size_t)l * DINNER_];
        sd += dv;
        float dx = dv * xv;
        #pragma unroll
        for (int s = 0; s < 16; ++s) {
            float e = __expf(dv * A[s]);
            h[s] = fmaf(e, h[s], dx * sB[l][s]);
        }
    }
    float* hf = hfin + (((size_t)b * NCHUNK + c) * DINNER_ + d) * 16;
    #pragma unroll
    for (int i = 0; i < 4; ++i) {
        float4 v; v.x = h[i*4]; v.y = h[i*4+1]; v.z = h[i*4+2]; v.w = h[i*4+3];
        *(float4*)(hf + i * 4) = v;
    }
    sumd[((size_t)b * NCHUNK + c) * DINNER_ + d] = sd;
}

// ---------------- SSM pass 2: carry propagation across chunks ----------------
__global__ __launch_bounds__(256) void ssm_carry(const float* __restrict__ hfin,
                                                 const float* __restrict__ sumd,
                                                 const float* __restrict__ A_log,
                                                 float* __restrict__ h0buf) {
    int t = blockIdx.x * 256 + threadIdx.x;  // 0..32767
    int s = t & 15;
    int dg = t >> 4;
    int d = dg & (DINNER_ - 1);
    int b = dg >> 10;
    float As = -__expf(A_log[(size_t)d * DSTATE_ + s]);
    float hc = 0.f;
    for (int c = 0; c < NCHUNK; ++c) {
        size_t k = (((size_t)b * NCHUNK + c) * DINNER_ + d) * 16 + s;
        h0buf[k] = hc;
        float sdv = sumd[((size_t)b * NCHUNK + c) * DINNER_ + d];
        float hf = hfin[k];
        hc = fmaf(__expf(As * sdv), hc, hf);
    }
}

// ---------------- SSM pass 3: local scan w/ carry + y + gate -> ys(bf16) ----------------
__global__ __launch_bounds__(256) void ssm_part2(const float* __restrict__ delta,
                                                 const float* __restrict__ xc,
                                                 const float* __restrict__ dbc,
                                                 const float* __restrict__ xz,
                                                 const float* __restrict__ A_log,
                                                 const float* __restrict__ Dp,
                                                 const float* __restrict__ h0buf,
                                                 u16* __restrict__ ys) {
    int tid = threadIdx.x;
    int d = blockIdx.x * 256 + tid;
    int c = blockIdx.y;
    int b = blockIdx.z;
    __shared__ float sBC[CLEN][32];
    {
        int l = tid >> 5, j = tid & 31;
        sBC[l][j] = dbc[((size_t)(b * L_ + c * CLEN + l)) * 64 + DTRANK_ + j];
        int e1 = tid + 256;
        l = e1 >> 5; j = e1 & 31;
        sBC[l][j] = dbc[((size_t)(b * L_ + c * CLEN + l)) * 64 + DTRANK_ + j];
    }
    float A[16], h[16];
    {
        const float4* Ar = (const float4*)(A_log + (size_t)d * DSTATE_);
        #pragma unroll
        for (int i = 0; i < 4; ++i) {
            float4 al = Ar[i];
            A[i * 4 + 0] = -__expf(al.x); A[i * 4 + 1] = -__expf(al.y);
            A[i * 4 + 2] = -__expf(al.z); A[i * 4 + 3] = -__expf(al.w);
        }
        const float4* h0 = (const float4*)(h0buf + (((size_t)b * NCHUNK + c) * DINNER_ + d) * 16);
        #pragma unroll
        for (int i = 0; i < 4; ++i) {
            float4 v = h0[i];
            h[i * 4 + 0] = v.x; h[i * 4 + 1] = v.y; h[i * 4 + 2] = v.z; h[i * 4 + 3] = v.w;
        }
    }
    float Dval = Dp[d];
    __syncthreads();
    size_t base = ((size_t)b * L_ + c * CLEN) * DINNER_ + d;
    size_t zbase = ((size_t)b * L_ + c * CLEN) * (2 * DINNER_) + DINNER_ + d;
    #pragma unroll
    for (int l = 0; l < CLEN; ++l) {
        float dv = delta[base + (size_t)l * DINNER_];
        float xv = xc[base + (size_t)l * DINNER_];
        float zv = xz[zbase + (size_t)l * (2 * DINNER_)];
        float dx = dv * xv;
        float y = 0.f;
        #pragma unroll
        for (int s = 0; s < 16; ++s) {
            float e = __expf(dv * A[s]);
            h[s] = fmaf(e, h[s], dx * sBC[l][s]);
            y = fmaf(h[s], sBC[l][16 + s], y);
        }
        y = fmaf(Dval, xv, y);
        float sg = zv / (1.0f + __expf(-zv));
        ys[base + (size_t)l * DINNER_] = f2bf(y * sg);
    }
}

extern "C" void kernel_launch(void* const* d_in, const int* in_sizes, int n_in,
                              void* d_out, int out_size, void* d_ws, size_t ws_size,
                              hipStream_t stream) {
    const int*   x       = (const int*)d_in[0];
    const float* embed   = (const float*)d_in[1];
    const float* rms_w   = (const float*)d_in[2];
    const float* in_w    = (const float*)d_in[3];
    const float* conv_w  = (const float*)d_in[4];
    const float* conv_b  = (const float*)d_in[5];
    const float* xproj_w = (const float*)d_in[6];
    const float* dt_w    = (const float*)d_in[7];
    const float* dt_b    = (const float*)d_in[8];
    const float* A_log   = (const float*)d_in[9];
    const float* Dp      = (const float*)d_in[10];
    const float* out_w   = (const float*)d_in[11];
    const float* ln_g    = (const float*)d_in[12];
    const float* ln_b    = (const float*)d_in[13];
    const float* head_w  = (const float*)d_in[14];
    const float* head_b  = (const float*)d_in[15];
    float* out = (float*)d_out;

    char* p = (char*)d_ws;
    auto take = [&](size_t n) { char* q = p; p += (n + 255) & ~(size_t)255; return q; };
    float* h    = (float*)take(2048ull * 512 * 4);
    u16*   r_bf = (u16*)  take(2048ull * 512 * 2);
    float* xz   = (float*)take(2048ull * 2048 * 4);
    float* xc   = (float*)take(2048ull * 1024 * 4);
    float* dbc  = (float*)take(2048ull * 64 * 4);
    float* dlt  = (float*)take(2048ull * 1024 * 4);
    u16*   ys   = (u16*)  take(2048ull * 1024 * 2);
    u16*   hn   = (u16*)  take(2048ull * 512 * 2);
    u16*   win  = (u16*)  take(2048ull * 512 * 2);
    u16*   wout = (u16*)  take(512ull * 1024 * 2);
    u16*   whd  = (u16*)  take(32000ull * 512 * 2);

    // scan scratch aliases the whd region (head weights converted after layers)
    float* hfin = (float*)whd;                                   // 8 MB
    float* h0b  = hfin + (size_t)B_ * NCHUNK * DINNER_ * 16;     // 8 MB
    float* sumd = h0b + (size_t)B_ * NCHUNK * DINNER_ * 16;      // 0.5 MB (16.5 < 32.7 MB)

    embed_gather<<<512, 256, 0, stream>>>(x, embed, h);

    for (int l = 0; l < 2; ++l) {
        f32_to_bf16<<<(2048 * 512 / 4 + 255) / 256, 256, 0, stream>>>(in_w + (size_t)l * 2048 * 512, win, 2048 * 512);
        f32_to_bf16<<<(512 * 1024 / 4 + 255) / 256, 256, 0, stream>>>(out_w + (size_t)l * 512 * 1024, wout, 512 * 1024);
        rmsnorm_bf16<<<512, 256, 0, stream>>>(h, rms_w + l * DIM_, r_bf);
        gemm_bt<0><<<dim3(16, 16), 256, 0, stream>>>(r_bf, win, xz, nullptr, 2048, 2048, 512);
        conv_silu<<<2048 * 1024 / 256, 256, 0, stream>>>(xz, conv_w + l * DINNER_ * 4, conv_b + l * DINNER_, xc);
        xproj_kernel<<<512, 256, 0, stream>>>(xc, xproj_w + (size_t)l * 64 * 1024, dbc);
        dt_softplus<<<dim3(4, 256), 256, 0, stream>>>(dbc, dt_w + (size_t)l * 1024 * 32, dt_b + l * DINNER_, dlt);
        ssm_part1<<<dim3(4, NCHUNK, B_), 256, 0, stream>>>(dlt, xc, dbc, A_log + (size_t)l * DINNER_ * DSTATE_, hfin, sumd);
        ssm_carry<<<128, 256, 0, stream>>>(hfin, sumd, A_log + (size_t)l * DINNER_ * DSTATE_, h0b);
        ssm_part2<<<dim3(4, NCHUNK, B_), 256, 0, stream>>>(dlt, xc, dbc, xz, A_log + (size_t)l * DINNER_ * DSTATE_,
                                                           Dp + l * DINNER_, h0b, ys);
        gemm_bt<1><<<dim3(16, 4), 256, 0, stream>>>(ys, wout, h, nullptr, 2048, 512, 1024);
    }

    f32_to_bf16<<<(VOCAB_ * DIM_ / 4 + 255) / 256, 256, 0, stream>>>(head_w, whd, VOCAB_ * DIM_);
    layernorm_bf16<<<512, 256, 0, stream>>>(h, ln_g, ln_b, hn);
    gemm_bt<2><<<dim3(16, 250), 256, 0, stream>>>(hn, whd, out, head_b, 2048, VOCAB_, 512);
}

// Round 3
// 472.123 us; speedup vs baseline: 2.3422x; 1.1180x over previous
//
#include <hip/hip_runtime.h>

typedef unsigned short u16;
typedef __attribute__((ext_vector_type(8))) __bf16 bf16x8;
typedef __attribute__((ext_vector_type(4))) float f32x4;

#define B_ 2
#define L_ 1024
#define DIM_ 512
#define DINNER_ 1024
#define DSTATE_ 16
#define DTRANK_ 32
#define VOCAB_ 32000
#define NCHUNK 64
#define CLEN 16

__device__ __forceinline__ u16 f2bf(float f) {
    union { float f; unsigned u; } x; x.f = f;
    unsigned r = x.u + 0x7FFFu + ((x.u >> 16) & 1u);
    return (u16)(r >> 16);
}

// ---------------- f32 -> bf16 convert ----------------
__global__ __launch_bounds__(256) void f32_to_bf16(const float* __restrict__ in,
                                                   u16* __restrict__ out, int n) {
    int i = (blockIdx.x * 256 + threadIdx.x) * 4;
    if (i + 3 < n) {
        float4 v = *(const float4*)(in + i);
        ushort4 o;
        o.x = f2bf(v.x); o.y = f2bf(v.y); o.z = f2bf(v.z); o.w = f2bf(v.w);
        *(ushort4*)(out + i) = o;
    } else {
        for (; i < n; ++i) out[i] = f2bf(in[i]);
    }
}

// ---------------- embedding gather ----------------
__global__ __launch_bounds__(256) void embed_gather(const int* __restrict__ x,
                                                    const float* __restrict__ embed,
                                                    float* __restrict__ h) {
    int wave = threadIdx.x >> 6, lane = threadIdx.x & 63;
    int row = blockIdx.x * 4 + wave;
    int tok = x[row];
    const float4* s = (const float4*)(embed + (size_t)tok * DIM_);
    float4* d = (float4*)(h + (size_t)row * DIM_);
    d[lane] = s[lane];
    d[lane + 64] = s[lane + 64];
}

// ---------------- RMSNorm -> bf16 ----------------
__global__ __launch_bounds__(256) void rmsnorm_bf16(const float* __restrict__ h,
                                                    const float* __restrict__ w,
                                                    u16* __restrict__ out) {
    int wave = threadIdx.x >> 6, lane = threadIdx.x & 63;
    int row = blockIdx.x * 4 + wave;
    const float4* r4 = (const float4*)(h + (size_t)row * DIM_);
    float4 v0 = r4[lane], v1 = r4[lane + 64];
    float ss = v0.x*v0.x + v0.y*v0.y + v0.z*v0.z + v0.w*v0.w
             + v1.x*v1.x + v1.y*v1.y + v1.z*v1.z + v1.w*v1.w;
    for (int m = 1; m < 64; m <<= 1) ss += __shfl_xor(ss, m);
    float rms = rsqrtf(ss * (1.0f / DIM_) + 1e-5f);
    const float4* w4 = (const float4*)w;
    float4 w0 = w4[lane], w1 = w4[lane + 64];
    u16* o = out + (size_t)row * DIM_;
    ushort4 a, b;
    a.x = f2bf(v0.x * rms * w0.x); a.y = f2bf(v0.y * rms * w0.y);
    a.z = f2bf(v0.z * rms * w0.z); a.w = f2bf(v0.w * rms * w0.w);
    b.x = f2bf(v1.x * rms * w1.x); b.y = f2bf(v1.y * rms * w1.y);
    b.z = f2bf(v1.z * rms * w1.z); b.w = f2bf(v1.w * rms * w1.w);
    *(ushort4*)(o + lane * 4) = a;
    *(ushort4*)(o + 256 + lane * 4) = b;
}

// ---------------- LayerNorm -> bf16 ----------------
__global__ __launch_bounds__(256) void layernorm_bf16(const float* __restrict__ h,
                                                      const float* __restrict__ g,
                                                      const float* __restrict__ bta,
                                                      u16* __restrict__ out) {
    int wave = threadIdx.x >> 6, lane = threadIdx.x & 63;
    int row = blockIdx.x * 4 + wave;
    const float4* r4 = (const float4*)(h + (size_t)row * DIM_);
    float4 v0 = r4[lane], v1 = r4[lane + 64];
    float s = v0.x + v0.y + v0.z + v0.w + v1.x + v1.y + v1.z + v1.w;
    float ss = v0.x*v0.x + v0.y*v0.y + v0.z*v0.z + v0.w*v0.w
             + v1.x*v1.x + v1.y*v1.y + v1.z*v1.z + v1.w*v1.w;
    for (int m = 1; m < 64; m <<= 1) { s += __shfl_xor(s, m); ss += __shfl_xor(ss, m); }
    float mu = s * (1.0f / DIM_);
    float var = ss * (1.0f / DIM_) - mu * mu;
    float rs = rsqrtf(var + 1e-5f);
    const float4* g4 = (const float4*)g;
    const float4* b4 = (const float4*)bta;
    float4 g0 = g4[lane], g1 = g4[lane + 64];
    float4 b0 = b4[lane], b1 = b4[lane + 64];
    u16* o = out + (size_t)row * DIM_;
    ushort4 a, b;
    a.x = f2bf((v0.x - mu) * rs * g0.x + b0.x); a.y = f2bf((v0.y - mu) * rs * g0.y + b0.y);
    a.z = f2bf((v0.z - mu) * rs * g0.z + b0.z); a.w = f2bf((v0.w - mu) * rs * g0.w + b0.w);
    b.x = f2bf((v1.x - mu) * rs * g1.x + b1.x); b.y = f2bf((v1.y - mu) * rs * g1.y + b1.y);
    b.z = f2bf((v1.z - mu) * rs * g1.z + b1.z); b.w = f2bf((v1.w - mu) * rs * g1.w + b1.w);
    *(ushort4*)(o + lane * 4) = a;
    *(ushort4*)(o + 256 + lane * 4) = b;
}

// ---------------- MFMA GEMM 128x128 (head): C = A*B^T (+bias) ----------------
// 1D grid with XCD swizzle. nbx = M/128 tiles (varies fastest).
#define BK 32
template <int MODE>
__global__ __launch_bounds__(256) void gemm_bt(const u16* __restrict__ A,
                                               const u16* __restrict__ B,
                                               float* __restrict__ C,
                                               const float* __restrict__ bias,
                                               int M, int N, int K,
                                               int nbx, int swzq) {
    __shared__ u16 As[128 * BK];
    __shared__ u16 Bs[128 * BK];
    const int tid = threadIdx.x;
    const int wave = tid >> 6;
    const int lane = tid & 63;
    int lin = blockIdx.x;
    if (swzq) lin = (lin & 7) * swzq + (lin >> 3);   // XCD chunking (nwg%8==0)
    const int m0 = (lin % nbx) * 128;
    const int n0 = (lin / nbx) * 128;
    const int wr = wave >> 1, wc = wave & 1;
    f32x4 acc[4][4] = {};

    const int sub = lane >> 2;
    const int koff = (lane & 3) * 8;

    for (int k0 = 0; k0 < K; k0 += BK) {
        #pragma unroll
        for (int i = 0; i < 4; ++i) {
            int c = wave * 4 + i;
            const u16* src;
            u16* dst;
            if (c < 8) {
                int row = c * 16 + sub;
                src = A + (size_t)(m0 + row) * K + k0 + koff;
                dst = As + c * 512;
            } else {
                int cc = c - 8;
                int row = cc * 16 + sub;
                src = B + (size_t)(n0 + row) * K + k0 + koff;
                dst = Bs + cc * 512;
            }
            __builtin_amdgcn_global_load_lds((const __attribute__((address_space(1))) void*)src,
                                             (__attribute__((address_space(3))) void*)dst,
                                             16, 0, 0);
        }
        __syncthreads();
        bf16x8 a[4], b[4];
        const int fr = lane & 15;
        const int fk = (lane >> 4) * 8;
        #pragma unroll
        for (int mi = 0; mi < 4; ++mi)
            a[mi] = *(const bf16x8*)(As + (wr * 64 + mi * 16 + fr) * BK + fk);
        #pragma unroll
        for (int ni = 0; ni < 4; ++ni)
            b[ni] = *(const bf16x8*)(Bs + (wc * 64 + ni * 16 + fr) * BK + fk);
        #pragma unroll
        for (int mi = 0; mi < 4; ++mi)
            #pragma unroll
            for (int ni = 0; ni < 4; ++ni)
                acc[mi][ni] = __builtin_amdgcn_mfma_f32_16x16x32_bf16(a[mi], b[ni], acc[mi][ni], 0, 0, 0);
        __syncthreads();
    }

    const int cl = lane & 15;
    const int rq = (lane >> 4) * 4;
    #pragma unroll
    for (int mi = 0; mi < 4; ++mi) {
        #pragma unroll
        for (int ni = 0; ni < 4; ++ni) {
            int col = n0 + wc * 64 + ni * 16 + cl;
            #pragma unroll
            for (int rr = 0; rr < 4; ++rr) {
                int row = m0 + wr * 64 + mi * 16 + rq + rr;
                size_t idx = (size_t)row * N + col;
                float v = acc[mi][ni][rr];
                if (MODE == 1)      C[idx] += v;
                else if (MODE == 2) C[idx] = v + bias[col];
                else                C[idx] = v;
            }
        }
    }
}

// ---------------- MFMA GEMM 64x64, BK=64 (layer GEMMs; high occupancy) ----------------
template <int MODE>
__global__ __launch_bounds__(256) void gemm64(const u16* __restrict__ A,
                                              const u16* __restrict__ B,
                                              float* __restrict__ C,
                                              int M, int N, int K,
                                              int nbx, int swzq) {
    __shared__ u16 As[64 * 64];
    __shared__ u16 Bs[64 * 64];
    const int tid = threadIdx.x;
    const int wave = tid >> 6;
    const int lane = tid & 63;
    int lin = blockIdx.x;
    if (swzq) lin = (lin & 7) * swzq + (lin >> 3);
    const int m0 = (lin % nbx) * 64;
    const int n0 = (lin / nbx) * 64;
    const int wr = wave >> 1, wc = wave & 1;
    f32x4 acc[2][2] = {};

    const int srow = lane >> 3;        // row within 8-row chunk
    const int scol = (lane & 7) * 8;   // col offset (64-wide rows)

    for (int k0 = 0; k0 < K; k0 += 64) {
        #pragma unroll
        for (int i = 0; i < 4; ++i) {
            int c = wave * 4 + i;      // 0..15
            const u16* src;
            u16* dst;
            if (c < 8) {
                int row = c * 8 + srow;
                src = A + (size_t)(m0 + row) * K + k0 + scol;
                dst = As + c * 512;
            } else {
                int cc = c - 8;
                int row = cc * 8 + srow;
                src = B + (size_t)(n0 + row) * K + k0 + scol;
                dst = Bs + cc * 512;
            }
            __builtin_amdgcn_global_load_lds((const __attribute__((address_space(1))) void*)src,
                                             (__attribute__((address_space(3))) void*)dst,
                                             16, 0, 0);
        }
        __syncthreads();
        const int fr = lane & 15;
        const int fk = (lane >> 4) * 8;
        bf16x8 a[2][2], b[2][2];       // [ki][mi/ni]
        #pragma unroll
        for (int ki = 0; ki < 2; ++ki) {
            #pragma unroll
            for (int mi = 0; mi < 2; ++mi)
                a[ki][mi] = *(const bf16x8*)(As + (wr * 32 + mi * 16 + fr) * 64 + ki * 32 + fk);
            #pragma unroll
            for (int ni = 0; ni < 2; ++ni)
                b[ki][ni] = *(const bf16x8*)(Bs + (wc * 32 + ni * 16 + fr) * 64 + ki * 32 + fk);
        }
        #pragma unroll
        for (int ki = 0; ki < 2; ++ki)
            #pragma unroll
            for (int mi = 0; mi < 2; ++mi)
                #pragma unroll
                for (int ni = 0; ni < 2; ++ni)
                    acc[mi][ni] = __builtin_amdgcn_mfma_f32_16x16x32_bf16(a[ki][mi], b[ki][ni], acc[mi][ni], 0, 0, 0);
        __syncthreads();
    }

    const int cl = lane & 15;
    const int rq = (lane >> 4) * 4;
    #pragma unroll
    for (int mi = 0; mi < 2; ++mi) {
        #pragma unroll
        for (int ni = 0; ni < 2; ++ni) {
            int col = n0 + wc * 32 + ni * 16 + cl;
            #pragma unroll
            for (int rr = 0; rr < 4; ++rr) {
                int row = m0 + wr * 32 + mi * 16 + rq + rr;
                size_t idx = (size_t)row * N + col;
                float v = acc[mi][ni][rr];
                if (MODE == 1)      C[idx] += v;
                else                C[idx] = v;
            }
        }
    }
}

// ---------------- causal depthwise conv (width 4) + silu ----------------
__global__ __launch_bounds__(256) void conv_silu(const float* __restrict__ xz,
                                                 const float* __restrict__ cw,
                                                 const float* __restrict__ cb,
                                                 float* __restrict__ xc) {
    int idx = blockIdx.x * 256 + threadIdx.x;
    int d = idx & (DINNER_ - 1);
    int m = idx >> 10;
    int l = m & (L_ - 1);
    float acc = cb[d];
    #pragma unroll
    for (int j = 0; j < 4; ++j) {
        int ll = l - 3 + j;
        if (ll >= 0) acc = fmaf(cw[d * 4 + j], xz[(size_t)(m - 3 + j) * (2 * DINNER_) + d], acc);
    }
    float sv = acc / (1.0f + __expf(-acc));
    xc[idx] = sv;
}

// ---------------- fused x-projection + dt projection + softplus ----------------
// block: 256 threads, 4 rows. Phase 1: dbc[4][64] (thread=(mi,n)); Phase 2: delta.
__global__ __launch_bounds__(256) void xproj_dt(const float* __restrict__ xc,
                                                const float* __restrict__ xw,
                                                const float* __restrict__ dtw,
                                                const float* __restrict__ dtb,
                                                float* __restrict__ dbc,
                                                float* __restrict__ delta) {
    __shared__ float sdbc[4][64];
    int t = threadIdx.x;
    {
        int n = t & 63;
        int mi = t >> 6;
        int m = blockIdx.x * 4 + mi;
        const float4* xr = (const float4*)(xc + (size_t)m * DINNER_);
        const float4* wr = (const float4*)(xw + (size_t)n * DINNER_);
        float acc = 0.f;
        #pragma unroll 4
        for (int i = 0; i < DINNER_ / 4; ++i) {
            float4 a = xr[i], b = wr[i];
            acc += a.x * b.x + a.y * b.y + a.z * b.z + a.w * b.w;
        }
        sdbc[mi][n] = acc;
        dbc[(size_t)m * 64 + n] = acc;
    }
    __syncthreads();
    // Phase 2: delta[m0+mi][d] for d = t*4..t*4+3
    int d0 = t * 4;
    float4 bias = *(const float4*)(dtb + d0);
    float4 o[4];
    #pragma unroll
    for (int j = 0; j < 4; ++j) {
        int d = d0 + j;
        const float4* wr = (const float4*)(dtw + (size_t)d * 32);
        float w[32];
        #pragma unroll
        for (int i = 0; i < 8; ++i) {
            float4 v = wr[i];
            w[i*4] = v.x; w[i*4+1] = v.y; w[i*4+2] = v.z; w[i*4+3] = v.w;
        }
        float bj = (j == 0) ? bias.x : (j == 1) ? bias.y : (j == 2) ? bias.z : bias.w;
        #pragma unroll
        for (int mi = 0; mi < 4; ++mi) {
            float acc = bj;
            #pragma unroll
            for (int r = 0; r < 32; ++r) acc = fmaf(sdbc[mi][r], w[r], acc);
            float sp = (acc > 20.f) ? acc : log1pf(__expf(acc));
            ((float*)&o[mi])[j] = sp;
        }
    }
    int m0 = blockIdx.x * 4;
    #pragma unroll
    for (int mi = 0; mi < 4; ++mi)
        *(float4*)(delta + (size_t)(m0 + mi) * DINNER_ + d0) = o[mi];
}

// ---------------- SSM pass 1: per-chunk local scan (h0=0) ----------------
__global__ __launch_bounds__(256) void ssm_part1(const float* __restrict__ delta,
                                                 const float* __restrict__ xc,
                                                 const float* __restrict__ dbc,
                                                 const float* __restrict__ A_log,
                                                 float* __restrict__ hfin,
                                                 float* __restrict__ sumd) {
    int tid = threadIdx.x;
    int d = blockIdx.x * 256 + tid;
    int c = blockIdx.y;
    int b = blockIdx.z;
    __shared__ float sB[CLEN][DSTATE_];
    {
        int l = tid >> 4, s = tid & 15;
        sB[l][s] = dbc[((size_t)(b * L_ + c * CLEN + l)) * 64 + DTRANK_ + s];
    }
    float A[16], h[16];
    {
        const float4* Ar = (const float4*)(A_log + (size_t)d * DSTATE_);
        #pragma unroll
        for (int i = 0; i < 4; ++i) {
            float4 al = Ar[i];
            A[i * 4 + 0] = -__expf(al.x); A[i * 4 + 1] = -__expf(al.y);
            A[i * 4 + 2] = -__expf(al.z); A[i * 4 + 3] = -__expf(al.w);
        }
    }
    #pragma unroll
    for (int s = 0; s < 16; ++s) h[s] = 0.f;
    __syncthreads();
    float sd = 0.f;
    size_t base = ((size_t)b * L_ + c * CLEN) * DINNER_ + d;
    #pragma unroll
    for (int l = 0; l < CLEN; ++l) {
        float dv = delta[base + (size_t)l * DINNER_];
        float xv = xc[base + (size_t)l * DINNER_];
        sd += dv;
        float dx = dv * xv;
        #pragma unroll
        for (int s = 0; s < 16; ++s) {
            float e = __expf(dv * A[s]);
            h[s] = fmaf(e, h[s], dx * sB[l][s]);
        }
    }
    float* hf = hfin + (((size_t)b * NCHUNK + c) * DINNER_ + d) * 16;
    #pragma unroll
    for (int i = 0; i < 4; ++i) {
        float4 v; v.x = h[i*4]; v.y = h[i*4+1]; v.z = h[i*4+2]; v.w = h[i*4+3];
        *(float4*)(hf + i * 4) = v;
    }
    sumd[((size_t)b * NCHUNK + c) * DINNER_ + d] = sd;
}

// ---------------- SSM pass 2: carry propagation across chunks ----------------
__global__ __launch_bounds__(256) void ssm_carry(const float* __restrict__ hfin,
                                                 const float* __restrict__ sumd,
                                                 const float* __restrict__ A_log,
                                                 float* __restrict__ h0buf) {
    int t = blockIdx.x * 256 + threadIdx.x;
    int s = t & 15;
    int dg = t >> 4;
    int d = dg & (DINNER_ - 1);
    int b = dg >> 10;
    float As = -__expf(A_log[(size_t)d * DSTATE_ + s]);
    float hc = 0.f;
    for (int c = 0; c < NCHUNK; ++c) {
        size_t k = (((size_t)b * NCHUNK + c) * DINNER_ + d) * 16 + s;
        h0buf[k] = hc;
        float sdv = sumd[((size_t)b * NCHUNK + c) * DINNER_ + d];
        float hf = hfin[k];
        hc = fmaf(__expf(As * sdv), hc, hf);
    }
}

// ---------------- SSM pass 3: local scan w/ carry + y + gate -> ys(bf16) ----------------
__global__ __launch_bounds__(256) void ssm_part2(const float* __restrict__ delta,
                                                 const float* __restrict__ xc,
                                                 const float* __restrict__ dbc,
                                                 const float* __restrict__ xz,
                                                 const float* __restrict__ A_log,
                                                 const float* __restrict__ Dp,
                                                 const float* __restrict__ h0buf,
                                                 u16* __restrict__ ys) {
    int tid = threadIdx.x;
    int d = blockIdx.x * 256 + tid;
    int c = blockIdx.y;
    int b = blockIdx.z;
    __shared__ float sBC[CLEN][32];
    {
        int l = tid >> 5, j = tid & 31;
        sBC[l][j] = dbc[((size_t)(b * L_ + c * CLEN + l)) * 64 + DTRANK_ + j];
        int e1 = tid + 256;
        l = e1 >> 5; j = e1 & 31;
        sBC[l][j] = dbc[((size_t)(b * L_ + c * CLEN + l)) * 64 + DTRANK_ + j];
    }
    float A[16], h[16];
    {
        const float4* Ar = (const float4*)(A_log + (size_t)d * DSTATE_);
        #pragma unroll
        for (int i = 0; i < 4; ++i) {
            float4 al = Ar[i];
            A[i * 4 + 0] = -__expf(al.x); A[i * 4 + 1] = -__expf(al.y);
            A[i * 4 + 2] = -__expf(al.z); A[i * 4 + 3] = -__expf(al.w);
        }
        const float4* h0 = (const float4*)(h0buf + (((size_t)b * NCHUNK + c) * DINNER_ + d) * 16);
        #pragma unroll
        for (int i = 0; i < 4; ++i) {
            float4 v = h0[i];
            h[i * 4 + 0] = v.x; h[i * 4 + 1] = v.y; h[i * 4 + 2] = v.z; h[i * 4 + 3] = v.w;
        }
    }
    float Dval = Dp[d];
    __syncthreads();
    size_t base = ((size_t)b * L_ + c * CLEN) * DINNER_ + d;
    size_t zbase = ((size_t)b * L_ + c * CLEN) * (2 * DINNER_) + DINNER_ + d;
    #pragma unroll
    for (int l = 0; l < CLEN; ++l) {
        float dv = delta[base + (size_t)l * DINNER_];
        float xv = xc[base + (size_t)l * DINNER_];
        float zv = xz[zbase + (size_t)l * (2 * DINNER_)];
        float dx = dv * xv;
        float y = 0.f;
        #pragma unroll
        for (int s = 0; s < 16; ++s) {
            float e = __expf(dv * A[s]);
            h[s] = fmaf(e, h[s], dx * sBC[l][s]);
            y = fmaf(h[s], sBC[l][16 + s], y);
        }
        y = fmaf(Dval, xv, y);
        float sg = zv / (1.0f + __expf(-zv));
        ys[base + (size_t)l * DINNER_] = f2bf(y * sg);
    }
}

extern "C" void kernel_launch(void* const* d_in, const int* in_sizes, int n_in,
                              void* d_out, int out_size, void* d_ws, size_t ws_size,
                              hipStream_t stream) {
    const int*   x       = (const int*)d_in[0];
    const float* embed   = (const float*)d_in[1];
    const float* rms_w   = (const float*)d_in[2];
    const float* in_w    = (const float*)d_in[3];
    const float* conv_w  = (const float*)d_in[4];
    const float* conv_b  = (const float*)d_in[5];
    const float* xproj_w = (const float*)d_in[6];
    const float* dt_w    = (const float*)d_in[7];
    const float* dt_b    = (const float*)d_in[8];
    const float* A_log   = (const float*)d_in[9];
    const float* Dp      = (const float*)d_in[10];
    const float* out_w   = (const float*)d_in[11];
    const float* ln_g    = (const float*)d_in[12];
    const float* ln_b    = (const float*)d_in[13];
    const float* head_w  = (const float*)d_in[14];
    const float* head_b  = (const float*)d_in[15];
    float* out = (float*)d_out;

    char* p = (char*)d_ws;
    auto take = [&](size_t n) { char* q = p; p += (n + 255) & ~(size_t)255; return q; };
    float* h    = (float*)take(2048ull * 512 * 4);
    u16*   r_bf = (u16*)  take(2048ull * 512 * 2);
    float* xz   = (float*)take(2048ull * 2048 * 4);
    float* xc   = (float*)take(2048ull * 1024 * 4);
    float* dbc  = (float*)take(2048ull * 64 * 4);
    float* dlt  = (float*)take(2048ull * 1024 * 4);
    u16*   ys   = (u16*)  take(2048ull * 1024 * 2);
    u16*   hn   = (u16*)  take(2048ull * 512 * 2);
    u16*   win  = (u16*)  take(2048ull * 512 * 2);
    u16*   wout = (u16*)  take(512ull * 1024 * 2);
    u16*   whd  = (u16*)  take(32000ull * 512 * 2);

    // scan scratch aliases the whd region (head weights converted after layers)
    float* hfin = (float*)whd;
    float* h0b  = hfin + (size_t)B_ * NCHUNK * DINNER_ * 16;
    float* sumd = h0b + (size_t)B_ * NCHUNK * DINNER_ * 16;

    embed_gather<<<512, 256, 0, stream>>>(x, embed, h);

    for (int l = 0; l < 2; ++l) {
        f32_to_bf16<<<(2048 * 512 / 4 + 255) / 256, 256, 0, stream>>>(in_w + (size_t)l * 2048 * 512, win, 2048 * 512);
        f32_to_bf16<<<(512 * 1024 / 4 + 255) / 256, 256, 0, stream>>>(out_w + (size_t)l * 512 * 1024, wout, 512 * 1024);
        rmsnorm_bf16<<<512, 256, 0, stream>>>(h, rms_w + l * DIM_, r_bf);
        // xz = r_bf(2048x512) @ win^T(2048x512) : grid 32x32=1024, swzq=128
        gemm64<0><<<1024, 256, 0, stream>>>(r_bf, win, xz, 2048, 2048, 512, 32, 128);
        conv_silu<<<2048 * 1024 / 256, 256, 0, stream>>>(xz, conv_w + l * DINNER_ * 4, conv_b + l * DINNER_, xc);
        xproj_dt<<<512, 256, 0, stream>>>(xc, xproj_w + (size_t)l * 64 * 1024,
                                          dt_w + (size_t)l * 1024 * 32, dt_b + l * DINNER_, dbc, dlt);
        ssm_part1<<<dim3(4, NCHUNK, B_), 256, 0, stream>>>(dlt, xc, dbc, A_log + (size_t)l * DINNER_ * DSTATE_, hfin, sumd);
        ssm_carry<<<128, 256, 0, stream>>>(hfin, sumd, A_log + (size_t)l * DINNER_ * DSTATE_, h0b);
        ssm_part2<<<dim3(4, NCHUNK, B_), 256, 0, stream>>>(dlt, xc, dbc, xz, A_log + (size_t)l * DINNER_ * DSTATE_,
                                                           Dp + l * DINNER_, h0b, ys);
        // h += ys(2048x1024) @ wout^T(512x1024) : grid 32x8=256, swzq=32
        gemm64<1><<<256, 256, 0, stream>>>(ys, wout, h, 2048, 512, 1024, 32, 32);
    }

    f32_to_bf16<<<(VOCAB_ * DIM_ / 4 + 255) / 256, 256, 0, stream>>>(head_w, whd, VOCAB_ * DIM_);
    layernorm_bf16<<<512, 256, 0, stream>>>(h, ln_g, ln_b, hn);
    // logits = hn(2048x512) @ whd^T(32000x512) + head_b : grid 16x250=4000, swzq=500
    gemm_bt<2><<<4000, 256, 0, stream>>>(hn, whd, out, head_b, 2048, VOCAB_, 512, 16, 500);
}

// Round 4
// 445.240 us; speedup vs baseline: 2.4836x; 1.0604x over previous
//
#include <hip/hip_runtime.h>

typedef unsigned short u16;
typedef __attribute__((ext_vector_type(8))) __bf16 bf16x8;
typedef __attribute__((ext_vector_type(4))) float f32x4;

#define B_ 2
#define L_ 1024
#define DIM_ 512
#define DINNER_ 1024
#define DSTATE_ 16
#define DTRANK_ 32
#define VOCAB_ 32000
#define NCHUNK 64
#define CLEN 16

__device__ __forceinline__ u16 f2bf(float f) {
    union { float f; unsigned u; } x; x.f = f;
    unsigned r = x.u + 0x7FFFu + ((x.u >> 16) & 1u);
    return (u16)(r >> 16);
}

// ---------------- all weight conversions in one kernel ----------------
// win: 2 layers of in_w (2048x512), wout: 2 layers (512x1024), whd: head (32000x512)
__global__ __launch_bounds__(256) void convert_all(const float* __restrict__ in_w,
                                                   const float* __restrict__ out_w,
                                                   const float* __restrict__ head_w,
                                                   u16* __restrict__ win,
                                                   u16* __restrict__ wout,
                                                   u16* __restrict__ whd) {
    const int n1 = 524288;              // in_w float4s (both layers)
    const int n2 = n1 + 262144;         // + out_w
    const int n3 = n2 + 4096000;        // + head_w
    int i = blockIdx.x * 256 + threadIdx.x;
    if (i >= n3) return;
    const float4* s; ushort4* d; int j;
    if (i < n1)      { s = (const float4*)in_w;   d = (ushort4*)win;  j = i; }
    else if (i < n2) { s = (const float4*)out_w;  d = (ushort4*)wout; j = i - n1; }
    else             { s = (const float4*)head_w; d = (ushort4*)whd;  j = i - n2; }
    float4 v = s[j];
    ushort4 o; o.x = f2bf(v.x); o.y = f2bf(v.y); o.z = f2bf(v.z); o.w = f2bf(v.w);
    d[j] = o;
}

// ---------------- embedding gather + RMSNorm (layer 0) ----------------
__global__ __launch_bounds__(256) void embed_rms(const int* __restrict__ x,
                                                 const float* __restrict__ embed,
                                                 const float* __restrict__ w,
                                                 float* __restrict__ h,
                                                 u16* __restrict__ out) {
    int wave = threadIdx.x >> 6, lane = threadIdx.x & 63;
    int row = blockIdx.x * 4 + wave;
    int tok = x[row];
    const float4* s = (const float4*)(embed + (size_t)tok * DIM_);
    float4 v0 = s[lane], v1 = s[lane + 64];
    float4* hd = (float4*)(h + (size_t)row * DIM_);
    hd[lane] = v0;
    hd[lane + 64] = v1;
    float ss = v0.x*v0.x + v0.y*v0.y + v0.z*v0.z + v0.w*v0.w
             + v1.x*v1.x + v1.y*v1.y + v1.z*v1.z + v1.w*v1.w;
    for (int m = 1; m < 64; m <<= 1) ss += __shfl_xor(ss, m);
    float rms = rsqrtf(ss * (1.0f / DIM_) + 1e-5f);
    const float4* w4 = (const float4*)w;
    float4 w0 = w4[lane], w1 = w4[lane + 64];
    u16* o = out + (size_t)row * DIM_;
    ushort4 a, b;
    a.x = f2bf(v0.x * rms * w0.x); a.y = f2bf(v0.y * rms * w0.y);
    a.z = f2bf(v0.z * rms * w0.z); a.w = f2bf(v0.w * rms * w0.w);
    b.x = f2bf(v1.x * rms * w1.x); b.y = f2bf(v1.y * rms * w1.y);
    b.z = f2bf(v1.z * rms * w1.z); b.w = f2bf(v1.w * rms * w1.w);
    *(ushort4*)(o + lane * 4) = a;
    *(ushort4*)(o + 256 + lane * 4) = b;
}

// ---------------- RMSNorm -> bf16 ----------------
__global__ __launch_bounds__(256) void rmsnorm_bf16(const float* __restrict__ h,
                                                    const float* __restrict__ w,
                                                    u16* __restrict__ out) {
    int wave = threadIdx.x >> 6, lane = threadIdx.x & 63;
    int row = blockIdx.x * 4 + wave;
    const float4* r4 = (const float4*)(h + (size_t)row * DIM_);
    float4 v0 = r4[lane], v1 = r4[lane + 64];
    float ss = v0.x*v0.x + v0.y*v0.y + v0.z*v0.z + v0.w*v0.w
             + v1.x*v1.x + v1.y*v1.y + v1.z*v1.z + v1.w*v1.w;
    for (int m = 1; m < 64; m <<= 1) ss += __shfl_xor(ss, m);
    float rms = rsqrtf(ss * (1.0f / DIM_) + 1e-5f);
    const float4* w4 = (const float4*)w;
    float4 w0 = w4[lane], w1 = w4[lane + 64];
    u16* o = out + (size_t)row * DIM_;
    ushort4 a, b;
    a.x = f2bf(v0.x * rms * w0.x); a.y = f2bf(v0.y * rms * w0.y);
    a.z = f2bf(v0.z * rms * w0.z); a.w = f2bf(v0.w * rms * w0.w);
    b.x = f2bf(v1.x * rms * w1.x); b.y = f2bf(v1.y * rms * w1.y);
    b.z = f2bf(v1.z * rms * w1.z); b.w = f2bf(v1.w * rms * w1.w);
    *(ushort4*)(o + lane * 4) = a;
    *(ushort4*)(o + 256 + lane * 4) = b;
}

// ---------------- LayerNorm -> bf16 ----------------
__global__ __launch_bounds__(256) void layernorm_bf16(const float* __restrict__ h,
                                                      const float* __restrict__ g,
                                                      const float* __restrict__ bta,
                                                      u16* __restrict__ out) {
    int wave = threadIdx.x >> 6, lane = threadIdx.x & 63;
    int row = blockIdx.x * 4 + wave;
    const float4* r4 = (const float4*)(h + (size_t)row * DIM_);
    float4 v0 = r4[lane], v1 = r4[lane + 64];
    float s = v0.x + v0.y + v0.z + v0.w + v1.x + v1.y + v1.z + v1.w;
    float ss = v0.x*v0.x + v0.y*v0.y + v0.z*v0.z + v0.w*v0.w
             + v1.x*v1.x + v1.y*v1.y + v1.z*v1.z + v1.w*v1.w;
    for (int m = 1; m < 64; m <<= 1) { s += __shfl_xor(s, m); ss += __shfl_xor(ss, m); }
    float mu = s * (1.0f / DIM_);
    float var = ss * (1.0f / DIM_) - mu * mu;
    float rs = rsqrtf(var + 1e-5f);
    const float4* g4 = (const float4*)g;
    const float4* b4 = (const float4*)bta;
    float4 g0 = g4[lane], g1 = g4[lane + 64];
    float4 b0 = b4[lane], b1 = b4[lane + 64];
    u16* o = out + (size_t)row * DIM_;
    ushort4 a, b;
    a.x = f2bf((v0.x - mu) * rs * g0.x + b0.x); a.y = f2bf((v0.y - mu) * rs * g0.y + b0.y);
    a.z = f2bf((v0.z - mu) * rs * g0.z + b0.z); a.w = f2bf((v0.w - mu) * rs * g0.w + b0.w);
    b.x = f2bf((v1.x - mu) * rs * g1.x + b1.x); b.y = f2bf((v1.y - mu) * rs * g1.y + b1.y);
    b.z = f2bf((v1.z - mu) * rs * g1.z + b1.z); b.w = f2bf((v1.w - mu) * rs * g1.w + b1.w);
    *(ushort4*)(o + lane * 4) = a;
    *(ushort4*)(o + 256 + lane * 4) = b;
}

// ---------------- MFMA GEMM 128x128, BK=32, 2-phase double-buffered ----------------
// MODE 0: C = acc ; MODE 2: C = acc + bias[col]
template <int MODE>
__global__ __launch_bounds__(256) void gemm_bt(const u16* __restrict__ A,
                                               const u16* __restrict__ B,
                                               float* __restrict__ C,
                                               const float* __restrict__ bias,
                                               int M, int N, int K,
                                               int nbx, int swzq) {
    __shared__ u16 As[2][128 * 32];
    __shared__ u16 Bs[2][128 * 32];
    const int tid = threadIdx.x;
    const int wave = tid >> 6;
    const int lane = tid & 63;
    int lin = blockIdx.x;
    if (swzq) lin = (lin & 7) * swzq + (lin >> 3);   // XCD chunking (nwg%8==0)
    const int m0 = (lin % nbx) * 128;
    const int n0 = (lin / nbx) * 128;
    const int wr = wave >> 1, wc = wave & 1;
    f32x4 acc[4][4] = {};

    const int sub = lane >> 2;
    const int koff = (lane & 3) * 8;

    auto stage = [&](int buf, int k0) {
        #pragma unroll
        for (int i = 0; i < 4; ++i) {
            int c = wave * 4 + i;
            const u16* src;
            u16* dst;
            if (c < 8) {
                int row = c * 16 + sub;
                src = A + (size_t)(m0 + row) * K + k0 + koff;
                dst = &As[buf][c * 512];
            } else {
                int cc = c - 8;
                int row = cc * 16 + sub;
                src = B + (size_t)(n0 + row) * K + k0 + koff;
                dst = &Bs[buf][cc * 512];
            }
            __builtin_amdgcn_global_load_lds((const __attribute__((address_space(1))) void*)src,
                                             (__attribute__((address_space(3))) void*)dst,
                                             16, 0, 0);
        }
    };

    const int nt = K / 32;
    stage(0, 0);
    __syncthreads();                    // compiler drains vmcnt before barrier
    int cur = 0;
    for (int t = 0; t < nt; ++t) {
        if (t + 1 < nt) stage(cur ^ 1, (t + 1) * 32);
        bf16x8 a[4], b[4];
        const int fr = lane & 15;
        const int fk = (lane >> 4) * 8;
        #pragma unroll
        for (int mi = 0; mi < 4; ++mi)
            a[mi] = *(const bf16x8*)(&As[cur][(wr * 64 + mi * 16 + fr) * 32 + fk]);
        #pragma unroll
        for (int ni = 0; ni < 4; ++ni)
            b[ni] = *(const bf16x8*)(&Bs[cur][(wc * 64 + ni * 16 + fr) * 32 + fk]);
        #pragma unroll
        for (int mi = 0; mi < 4; ++mi)
            #pragma unroll
            for (int ni = 0; ni < 4; ++ni)
                acc[mi][ni] = __builtin_amdgcn_mfma_f32_16x16x32_bf16(a[mi], b[ni], acc[mi][ni], 0, 0, 0);
        __syncthreads();                // drains next-tile loads + protects cur buffer
        cur ^= 1;
    }

    const int cl = lane & 15;
    const int rq = (lane >> 4) * 4;
    #pragma unroll
    for (int mi = 0; mi < 4; ++mi) {
        #pragma unroll
        for (int ni = 0; ni < 4; ++ni) {
            int col = n0 + wc * 64 + ni * 16 + cl;
            #pragma unroll
            for (int rr = 0; rr < 4; ++rr) {
                int row = m0 + wr * 64 + mi * 16 + rq + rr;
                size_t idx = (size_t)row * N + col;
                float v = acc[mi][ni][rr];
                if (MODE == 2)      C[idx] = v + bias[col];
                else                C[idx] = v;
            }
        }
    }
}

// ---------------- MFMA GEMM 64x64, BK=64, 2-phase double-buffered ----------------
template <int MODE>
__global__ __launch_bounds__(256) void gemm64(const u16* __restrict__ A,
                                              const u16* __restrict__ B,
                                              float* __restrict__ C,
                                              int M, int N, int K,
                                              int nbx, int swzq) {
    __shared__ u16 As[2][64 * 64];
    __shared__ u16 Bs[2][64 * 64];
    const int tid = threadIdx.x;
    const int wave = tid >> 6;
    const int lane = tid & 63;
    int lin = blockIdx.x;
    if (swzq) lin = (lin & 7) * swzq + (lin >> 3);
    const int m0 = (lin % nbx) * 64;
    const int n0 = (lin / nbx) * 64;
    const int wr = wave >> 1, wc = wave & 1;
    f32x4 acc[2][2] = {};

    const int srow = lane >> 3;
    const int scol = (lane & 7) * 8;

    auto stage = [&](int buf, int k0) {
        #pragma unroll
        for (int i = 0; i < 4; ++i) {
            int c = wave * 4 + i;
            const u16* src;
            u16* dst;
            if (c < 8) {
                int row = c * 8 + srow;
                src = A + (size_t)(m0 + row) * K + k0 + scol;
                dst = &As[buf][c * 512];
            } else {
                int cc = c - 8;
                int row = cc * 8 + srow;
                src = B + (size_t)(n0 + row) * K + k0 + scol;
                dst = &Bs[buf][cc * 512];
            }
            __builtin_amdgcn_global_load_lds((const __attribute__((address_space(1))) void*)src,
                                             (__attribute__((address_space(3))) void*)dst,
                                             16, 0, 0);
        }
    };

    const int nt = K / 64;
    stage(0, 0);
    __syncthreads();
    int cur = 0;
    for (int t = 0; t < nt; ++t) {
        if (t + 1 < nt) stage(cur ^ 1, (t + 1) * 64);
        const int fr = lane & 15;
        const int fk = (lane >> 4) * 8;
        bf16x8 a[2][2], b[2][2];
        #pragma unroll
        for (int ki = 0; ki < 2; ++ki) {
            #pragma unroll
            for (int mi = 0; mi < 2; ++mi)
                a[ki][mi] = *(const bf16x8*)(&As[cur][(wr * 32 + mi * 16 + fr) * 64 + ki * 32 + fk]);
            #pragma unroll
            for (int ni = 0; ni < 2; ++ni)
                b[ki][ni] = *(const bf16x8*)(&Bs[cur][(wc * 32 + ni * 16 + fr) * 64 + ki * 32 + fk]);
        }
        #pragma unroll
        for (int ki = 0; ki < 2; ++ki)
            #pragma unroll
            for (int mi = 0; mi < 2; ++mi)
                #pragma unroll
                for (int ni = 0; ni < 2; ++ni)
                    acc[mi][ni] = __builtin_amdgcn_mfma_f32_16x16x32_bf16(a[ki][mi], b[ki][ni], acc[mi][ni], 0, 0, 0);
        __syncthreads();
        cur ^= 1;
    }

    const int cl = lane & 15;
    const int rq = (lane >> 4) * 4;
    #pragma unroll
    for (int mi = 0; mi < 2; ++mi) {
        #pragma unroll
        for (int ni = 0; ni < 2; ++ni) {
            int col = n0 + wc * 32 + ni * 16 + cl;
            #pragma unroll
            for (int rr = 0; rr < 4; ++rr) {
                int row = m0 + wr * 32 + mi * 16 + rq + rr;
                size_t idx = (size_t)row * N + col;
                float v = acc[mi][ni][rr];
                if (MODE == 1)      C[idx] += v;
                else                C[idx] = v;
            }
        }
    }
}

// ---------------- fused conv+silu -> xproj -> dt+softplus ----------------
// block: 256 threads, 4 rows.
__global__ __launch_bounds__(256) void conv_xproj_dt(const float* __restrict__ xz,
                                                     const float* __restrict__ cw,
                                                     const float* __restrict__ cb,
                                                     const float* __restrict__ xw,
                                                     const float* __restrict__ dtw,
                                                     const float* __restrict__ dtb,
                                                     float* __restrict__ xc,
                                                     float* __restrict__ dbc,
                                                     float* __restrict__ delta) {
    __shared__ float sxc[4][1028];
    __shared__ float sdbc[4][64];
    int t = threadIdx.x;
    int m0 = blockIdx.x * 4;
    // phase 0: conv + silu for 4 rows into LDS + global xc
    #pragma unroll
    for (int i = 0; i < 16; ++i) {
        int idx = t + i * 256;            // 0..4095
        int mi = idx >> 10, d = idx & 1023;
        int m = m0 + mi;
        int l = m & (L_ - 1);
        float acc = cb[d];
        #pragma unroll
        for (int j = 0; j < 4; ++j) {
            int ll = l - 3 + j;
            if (ll >= 0) acc = fmaf(cw[d * 4 + j], xz[(size_t)(m - 3 + j) * (2 * DINNER_) + d], acc);
        }
        float sv = acc / (1.0f + __expf(-acc));
        sxc[mi][d] = sv;
        xc[(size_t)m * DINNER_ + d] = sv;
    }
    __syncthreads();
    // phase 1: xproj (thread = (mi, n)) reading conv output from LDS
    {
        int n = t & 63, mi = t >> 6;
        const float4* wr = (const float4*)(xw + (size_t)n * DINNER_);
        const float* xr = sxc[mi];
        float acc = 0.f;
        #pragma unroll 4
        for (int i = 0; i < 256; ++i) {
            float4 b = wr[i];
            float4 a = *(const float4*)(xr + i * 4);
            acc += a.x * b.x + a.y * b.y + a.z * b.z + a.w * b.w;
        }
        sdbc[mi][n] = acc;
        dbc[(size_t)(m0 + mi) * 64 + n] = acc;
    }
    __syncthreads();
    // phase 2: dt projection + softplus (thread covers d = 4t..4t+3)
    int d0 = t * 4;
    float4 bias = *(const float4*)(dtb + d0);
    float4 o[4];
    #pragma unroll
    for (int j = 0; j < 4; ++j) {
        int d = d0 + j;
        const float4* wr = (const float4*)(dtw + (size_t)d * 32);
        float w[32];
        #pragma unroll
        for (int i = 0; i < 8; ++i) {
            float4 v = wr[i];
            w[i*4] = v.x; w[i*4+1] = v.y; w[i*4+2] = v.z; w[i*4+3] = v.w;
        }
        float bj = (j == 0) ? bias.x : (j == 1) ? bias.y : (j == 2) ? bias.z : bias.w;
        #pragma unroll
        for (int mi = 0; mi < 4; ++mi) {
            float acc = bj;
            #pragma unroll
            for (int r = 0; r < 32; ++r) acc = fmaf(sdbc[mi][r], w[r], acc);
            float sp = (acc > 20.f) ? acc : log1pf(__expf(acc));
            ((float*)&o[mi])[j] = sp;
        }
    }
    #pragma unroll
    for (int mi = 0; mi < 4; ++mi)
        *(float4*)(delta + (size_t)(m0 + mi) * DINNER_ + d0) = o[mi];
}

// ---------------- SSM pass 1: per-chunk local scan (h0=0) ----------------
__global__ __launch_bounds__(256) void ssm_part1(const float* __restrict__ delta,
                                                 const float* __restrict__ xc,
                                                 const float* __restrict__ dbc,
                                                 const float* __restrict__ A_log,
                                                 float* __restrict__ hfin,
                                                 float* __restrict__ sumd) {
    int tid = threadIdx.x;
    int d = blockIdx.x * 256 + tid;
    int c = blockIdx.y;
    int b = blockIdx.z;
    __shared__ float sB[CLEN][DSTATE_];
    {
        int l = tid >> 4, s = tid & 15;
        sB[l][s] = dbc[((size_t)(b * L_ + c * CLEN + l)) * 64 + DTRANK_ + s];
    }
    float A[16], h[16];
    {
        const float4* Ar = (const float4*)(A_log + (size_t)d * DSTATE_);
        #pragma unroll
        for (int i = 0; i < 4; ++i) {
            float4 al = Ar[i];
            A[i * 4 + 0] = -__expf(al.x); A[i * 4 + 1] = -__expf(al.y);
            A[i * 4 + 2] = -__expf(al.z); A[i * 4 + 3] = -__expf(al.w);
        }
    }
    #pragma unroll
    for (int s = 0; s < 16; ++s) h[s] = 0.f;
    __syncthreads();
    float sd = 0.f;
    size_t base = ((size_t)b * L_ + c * CLEN) * DINNER_ + d;
    #pragma unroll
    for (int l = 0; l < CLEN; ++l) {
        float dv = delta[base + (size_t)l * DINNER_];
        float xv = xc[base + (size_t)l * DINNER_];
        sd += dv;
        float dx = dv * xv;
        #pragma unroll
        for (int s = 0; s < 16; ++s) {
            float e = __expf(dv * A[s]);
            h[s] = fmaf(e, h[s], dx * sB[l][s]);
        }
    }
    float* hf = hfin + (((size_t)b * NCHUNK + c) * DINNER_ + d) * 16;
    #pragma unroll
    for (int i = 0; i < 4; ++i) {
        float4 v; v.x = h[i*4]; v.y = h[i*4+1]; v.z = h[i*4+2]; v.w = h[i*4+3];
        *(float4*)(hf + i * 4) = v;
    }
    sumd[((size_t)b * NCHUNK + c) * DINNER_ + d] = sd;
}

// ---------------- SSM pass 2: carry propagation across chunks ----------------
__global__ __launch_bounds__(256) void ssm_carry(const float* __restrict__ hfin,
                                                 const float* __restrict__ sumd,
                                                 const float* __restrict__ A_log,
                                                 float* __restrict__ h0buf) {
    int t = blockIdx.x * 256 + threadIdx.x;
    int s = t & 15;
    int dg = t >> 4;
    int d = dg & (DINNER_ - 1);
    int b = dg >> 10;
    float As = -__expf(A_log[(size_t)d * DSTATE_ + s]);
    float hc = 0.f;
    #pragma unroll 4
    for (int c = 0; c < NCHUNK; ++c) {
        size_t k = (((size_t)b * NCHUNK + c) * DINNER_ + d) * 16 + s;
        h0buf[k] = hc;
        float sdv = sumd[((size_t)b * NCHUNK + c) * DINNER_ + d];
        float hf = hfin[k];
        hc = fmaf(__expf(As * sdv), hc, hf);
    }
}

// ---------------- SSM pass 3: local scan w/ carry + y + gate -> ys(bf16) ----------------
__global__ __launch_bounds__(256) void ssm_part2(const float* __restrict__ delta,
                                                 const float* __restrict__ xc,
                                                 const float* __restrict__ dbc,
                                                 const float* __restrict__ xz,
                                                 const float* __restrict__ A_log,
                                                 const float* __restrict__ Dp,
                                                 const float* __restrict__ h0buf,
                                                 u16* __restrict__ ys) {
    int tid = threadIdx.x;
    int d = blockIdx.x * 256 + tid;
    int c = blockIdx.y;
    int b = blockIdx.z;
    __shared__ float sBC[CLEN][32];
    {
        int l = tid >> 5, j = tid & 31;
        sBC[l][j] = dbc[((size_t)(b * L_ + c * CLEN + l)) * 64 + DTRANK_ + j];
        int e1 = tid + 256;
        l = e1 >> 5; j = e1 & 31;
        sBC[l][j] = dbc[((size_t)(b * L_ + c * CLEN + l)) * 64 + DTRANK_ + j];
    }
    float A[16], h[16];
    {
        const float4* Ar = (const float4*)(A_log + (size_t)d * DSTATE_);
        #pragma unroll
        for (int i = 0; i < 4; ++i) {
            float4 al = Ar[i];
            A[i * 4 + 0] = -__expf(al.x); A[i * 4 + 1] = -__expf(al.y);
            A[i * 4 + 2] = -__expf(al.z); A[i * 4 + 3] = -__expf(al.w);
        }
        const float4* h0 = (const float4*)(h0buf + (((size_t)b * NCHUNK + c) * DINNER_ + d) * 16);
        #pragma unroll
        for (int i = 0; i < 4; ++i) {
            float4 v = h0[i];
            h[i * 4 + 0] = v.x; h[i * 4 + 1] = v.y; h[i * 4 + 2] = v.z; h[i * 4 + 3] = v.w;
        }
    }
    float Dval = Dp[d];
    __syncthreads();
    size_t base = ((size_t)b * L_ + c * CLEN) * DINNER_ + d;
    size_t zbase = ((size_t)b * L_ + c * CLEN) * (2 * DINNER_) + DINNER_ + d;
    #pragma unroll
    for (int l = 0; l < CLEN; ++l) {
        float dv = delta[base + (size_t)l * DINNER_];
        float xv = xc[base + (size_t)l * DINNER_];
        float zv = xz[zbase + (size_t)l * (2 * DINNER_)];
        float dx = dv * xv;
        float y = 0.f;
        #pragma unroll
        for (int s = 0; s < 16; ++s) {
            float e = __expf(dv * A[s]);
            h[s] = fmaf(e, h[s], dx * sBC[l][s]);
            y = fmaf(h[s], sBC[l][16 + s], y);
        }
        y = fmaf(Dval, xv, y);
        float sg = zv / (1.0f + __expf(-zv));
        ys[base + (size_t)l * DINNER_] = f2bf(y * sg);
    }
}

extern "C" void kernel_launch(void* const* d_in, const int* in_sizes, int n_in,
                              void* d_out, int out_size, void* d_ws, size_t ws_size,
                              hipStream_t stream) {
    const int*   x       = (const int*)d_in[0];
    const float* embed   = (const float*)d_in[1];
    const float* rms_w   = (const float*)d_in[2];
    const float* in_w    = (const float*)d_in[3];
    const float* conv_w  = (const float*)d_in[4];
    const float* conv_b  = (const float*)d_in[5];
    const float* xproj_w = (const float*)d_in[6];
    const float* dt_w    = (const float*)d_in[7];
    const float* dt_b    = (const float*)d_in[8];
    const float* A_log   = (const float*)d_in[9];
    const float* Dp      = (const float*)d_in[10];
    const float* out_w   = (const float*)d_in[11];
    const float* ln_g    = (const float*)d_in[12];
    const float* ln_b    = (const float*)d_in[13];
    const float* head_w  = (const float*)d_in[14];
    const float* head_b  = (const float*)d_in[15];
    float* out = (float*)d_out;

    char* p = (char*)d_ws;
    auto take = [&](size_t n) { char* q = p; p += (n + 255) & ~(size_t)255; return q; };
    float* h    = (float*)take(2048ull * 512 * 4);
    u16*   r_bf = (u16*)  take(2048ull * 512 * 2);
    float* xz   = (float*)take(2048ull * 2048 * 4);
    float* xc   = (float*)take(2048ull * 1024 * 4);
    float* dbc  = (float*)take(2048ull * 64 * 4);
    float* dlt  = (float*)take(2048ull * 1024 * 4);
    u16*   ys   = (u16*)  take(2048ull * 1024 * 2);
    u16*   hn   = (u16*)  take(2048ull * 512 * 2);
    u16*   win  = (u16*)  take(2ull * 2048 * 512 * 2);
    u16*   wout = (u16*)  take(2ull * 512 * 1024 * 2);
    u16*   whd  = (u16*)  take(32000ull * 512 * 2);
    float* hfin = (float*)take((size_t)B_ * NCHUNK * DINNER_ * 16 * 4);
    float* h0b  = (float*)take((size_t)B_ * NCHUNK * DINNER_ * 16 * 4);
    float* sumd = (float*)take((size_t)B_ * NCHUNK * DINNER_ * 4);

    convert_all<<<19072, 256, 0, stream>>>(in_w, out_w, head_w, win, wout, whd);
    embed_rms<<<512, 256, 0, stream>>>(x, embed, rms_w, h, r_bf);

    for (int l = 0; l < 2; ++l) {
        if (l > 0) rmsnorm_bf16<<<512, 256, 0, stream>>>(h, rms_w + l * DIM_, r_bf);
        // xz = r_bf(2048x512) @ win^T(2048x512) : grid 32x32=1024, swzq=128
        gemm64<0><<<1024, 256, 0, stream>>>(r_bf, win + (size_t)l * 2048 * 512, xz, 2048, 2048, 512, 32, 128);
        conv_xproj_dt<<<512, 256, 0, stream>>>(xz, conv_w + l * DINNER_ * 4, conv_b + l * DINNER_,
                                               xproj_w + (size_t)l * 64 * 1024,
                                               dt_w + (size_t)l * 1024 * 32, dt_b + l * DINNER_,
                                               xc, dbc, dlt);
        ssm_part1<<<dim3(4, NCHUNK, B_), 256, 0, stream>>>(dlt, xc, dbc, A_log + (size_t)l * DINNER_ * DSTATE_, hfin, sumd);
        ssm_carry<<<128, 256, 0, stream>>>(hfin, sumd, A_log + (size_t)l * DINNER_ * DSTATE_, h0b);
        ssm_part2<<<dim3(4, NCHUNK, B_), 256, 0, stream>>>(dlt, xc, dbc, xz, A_log + (size_t)l * DINNER_ * DSTATE_,
                                                           Dp + l * DINNER_, h0b, ys);
        // h += ys(2048x1024) @ wout^T(512x1024) : grid 32x8=256, swzq=32
        gemm64<1><<<256, 256, 0, stream>>>(ys, wout + (size_t)l * 512 * 1024, h, 2048, 512, 1024, 32, 32);
    }

    layernorm_bf16<<<512, 256, 0, stream>>>(h, ln_g, ln_b, hn);
    // logits = hn(2048x512) @ whd^T(32000x512) + head_b : grid 16x250=4000, swzq=500
    gemm_bt<2><<<4000, 256, 0, stream>>>(hn, whd, out, head_b, 2048, VOCAB_, 512, 16, 500);
}

// Round 5
// 404.067 us; speedup vs baseline: 2.7366x; 1.1019x over previous
//
#include <hip/hip_runtime.h>

typedef unsigned short u16;
typedef __attribute__((ext_vector_type(8))) __bf16 bf16x8;
typedef __attribute__((ext_vector_type(4))) float f32x4;

#define B_ 2
#define L_ 1024
#define DIM_ 512
#define DINNER_ 1024
#define DSTATE_ 16
#define DTRANK_ 32
#define VOCAB_ 32000
#define NCHUNK 64
#define CLEN 16

__device__ __forceinline__ u16 f2bf(float f) {
    union { float f; unsigned u; } x; x.f = f;
    unsigned r = x.u + 0x7FFFu + ((x.u >> 16) & 1u);
    return (u16)(r >> 16);
}

// ---------------- prep: weight bf16 conversions + dtw transpose + embed+rms ----------------
// blocks [0,19072): f32->bf16 of in_w/out_w/head_w
// blocks [19072,19328): dtwT[l] (32x1024) = transpose of dt_w[l] (1024x32)
// blocks [19328,19840): embed gather + rmsnorm layer 0
__global__ __launch_bounds__(256) void prep(const float* __restrict__ in_w,
                                            const float* __restrict__ out_w,
                                            const float* __restrict__ head_w,
                                            const float* __restrict__ dt_w,
                                            const int* __restrict__ x,
                                            const float* __restrict__ embed,
                                            const float* __restrict__ rw,
                                            u16* __restrict__ win,
                                            u16* __restrict__ wout,
                                            u16* __restrict__ whd,
                                            float* __restrict__ dtwT,
                                            float* __restrict__ h,
                                            u16* __restrict__ rbf) {
    int bk = blockIdx.x;
    int t = threadIdx.x;
    if (bk < 19072) {
        const int n1 = 524288;
        const int n2 = n1 + 262144;
        int i = bk * 256 + t;
        const float4* s; ushort4* d; int j;
        if (i < n1)      { s = (const float4*)in_w;   d = (ushort4*)win;  j = i; }
        else if (i < n2) { s = (const float4*)out_w;  d = (ushort4*)wout; j = i - n1; }
        else             { s = (const float4*)head_w; d = (ushort4*)whd;  j = i - n2; }
        float4 v = s[j];
        ushort4 o; o.x = f2bf(v.x); o.y = f2bf(v.y); o.z = f2bf(v.z); o.w = f2bf(v.w);
        d[j] = o;
    } else if (bk < 19328) {
        int bb = bk - 19072;
        int l = bb >> 7;
        int e = (bb & 127) * 256 + t;       // 0..32767
        int r = e >> 10, d = e & 1023;
        dtwT[(size_t)l * 32768 + r * 1024 + d] = dt_w[(size_t)l * 32768 + d * 32 + r];
    } else {
        int wave = t >> 6, lane = t & 63;
        int row = (bk - 19328) * 4 + wave;
        int tok = x[row];
        const float4* s = (const float4*)(embed + (size_t)tok * DIM_);
        float4 v0 = s[lane], v1 = s[lane + 64];
        float4* hd = (float4*)(h + (size_t)row * DIM_);
        hd[lane] = v0;
        hd[lane + 64] = v1;
        float ss = v0.x*v0.x + v0.y*v0.y + v0.z*v0.z + v0.w*v0.w
                 + v1.x*v1.x + v1.y*v1.y + v1.z*v1.z + v1.w*v1.w;
        for (int m = 1; m < 64; m <<= 1) ss += __shfl_xor(ss, m);
        float rms = rsqrtf(ss * (1.0f / DIM_) + 1e-5f);
        const float4* w4 = (const float4*)rw;
        float4 w0 = w4[lane], w1 = w4[lane + 64];
        u16* o = rbf + (size_t)row * DIM_;
        ushort4 a, b;
        a.x = f2bf(v0.x * rms * w0.x); a.y = f2bf(v0.y * rms * w0.y);
        a.z = f2bf(v0.z * rms * w0.z); a.w = f2bf(v0.w * rms * w0.w);
        b.x = f2bf(v1.x * rms * w1.x); b.y = f2bf(v1.y * rms * w1.y);
        b.z = f2bf(v1.z * rms * w1.z); b.w = f2bf(v1.w * rms * w1.w);
        *(ushort4*)(o + lane * 4) = a;
        *(ushort4*)(o + 256 + lane * 4) = b;
    }
}

// ---------------- RMSNorm -> bf16 ----------------
__global__ __launch_bounds__(256) void rmsnorm_bf16(const float* __restrict__ h,
                                                    const float* __restrict__ w,
                                                    u16* __restrict__ out) {
    int wave = threadIdx.x >> 6, lane = threadIdx.x & 63;
    int row = blockIdx.x * 4 + wave;
    const float4* r4 = (const float4*)(h + (size_t)row * DIM_);
    float4 v0 = r4[lane], v1 = r4[lane + 64];
    float ss = v0.x*v0.x + v0.y*v0.y + v0.z*v0.z + v0.w*v0.w
             + v1.x*v1.x + v1.y*v1.y + v1.z*v1.z + v1.w*v1.w;
    for (int m = 1; m < 64; m <<= 1) ss += __shfl_xor(ss, m);
    float rms = rsqrtf(ss * (1.0f / DIM_) + 1e-5f);
    const float4* w4 = (const float4*)w;
    float4 w0 = w4[lane], w1 = w4[lane + 64];
    u16* o = out + (size_t)row * DIM_;
    ushort4 a, b;
    a.x = f2bf(v0.x * rms * w0.x); a.y = f2bf(v0.y * rms * w0.y);
    a.z = f2bf(v0.z * rms * w0.z); a.w = f2bf(v0.w * rms * w0.w);
    b.x = f2bf(v1.x * rms * w1.x); b.y = f2bf(v1.y * rms * w1.y);
    b.z = f2bf(v1.z * rms * w1.z); b.w = f2bf(v1.w * rms * w1.w);
    *(ushort4*)(o + lane * 4) = a;
    *(ushort4*)(o + 256 + lane * 4) = b;
}

// ---------------- LayerNorm -> bf16 ----------------
__global__ __launch_bounds__(256) void layernorm_bf16(const float* __restrict__ h,
                                                      const float* __restrict__ g,
                                                      const float* __restrict__ bta,
                                                      u16* __restrict__ out) {
    int wave = threadIdx.x >> 6, lane = threadIdx.x & 63;
    int row = blockIdx.x * 4 + wave;
    const float4* r4 = (const float4*)(h + (size_t)row * DIM_);
    float4 v0 = r4[lane], v1 = r4[lane + 64];
    float s = v0.x + v0.y + v0.z + v0.w + v1.x + v1.y + v1.z + v1.w;
    float ss = v0.x*v0.x + v0.y*v0.y + v0.z*v0.z + v0.w*v0.w
             + v1.x*v1.x + v1.y*v1.y + v1.z*v1.z + v1.w*v1.w;
    for (int m = 1; m < 64; m <<= 1) { s += __shfl_xor(s, m); ss += __shfl_xor(ss, m); }
    float mu = s * (1.0f / DIM_);
    float var = ss * (1.0f / DIM_) - mu * mu;
    float rs = rsqrtf(var + 1e-5f);
    const float4* g4 = (const float4*)g;
    const float4* b4 = (const float4*)bta;
    float4 g0 = g4[lane], g1 = g4[lane + 64];
    float4 b0 = b4[lane], b1 = b4[lane + 64];
    u16* o = out + (size_t)row * DIM_;
    ushort4 a, b;
    a.x = f2bf((v0.x - mu) * rs * g0.x + b0.x); a.y = f2bf((v0.y - mu) * rs * g0.y + b0.y);
    a.z = f2bf((v0.z - mu) * rs * g0.z + b0.z); a.w = f2bf((v0.w - mu) * rs * g0.w + b0.w);
    b.x = f2bf((v1.x - mu) * rs * g1.x + b1.x); b.y = f2bf((v1.y - mu) * rs * g1.y + b1.y);
    b.z = f2bf((v1.z - mu) * rs * g1.z + b1.z); b.w = f2bf((v1.w - mu) * rs * g1.w + b1.w);
    *(ushort4*)(o + lane * 4) = a;
    *(ushort4*)(o + 256 + lane * 4) = b;
}

// ---------------- MFMA GEMM 128x128, BK=32, 2-phase double-buffered ----------------
template <int MODE>
__global__ __launch_bounds__(256) void gemm_bt(const u16* __restrict__ A,
                                               const u16* __restrict__ B,
                                               float* __restrict__ C,
                                               const float* __restrict__ bias,
                                               int M, int N, int K,
                                               int nbx, int swzq) {
    __shared__ u16 As[2][128 * 32];
    __shared__ u16 Bs[2][128 * 32];
    const int tid = threadIdx.x;
    const int wave = tid >> 6;
    const int lane = tid & 63;
    int lin = blockIdx.x;
    if (swzq) lin = (lin & 7) * swzq + (lin >> 3);
    const int m0 = (lin % nbx) * 128;
    const int n0 = (lin / nbx) * 128;
    const int wr = wave >> 1, wc = wave & 1;
    f32x4 acc[4][4] = {};

    const int sub = lane >> 2;
    const int koff = (lane & 3) * 8;

    auto stage = [&](int buf, int k0) {
        #pragma unroll
        for (int i = 0; i < 4; ++i) {
            int c = wave * 4 + i;
            const u16* src;
            u16* dst;
            if (c < 8) {
                int row = c * 16 + sub;
                src = A + (size_t)(m0 + row) * K + k0 + koff;
                dst = &As[buf][c * 512];
            } else {
                int cc = c - 8;
                int row = cc * 16 + sub;
                src = B + (size_t)(n0 + row) * K + k0 + koff;
                dst = &Bs[buf][cc * 512];
            }
            __builtin_amdgcn_global_load_lds((const __attribute__((address_space(1))) void*)src,
                                             (__attribute__((address_space(3))) void*)dst,
                                             16, 0, 0);
        }
    };

    const int nt = K / 32;
    stage(0, 0);
    __syncthreads();
    int cur = 0;
    for (int t = 0; t < nt; ++t) {
        if (t + 1 < nt) stage(cur ^ 1, (t + 1) * 32);
        bf16x8 a[4], b[4];
        const int fr = lane & 15;
        const int fk = (lane >> 4) * 8;
        #pragma unroll
        for (int mi = 0; mi < 4; ++mi)
            a[mi] = *(const bf16x8*)(&As[cur][(wr * 64 + mi * 16 + fr) * 32 + fk]);
        #pragma unroll
        for (int ni = 0; ni < 4; ++ni)
            b[ni] = *(const bf16x8*)(&Bs[cur][(wc * 64 + ni * 16 + fr) * 32 + fk]);
        #pragma unroll
        for (int mi = 0; mi < 4; ++mi)
            #pragma unroll
            for (int ni = 0; ni < 4; ++ni)
                acc[mi][ni] = __builtin_amdgcn_mfma_f32_16x16x32_bf16(a[mi], b[ni], acc[mi][ni], 0, 0, 0);
        __syncthreads();
        cur ^= 1;
    }

    const int cl = lane & 15;
    const int rq = (lane >> 4) * 4;
    #pragma unroll
    for (int mi = 0; mi < 4; ++mi) {
        #pragma unroll
        for (int ni = 0; ni < 4; ++ni) {
            int col = n0 + wc * 64 + ni * 16 + cl;
            #pragma unroll
            for (int rr = 0; rr < 4; ++rr) {
                int row = m0 + wr * 64 + mi * 16 + rq + rr;
                size_t idx = (size_t)row * N + col;
                float v = acc[mi][ni][rr];
                if (MODE == 2)      C[idx] = v + bias[col];
                else                C[idx] = v;
            }
        }
    }
}

// ---------------- MFMA GEMM 64x64, BK=64, 2-phase double-buffered ----------------
template <int MODE>
__global__ __launch_bounds__(256) void gemm64(const u16* __restrict__ A,
                                              const u16* __restrict__ B,
                                              float* __restrict__ C,
                                              int M, int N, int K,
                                              int nbx, int swzq) {
    __shared__ u16 As[2][64 * 64];
    __shared__ u16 Bs[2][64 * 64];
    const int tid = threadIdx.x;
    const int wave = tid >> 6;
    const int lane = tid & 63;
    int lin = blockIdx.x;
    if (swzq) lin = (lin & 7) * swzq + (lin >> 3);
    const int m0 = (lin % nbx) * 64;
    const int n0 = (lin / nbx) * 64;
    const int wr = wave >> 1, wc = wave & 1;
    f32x4 acc[2][2] = {};

    const int srow = lane >> 3;
    const int scol = (lane & 7) * 8;

    auto stage = [&](int buf, int k0) {
        #pragma unroll
        for (int i = 0; i < 4; ++i) {
            int c = wave * 4 + i;
            const u16* src;
            u16* dst;
            if (c < 8) {
                int row = c * 8 + srow;
                src = A + (size_t)(m0 + row) * K + k0 + scol;
                dst = &As[buf][c * 512];
            } else {
                int cc = c - 8;
                int row = cc * 8 + srow;
                src = B + (size_t)(n0 + row) * K + k0 + scol;
                dst = &Bs[buf][cc * 512];
            }
            __builtin_amdgcn_global_load_lds((const __attribute__((address_space(1))) void*)src,
                                             (__attribute__((address_space(3))) void*)dst,
                                             16, 0, 0);
        }
    };

    const int nt = K / 64;
    stage(0, 0);
    __syncthreads();
    int cur = 0;
    for (int t = 0; t < nt; ++t) {
        if (t + 1 < nt) stage(cur ^ 1, (t + 1) * 64);
        const int fr = lane & 15;
        const int fk = (lane >> 4) * 8;
        bf16x8 a[2][2], b[2][2];
        #pragma unroll
        for (int ki = 0; ki < 2; ++ki) {
            #pragma unroll
            for (int mi = 0; mi < 2; ++mi)
                a[ki][mi] = *(const bf16x8*)(&As[cur][(wr * 32 + mi * 16 + fr) * 64 + ki * 32 + fk]);
            #pragma unroll
            for (int ni = 0; ni < 2; ++ni)
                b[ki][ni] = *(const bf16x8*)(&Bs[cur][(wc * 32 + ni * 16 + fr) * 64 + ki * 32 + fk]);
        }
        #pragma unroll
        for (int ki = 0; ki < 2; ++ki)
            #pragma unroll
            for (int mi = 0; mi < 2; ++mi)
                #pragma unroll
                for (int ni = 0; ni < 2; ++ni)
                    acc[mi][ni] = __builtin_amdgcn_mfma_f32_16x16x32_bf16(a[ki][mi], b[ki][ni], acc[mi][ni], 0, 0, 0);
        __syncthreads();
        cur ^= 1;
    }

    const int cl = lane & 15;
    const int rq = (lane >> 4) * 4;
    #pragma unroll
    for (int mi = 0; mi < 2; ++mi) {
        #pragma unroll
        for (int ni = 0; ni < 2; ++ni) {
            int col = n0 + wc * 32 + ni * 16 + cl;
            #pragma unroll
            for (int rr = 0; rr < 4; ++rr) {
                int row = m0 + wr * 32 + mi * 16 + rq + rr;
                size_t idx = (size_t)row * N + col;
                float v = acc[mi][ni][rr];
                if (MODE == 1)      C[idx] += v;
                else                C[idx] = v;
            }
        }
    }
}

// ---------------- fused conv+silu -> xproj (LDS-staged) -> dt+softplus (dtwT) ----------------
// block: 256 threads, 4 rows.
__global__ __launch_bounds__(256) void conv_xproj_dt(const float* __restrict__ xz,
                                                     const float* __restrict__ cw,
                                                     const float* __restrict__ cb,
                                                     const float* __restrict__ xw,
                                                     const float* __restrict__ dtwT,
                                                     const float* __restrict__ dtb,
                                                     float* __restrict__ xc,
                                                     float* __restrict__ dbc,
                                                     float* __restrict__ delta) {
    __shared__ float sxc[4 * 1024];
    __shared__ float sxw[64 * 132];    // pad 132: bank group (4n+k)%32, fully spread
    __shared__ float sdbc[4][64];
    int t = threadIdx.x;
    int m0 = blockIdx.x * 4;
    // phase 0: conv + silu for 4 rows into LDS + global xc
    #pragma unroll
    for (int i = 0; i < 16; ++i) {
        int idx = t + i * 256;            // 0..4095
        int mi = idx >> 10, d = idx & 1023;
        int m = m0 + mi;
        int l = m & (L_ - 1);
        float acc = cb[d];
        #pragma unroll
        for (int j = 0; j < 4; ++j) {
            int ll = l - 3 + j;
            if (ll >= 0) acc = fmaf(cw[d * 4 + j], xz[(size_t)(m - 3 + j) * (2 * DINNER_) + d], acc);
        }
        float sv = acc / (1.0f + __expf(-acc));
        sxc[mi * 1024 + d] = sv;
        xc[(size_t)m * DINNER_ + d] = sv;
    }
    // phase 1: xproj with xw staged through LDS in 8 chunks of k=128
    const int n = t & 63, mi = t >> 6;
    float acc = 0.f;
    for (int kc = 0; kc < 8; ++kc) {
        __syncthreads();                  // protect sxw (and order sxc on first iter)
        #pragma unroll
        for (int i = 0; i < 8; ++i) {
            int f = t + i * 256;          // 0..2047 float4s
            int row = f >> 5, col4 = f & 31;
            float4 v = *(const float4*)(xw + (size_t)row * DINNER_ + kc * 128 + col4 * 4);
            *(float4*)(&sxw[row * 132 + col4 * 4]) = v;
        }
        __syncthreads();
        #pragma unroll
        for (int k4 = 0; k4 < 32; ++k4) {
            float4 wv = *(const float4*)(&sxw[n * 132 + k4 * 4]);
            float4 xv = *(const float4*)(&sxc[mi * 1024 + kc * 128 + k4 * 4]);
            acc += wv.x * xv.x + wv.y * xv.y + wv.z * xv.z + wv.w * xv.w;
        }
    }
    sdbc[mi][n] = acc;
    dbc[(size_t)(m0 + mi) * 64 + n] = acc;
    __syncthreads();
    // phase 2: dt projection + softplus via transposed dtwT (coalesced float4)
    {
        int d0 = t * 4;
        float4 bias = *(const float4*)(dtb + d0);
        float am[4][4];
        #pragma unroll
        for (int m2 = 0; m2 < 4; ++m2) {
            am[m2][0] = bias.x; am[m2][1] = bias.y; am[m2][2] = bias.z; am[m2][3] = bias.w;
        }
        const float4* wT = (const float4*)dtwT;
        #pragma unroll
        for (int r = 0; r < 32; ++r) {
            float4 wv = wT[r * 256 + t];
            #pragma unroll
            for (int m2 = 0; m2 < 4; ++m2) {
                float s = sdbc[m2][r];
                am[m2][0] = fmaf(s, wv.x, am[m2][0]);
                am[m2][1] = fmaf(s, wv.y, am[m2][1]);
                am[m2][2] = fmaf(s, wv.z, am[m2][2]);
                am[m2][3] = fmaf(s, wv.w, am[m2][3]);
            }
        }
        #pragma unroll
        for (int m2 = 0; m2 < 4; ++m2) {
            float4 o;
            o.x = (am[m2][0] > 20.f) ? am[m2][0] : log1pf(__expf(am[m2][0]));
            o.y = (am[m2][1] > 20.f) ? am[m2][1] : log1pf(__expf(am[m2][1]));
            o.z = (am[m2][2] > 20.f) ? am[m2][2] : log1pf(__expf(am[m2][2]));
            o.w = (am[m2][3] > 20.f) ? am[m2][3] : log1pf(__expf(am[m2][3]));
            *(float4*)(delta + (size_t)(m0 + m2) * DINNER_ + d0) = o;
        }
    }
}

// ---------------- SSM pass 1: per-chunk local scan (h0=0) ----------------
__global__ __launch_bounds__(256) void ssm_part1(const float* __restrict__ delta,
                                                 const float* __restrict__ xc,
                                                 const float* __restrict__ dbc,
                                                 const float* __restrict__ A_log,
                                                 float* __restrict__ hfin,
                                                 float* __restrict__ sumd) {
    int tid = threadIdx.x;
    int d = blockIdx.x * 256 + tid;
    int c = blockIdx.y;
    int b = blockIdx.z;
    __shared__ float sB[CLEN][DSTATE_];
    {
        int l = tid >> 4, s = tid & 15;
        sB[l][s] = dbc[((size_t)(b * L_ + c * CLEN + l)) * 64 + DTRANK_ + s];
    }
    float A[16], h[16];
    {
        const float4* Ar = (const float4*)(A_log + (size_t)d * DSTATE_);
        #pragma unroll
        for (int i = 0; i < 4; ++i) {
            float4 al = Ar[i];
            A[i * 4 + 0] = -__expf(al.x); A[i * 4 + 1] = -__expf(al.y);
            A[i * 4 + 2] = -__expf(al.z); A[i * 4 + 3] = -__expf(al.w);
        }
    }
    #pragma unroll
    for (int s = 0; s < 16; ++s) h[s] = 0.f;
    __syncthreads();
    float sd = 0.f;
    size_t base = ((size_t)b * L_ + c * CLEN) * DINNER_ + d;
    #pragma unroll
    for (int l = 0; l < CLEN; ++l) {
        float dv = delta[base + (size_t)l * DINNER_];
        float xv = xc[base + (size_t)l * DINNER_];
        sd += dv;
        float dx = dv * xv;
        #pragma unroll
        for (int s = 0; s < 16; ++s) {
            float e = __expf(dv * A[s]);
            h[s] = fmaf(e, h[s], dx * sB[l][s]);
        }
    }
    float* hf = hfin + (((size_t)b * NCHUNK + c) * DINNER_ + d) * 16;
    #pragma unroll
    for (int i = 0; i < 4; ++i) {
        float4 v; v.x = h[i*4]; v.y = h[i*4+1]; v.z = h[i*4+2]; v.w = h[i*4+3];
        *(float4*)(hf + i * 4) = v;
    }
    sumd[((size_t)b * NCHUNK + c) * DINNER_ + d] = sd;
}

// ---------------- SSM pass 2: carry propagation across chunks ----------------
__global__ __launch_bounds__(256) void ssm_carry(const float* __restrict__ hfin,
                                                 const float* __restrict__ sumd,
                                                 const float* __restrict__ A_log,
                                                 float* __restrict__ h0buf) {
    int t = blockIdx.x * 256 + threadIdx.x;
    int s = t & 15;
    int dg = t >> 4;
    int d = dg & (DINNER_ - 1);
    int b = dg >> 10;
    float As = -__expf(A_log[(size_t)d * DSTATE_ + s]);
    float hc = 0.f;
    #pragma unroll 4
    for (int c = 0; c < NCHUNK; ++c) {
        size_t k = (((size_t)b * NCHUNK + c) * DINNER_ + d) * 16 + s;
        h0buf[k] = hc;
        float sdv = sumd[((size_t)b * NCHUNK + c) * DINNER_ + d];
        float hf = hfin[k];
        hc = fmaf(__expf(As * sdv), hc, hf);
    }
}

// ---------------- SSM pass 3: local scan w/ carry + y + gate -> ys(bf16) ----------------
__global__ __launch_bounds__(256) void ssm_part2(const float* __restrict__ delta,
                                                 const float* __restrict__ xc,
                                                 const float* __restrict__ dbc,
                                                 const float* __restrict__ xz,
                                                 const float* __restrict__ A_log,
                                                 const float* __restrict__ Dp,
                                                 const float* __restrict__ h0buf,
                                                 u16* __restrict__ ys) {
    int tid = threadIdx.x;
    int d = blockIdx.x * 256 + tid;
    int c = blockIdx.y;
    int b = blockIdx.z;
    __shared__ float sBC[CLEN][32];
    {
        int l = tid >> 5, j = tid & 31;
        sBC[l][j] = dbc[((size_t)(b * L_ + c * CLEN + l)) * 64 + DTRANK_ + j];
        int e1 = tid + 256;
        l = e1 >> 5; j = e1 & 31;
        sBC[l][j] = dbc[((size_t)(b * L_ + c * CLEN + l)) * 64 + DTRANK_ + j];
    }
    float A[16], h[16];
    {
        const float4* Ar = (const float4*)(A_log + (size_t)d * DSTATE_);
        #pragma unroll
        for (int i = 0; i < 4; ++i) {
            float4 al = Ar[i];
            A[i * 4 + 0] = -__expf(al.x); A[i * 4 + 1] = -__expf(al.y);
            A[i * 4 + 2] = -__expf(al.z); A[i * 4 + 3] = -__expf(al.w);
        }
        const float4* h0 = (const float4*)(h0buf + (((size_t)b * NCHUNK + c) * DINNER_ + d) * 16);
        #pragma unroll
        for (int i = 0; i < 4; ++i) {
            float4 v = h0[i];
            h[i * 4 + 0] = v.x; h[i * 4 + 1] = v.y; h[i * 4 + 2] = v.z; h[i * 4 + 3] = v.w;
        }
    }
    float Dval = Dp[d];
    __syncthreads();
    size_t base = ((size_t)b * L_ + c * CLEN) * DINNER_ + d;
    size_t zbase = ((size_t)b * L_ + c * CLEN) * (2 * DINNER_) + DINNER_ + d;
    #pragma unroll
    for (int l = 0; l < CLEN; ++l) {
        float dv = delta[base + (size_t)l * DINNER_];
        float xv = xc[base + (size_t)l * DINNER_];
        float zv = xz[zbase + (size_t)l * (2 * DINNER_)];
        float dx = dv * xv;
        float y = 0.f;
        #pragma unroll
        for (int s = 0; s < 16; ++s) {
            float e = __expf(dv * A[s]);
            h[s] = fmaf(e, h[s], dx * sBC[l][s]);
            y = fmaf(h[s], sBC[l][16 + s], y);
        }
        y = fmaf(Dval, xv, y);
        float sg = zv / (1.0f + __expf(-zv));
        ys[base + (size_t)l * DINNER_] = f2bf(y * sg);
    }
}

extern "C" void kernel_launch(void* const* d_in, const int* in_sizes, int n_in,
                              void* d_out, int out_size, void* d_ws, size_t ws_size,
                              hipStream_t stream) {
    const int*   x       = (const int*)d_in[0];
    const float* embed   = (const float*)d_in[1];
    const float* rms_w   = (const float*)d_in[2];
    const float* in_w    = (const float*)d_in[3];
    const float* conv_w  = (const float*)d_in[4];
    const float* conv_b  = (const float*)d_in[5];
    const float* xproj_w = (const float*)d_in[6];
    const float* dt_w    = (const float*)d_in[7];
    const float* dt_b    = (const float*)d_in[8];
    const float* A_log   = (const float*)d_in[9];
    const float* Dp      = (const float*)d_in[10];
    const float* out_w   = (const float*)d_in[11];
    const float* ln_g    = (const float*)d_in[12];
    const float* ln_b    = (const float*)d_in[13];
    const float* head_w  = (const float*)d_in[14];
    const float* head_b  = (const float*)d_in[15];
    float* out = (float*)d_out;

    char* p = (char*)d_ws;
    auto take = [&](size_t n) { char* q = p; p += (n + 255) & ~(size_t)255; return q; };
    float* h    = (float*)take(2048ull * 512 * 4);
    u16*   r_bf = (u16*)  take(2048ull * 512 * 2);
    float* xz   = (float*)take(2048ull * 2048 * 4);
    float* xc   = (float*)take(2048ull * 1024 * 4);
    float* dbc  = (float*)take(2048ull * 64 * 4);
    float* dlt  = (float*)take(2048ull * 1024 * 4);
    u16*   ys   = (u16*)  take(2048ull * 1024 * 2);
    u16*   hn   = (u16*)  take(2048ull * 512 * 2);
    u16*   win  = (u16*)  take(2ull * 2048 * 512 * 2);
    u16*   wout = (u16*)  take(2ull * 512 * 1024 * 2);
    u16*   whd  = (u16*)  take(32000ull * 512 * 2);
    float* dtwT = (float*)take(2ull * 32 * 1024 * 4);
    float* hfin = (float*)take((size_t)B_ * NCHUNK * DINNER_ * 16 * 4);
    float* h0b  = (float*)take((size_t)B_ * NCHUNK * DINNER_ * 16 * 4);
    float* sumd = (float*)take((size_t)B_ * NCHUNK * DINNER_ * 4);

    prep<<<19840, 256, 0, stream>>>(in_w, out_w, head_w, dt_w, x, embed, rms_w,
                                    win, wout, whd, dtwT, h, r_bf);

    for (int l = 0; l < 2; ++l) {
        if (l > 0) rmsnorm_bf16<<<512, 256, 0, stream>>>(h, rms_w + l * DIM_, r_bf);
        gemm64<0><<<1024, 256, 0, stream>>>(r_bf, win + (size_t)l * 2048 * 512, xz, 2048, 2048, 512, 32, 128);
        conv_xproj_dt<<<512, 256, 0, stream>>>(xz, conv_w + l * DINNER_ * 4, conv_b + l * DINNER_,
                                               xproj_w + (size_t)l * 64 * 1024,
                                               dtwT + (size_t)l * 32 * 1024, dt_b + l * DINNER_,
                                               xc, dbc, dlt);
        ssm_part1<<<dim3(4, NCHUNK, B_), 256, 0, stream>>>(dlt, xc, dbc, A_log + (size_t)l * DINNER_ * DSTATE_, hfin, sumd);
        ssm_carry<<<128, 256, 0, stream>>>(hfin, sumd, A_log + (size_t)l * DINNER_ * DSTATE_, h0b);
        ssm_part2<<<dim3(4, NCHUNK, B_), 256, 0, stream>>>(dlt, xc, dbc, xz, A_log + (size_t)l * DINNER_ * DSTATE_,
                                                           Dp + l * DINNER_, h0b, ys);
        gemm64<1><<<256, 256, 0, stream>>>(ys, wout + (size_t)l * 512 * 1024, h, 2048, 512, 1024, 32, 32);
    }

    layernorm_bf16<<<512, 256, 0, stream>>>(h, ln_g, ln_b, hn);
    gemm_bt<2><<<4000, 256, 0, stream>>>(hn, whd, out, head_b, 2048, VOCAB_, 512, 16, 500);
}

// Round 6
// 378.261 us; speedup vs baseline: 2.9233x; 1.0682x over previous
//
#include <hip/hip_runtime.h>

typedef unsigned short u16;
typedef __attribute__((ext_vector_type(8))) __bf16 bf16x8;
typedef __attribute__((ext_vector_type(4))) float f32x4;

#define B_ 2
#define L_ 1024
#define DIM_ 512
#define DINNER_ 1024
#define DSTATE_ 16
#define DTRANK_ 32
#define VOCAB_ 32000
#define NCHUNK 64
#define CLEN 16

__device__ __forceinline__ u16 f2bf(float f) {
    union { float f; unsigned u; } x; x.f = f;
    unsigned r = x.u + 0x7FFFu + ((x.u >> 16) & 1u);
    return (u16)(r >> 16);
}

// ---------------- prep: weight bf16 conversions + dtw transpose + embed+rms ----------------
__global__ __launch_bounds__(256) void prep(const float* __restrict__ in_w,
                                            const float* __restrict__ out_w,
                                            const float* __restrict__ head_w,
                                            const float* __restrict__ dt_w,
                                            const int* __restrict__ x,
                                            const float* __restrict__ embed,
                                            const float* __restrict__ rw,
                                            u16* __restrict__ win,
                                            u16* __restrict__ wout,
                                            u16* __restrict__ whd,
                                            float* __restrict__ dtwT,
                                            float* __restrict__ h,
                                            u16* __restrict__ rbf) {
    int bk = blockIdx.x;
    int t = threadIdx.x;
    if (bk < 19072) {
        const int n1 = 524288;
        const int n2 = n1 + 262144;
        int i = bk * 256 + t;
        const float4* s; ushort4* d; int j;
        if (i < n1)      { s = (const float4*)in_w;   d = (ushort4*)win;  j = i; }
        else if (i < n2) { s = (const float4*)out_w;  d = (ushort4*)wout; j = i - n1; }
        else             { s = (const float4*)head_w; d = (ushort4*)whd;  j = i - n2; }
        float4 v = s[j];
        ushort4 o; o.x = f2bf(v.x); o.y = f2bf(v.y); o.z = f2bf(v.z); o.w = f2bf(v.w);
        d[j] = o;
    } else if (bk < 19328) {
        int bb = bk - 19072;
        int l = bb >> 7;
        int e = (bb & 127) * 256 + t;
        int r = e >> 10, d = e & 1023;
        dtwT[(size_t)l * 32768 + r * 1024 + d] = dt_w[(size_t)l * 32768 + d * 32 + r];
    } else {
        int wave = t >> 6, lane = t & 63;
        int row = (bk - 19328) * 4 + wave;
        int tok = x[row];
        const float4* s = (const float4*)(embed + (size_t)tok * DIM_);
        float4 v0 = s[lane], v1 = s[lane + 64];
        float4* hd = (float4*)(h + (size_t)row * DIM_);
        hd[lane] = v0;
        hd[lane + 64] = v1;
        float ss = v0.x*v0.x + v0.y*v0.y + v0.z*v0.z + v0.w*v0.w
                 + v1.x*v1.x + v1.y*v1.y + v1.z*v1.z + v1.w*v1.w;
        for (int m = 1; m < 64; m <<= 1) ss += __shfl_xor(ss, m);
        float rms = rsqrtf(ss * (1.0f / DIM_) + 1e-5f);
        const float4* w4 = (const float4*)rw;
        float4 w0 = w4[lane], w1 = w4[lane + 64];
        u16* o = rbf + (size_t)row * DIM_;
        ushort4 a, b;
        a.x = f2bf(v0.x * rms * w0.x); a.y = f2bf(v0.y * rms * w0.y);
        a.z = f2bf(v0.z * rms * w0.z); a.w = f2bf(v0.w * rms * w0.w);
        b.x = f2bf(v1.x * rms * w1.x); b.y = f2bf(v1.y * rms * w1.y);
        b.z = f2bf(v1.z * rms * w1.z); b.w = f2bf(v1.w * rms * w1.w);
        *(ushort4*)(o + lane * 4) = a;
        *(ushort4*)(o + 256 + lane * 4) = b;
    }
}

// ---------------- RMSNorm -> bf16 ----------------
__global__ __launch_bounds__(256) void rmsnorm_bf16(const float* __restrict__ h,
                                                    const float* __restrict__ w,
                                                    u16* __restrict__ out) {
    int wave = threadIdx.x >> 6, lane = threadIdx.x & 63;
    int row = blockIdx.x * 4 + wave;
    const float4* r4 = (const float4*)(h + (size_t)row * DIM_);
    float4 v0 = r4[lane], v1 = r4[lane + 64];
    float ss = v0.x*v0.x + v0.y*v0.y + v0.z*v0.z + v0.w*v0.w
             + v1.x*v1.x + v1.y*v1.y + v1.z*v1.z + v1.w*v1.w;
    for (int m = 1; m < 64; m <<= 1) ss += __shfl_xor(ss, m);
    float rms = rsqrtf(ss * (1.0f / DIM_) + 1e-5f);
    const float4* w4 = (const float4*)w;
    float4 w0 = w4[lane], w1 = w4[lane + 64];
    u16* o = out + (size_t)row * DIM_;
    ushort4 a, b;
    a.x = f2bf(v0.x * rms * w0.x); a.y = f2bf(v0.y * rms * w0.y);
    a.z = f2bf(v0.z * rms * w0.z); a.w = f2bf(v0.w * rms * w0.w);
    b.x = f2bf(v1.x * rms * w1.x); b.y = f2bf(v1.y * rms * w1.y);
    b.z = f2bf(v1.z * rms * w1.z); b.w = f2bf(v1.w * rms * w1.w);
    *(ushort4*)(o + lane * 4) = a;
    *(ushort4*)(o + 256 + lane * 4) = b;
}

// ---------------- LayerNorm -> bf16 ----------------
__global__ __launch_bounds__(256) void layernorm_bf16(const float* __restrict__ h,
                                                      const float* __restrict__ g,
                                                      const float* __restrict__ bta,
                                                      u16* __restrict__ out) {
    int wave = threadIdx.x >> 6, lane = threadIdx.x & 63;
    int row = blockIdx.x * 4 + wave;
    const float4* r4 = (const float4*)(h + (size_t)row * DIM_);
    float4 v0 = r4[lane], v1 = r4[lane + 64];
    float s = v0.x + v0.y + v0.z + v0.w + v1.x + v1.y + v1.z + v1.w;
    float ss = v0.x*v0.x + v0.y*v0.y + v0.z*v0.z + v0.w*v0.w
             + v1.x*v1.x + v1.y*v1.y + v1.z*v1.z + v1.w*v1.w;
    for (int m = 1; m < 64; m <<= 1) { s += __shfl_xor(s, m); ss += __shfl_xor(ss, m); }
    float mu = s * (1.0f / DIM_);
    float var = ss * (1.0f / DIM_) - mu * mu;
    float rs = rsqrtf(var + 1e-5f);
    const float4* g4 = (const float4*)g;
    const float4* b4 = (const float4*)bta;
    float4 g0 = g4[lane], g1 = g4[lane + 64];
    float4 b0 = b4[lane], b1 = b4[lane + 64];
    u16* o = out + (size_t)row * DIM_;
    ushort4 a, b;
    a.x = f2bf((v0.x - mu) * rs * g0.x + b0.x); a.y = f2bf((v0.y - mu) * rs * g0.y + b0.y);
    a.z = f2bf((v0.z - mu) * rs * g0.z + b0.z); a.w = f2bf((v0.w - mu) * rs * g0.w + b0.w);
    b.x = f2bf((v1.x - mu) * rs * g1.x + b1.x); b.y = f2bf((v1.y - mu) * rs * g1.y + b1.y);
    b.z = f2bf((v1.z - mu) * rs * g1.z + b1.z); b.w = f2bf((v1.w - mu) * rs * g1.w + b1.w);
    *(ushort4*)(o + lane * 4) = a;
    *(ushort4*)(o + 256 + lane * 4) = b;
}

// ---------------- MFMA GEMM 128x128, BK=64, dbuf, XOR-swizzled LDS ----------------
// MODE 0: C = acc ; MODE 2: C = acc + bias[col]
template <int MODE>
__global__ __launch_bounds__(256) void gemm_bt(const u16* __restrict__ A,
                                               const u16* __restrict__ B,
                                               float* __restrict__ C,
                                               const float* __restrict__ bias,
                                               int M, int N, int K,
                                               int nbx, int swzq) {
    __shared__ u16 As[2][128 * 64];
    __shared__ u16 Bs[2][128 * 64];
    const int tid = threadIdx.x;
    const int wave = tid >> 6;
    const int lane = tid & 63;
    int lin = blockIdx.x;
    if (swzq) lin = (lin & 7) * swzq + (lin >> 3);
    const int m0 = (lin % nbx) * 128;
    const int n0 = (lin / nbx) * 128;
    const int wr = wave >> 1, wc = wave & 1;
    f32x4 acc[4][4] = {};

    // stage: 32 chunks of 1KB (8 rows x 64 cols bf16); wave handles 8.
    // source col pre-swizzled so that swizzled ds_read below sees linear data.
    const int crow = lane >> 3;                        // row within chunk
    const int scol = ((lane & 7) ^ crow) * 8;          // swizzled col (u16)

    auto stage = [&](int buf, int k0) {
        #pragma unroll
        for (int i = 0; i < 8; ++i) {
            int c = wave * 8 + i;                      // 0..31
            const u16* src;
            u16* dst;
            if (c < 16) {
                int row = c * 8 + crow;
                src = A + (size_t)(m0 + row) * K + k0 + scol;
                dst = &As[buf][c * 512];
            } else {
                int cc = c - 16;
                int row = cc * 8 + crow;
                src = B + (size_t)(n0 + row) * K + k0 + scol;
                dst = &Bs[buf][cc * 512];
            }
            __builtin_amdgcn_global_load_lds((const __attribute__((address_space(1))) void*)src,
                                             (__attribute__((address_space(3))) void*)dst,
                                             16, 0, 0);
        }
    };

    const int nt = K / 64;
    stage(0, 0);
    __syncthreads();
    int cur = 0;
    const int fr = lane & 15;
    const int q = lane >> 4;
    for (int t = 0; t < nt; ++t) {
        if (t + 1 < nt) stage(cur ^ 1, (t + 1) * 64);
        bf16x8 a[2][4], b[2][4];
        #pragma unroll
        for (int ki = 0; ki < 2; ++ki) {
            #pragma unroll
            for (int mi = 0; mi < 4; ++mi) {
                int row = wr * 64 + mi * 16 + fr;
                a[ki][mi] = *(const bf16x8*)(&As[cur][row * 64 + ((((ki << 2) + q) ^ (fr & 7)) * 8)]);
            }
            #pragma unroll
            for (int ni = 0; ni < 4; ++ni) {
                int row = wc * 64 + ni * 16 + fr;
                b[ki][ni] = *(const bf16x8*)(&Bs[cur][row * 64 + ((((ki << 2) + q) ^ (fr & 7)) * 8)]);
            }
        }
        #pragma unroll
        for (int ki = 0; ki < 2; ++ki)
            #pragma unroll
            for (int mi = 0; mi < 4; ++mi)
                #pragma unroll
                for (int ni = 0; ni < 4; ++ni)
                    acc[mi][ni] = __builtin_amdgcn_mfma_f32_16x16x32_bf16(a[ki][mi], b[ki][ni], acc[mi][ni], 0, 0, 0);
        __syncthreads();
        cur ^= 1;
    }

    const int cl = lane & 15;
    const int rq = (lane >> 4) * 4;
    #pragma unroll
    for (int mi = 0; mi < 4; ++mi) {
        #pragma unroll
        for (int ni = 0; ni < 4; ++ni) {
            int col = n0 + wc * 64 + ni * 16 + cl;
            #pragma unroll
            for (int rr = 0; rr < 4; ++rr) {
                int row = m0 + wr * 64 + mi * 16 + rq + rr;
                size_t idx = (size_t)row * N + col;
                float v = acc[mi][ni][rr];
                if (MODE == 2)      C[idx] = v + bias[col];
                else                C[idx] = v;
            }
        }
    }
}

// ---------------- MFMA GEMM 64x64, BK=64, dbuf, XOR-swizzled LDS ----------------
template <int MODE>
__global__ __launch_bounds__(256) void gemm64(const u16* __restrict__ A,
                                              const u16* __restrict__ B,
                                              float* __restrict__ C,
                                              int M, int N, int K,
                                              int nbx, int swzq) {
    __shared__ u16 As[2][64 * 64];
    __shared__ u16 Bs[2][64 * 64];
    const int tid = threadIdx.x;
    const int wave = tid >> 6;
    const int lane = tid & 63;
    int lin = blockIdx.x;
    if (swzq) lin = (lin & 7) * swzq + (lin >> 3);
    const int m0 = (lin % nbx) * 64;
    const int n0 = (lin / nbx) * 64;
    const int wr = wave >> 1, wc = wave & 1;
    f32x4 acc[2][2] = {};

    const int crow = lane >> 3;
    const int scol = ((lane & 7) ^ crow) * 8;

    auto stage = [&](int buf, int k0) {
        #pragma unroll
        for (int i = 0; i < 4; ++i) {
            int c = wave * 4 + i;                      // 0..15
            const u16* src;
            u16* dst;
            if (c < 8) {
                int row = c * 8 + crow;
                src = A + (size_t)(m0 + row) * K + k0 + scol;
                dst = &As[buf][c * 512];
            } else {
                int cc = c - 8;
                int row = cc * 8 + crow;
                src = B + (size_t)(n0 + row) * K + k0 + scol;
                dst = &Bs[buf][cc * 512];
            }
            __builtin_amdgcn_global_load_lds((const __attribute__((address_space(1))) void*)src,
                                             (__attribute__((address_space(3))) void*)dst,
                                             16, 0, 0);
        }
    };

    const int nt = K / 64;
    stage(0, 0);
    __syncthreads();
    int cur = 0;
    const int fr = lane & 15;
    const int q = lane >> 4;
    for (int t = 0; t < nt; ++t) {
        if (t + 1 < nt) stage(cur ^ 1, (t + 1) * 64);
        bf16x8 a[2][2], b[2][2];
        #pragma unroll
        for (int ki = 0; ki < 2; ++ki) {
            #pragma unroll
            for (int mi = 0; mi < 2; ++mi) {
                int row = wr * 32 + mi * 16 + fr;
                a[ki][mi] = *(const bf16x8*)(&As[cur][row * 64 + ((((ki << 2) + q) ^ (fr & 7)) * 8)]);
            }
            #pragma unroll
            for (int ni = 0; ni < 2; ++ni) {
                int row = wc * 32 + ni * 16 + fr;
                b[ki][ni] = *(const bf16x8*)(&Bs[cur][row * 64 + ((((ki << 2) + q) ^ (fr & 7)) * 8)]);
            }
        }
        #pragma unroll
        for (int ki = 0; ki < 2; ++ki)
            #pragma unroll
            for (int mi = 0; mi < 2; ++mi)
                #pragma unroll
                for (int ni = 0; ni < 2; ++ni)
                    acc[mi][ni] = __builtin_amdgcn_mfma_f32_16x16x32_bf16(a[ki][mi], b[ki][ni], acc[mi][ni], 0, 0, 0);
        __syncthreads();
        cur ^= 1;
    }

    const int cl = lane & 15;
    const int rq = (lane >> 4) * 4;
    #pragma unroll
    for (int mi = 0; mi < 2; ++mi) {
        #pragma unroll
        for (int ni = 0; ni < 2; ++ni) {
            int col = n0 + wc * 32 + ni * 16 + cl;
            #pragma unroll
            for (int rr = 0; rr < 4; ++rr) {
                int row = m0 + wr * 32 + mi * 16 + rq + rr;
                size_t idx = (size_t)row * N + col;
                float v = acc[mi][ni][rr];
                if (MODE == 1)      C[idx] += v;
                else                C[idx] = v;
            }
        }
    }
}

// ---------------- fused conv+silu -> xproj -> dt+softplus (8 rows/block) ----------------
// thread = (n = t&63, kg = t>>6): xproj accumulates 8 rows per xw read.
__global__ __launch_bounds__(256) void conv_xproj_dt(const float* __restrict__ xz,
                                                     const float* __restrict__ cw,
                                                     const float* __restrict__ cb,
                                                     const float* __restrict__ xw,
                                                     const float* __restrict__ dtwT,
                                                     const float* __restrict__ dtb,
                                                     float* __restrict__ xc,
                                                     float* __restrict__ dbc,
                                                     float* __restrict__ delta) {
    __shared__ float sxc[8 * 1024];       // 32 KB
    __shared__ float sxw[64 * 132];       // 33 KB (33-slot stride: full spread for b128)
    __shared__ float sred[4][8][68];      // kg partials
    __shared__ float sdbc[8][64];
    int t = threadIdx.x;
    int m0 = blockIdx.x * 8;
    // phase 0: conv + silu
    #pragma unroll
    for (int i = 0; i < 32; ++i) {
        int idx = t + i * 256;            // 0..8191
        int mi = idx >> 10, d = idx & 1023;
        int m = m0 + mi;
        int l = m & (L_ - 1);
        float acc = cb[d];
        #pragma unroll
        for (int j = 0; j < 4; ++j) {
            int ll = l - 3 + j;
            if (ll >= 0) acc = fmaf(cw[d * 4 + j], xz[(size_t)(m - 3 + j) * (2 * DINNER_) + d], acc);
        }
        float sv = acc / (1.0f + __expf(-acc));
        sxc[mi * 1024 + d] = sv;
        xc[(size_t)m * DINNER_ + d] = sv;
    }
    // phase 1: xproj; kc = k-chunk of 128, thread covers k4 in [kg*8, kg*8+8)
    const int n = t & 63, kg = t >> 6;
    float acc8[8] = {};
    for (int kc = 0; kc < 8; ++kc) {
        __syncthreads();
        #pragma unroll
        for (int i = 0; i < 8; ++i) {
            int f = t + i * 256;
            int row = f >> 5, col4 = f & 31;
            *(float4*)(&sxw[row * 132 + col4 * 4]) =
                *(const float4*)(xw + (size_t)row * DINNER_ + kc * 128 + col4 * 4);
        }
        __syncthreads();
        #pragma unroll
        for (int k4i = 0; k4i < 8; ++k4i) {
            int k4 = kg * 8 + k4i;
            float4 wv = *(const float4*)(&sxw[n * 132 + k4 * 4]);
            #pragma unroll
            for (int mi = 0; mi < 8; ++mi) {
                float4 xv = *(const float4*)(&sxc[mi * 1024 + kc * 128 + k4 * 4]);  // broadcast
                acc8[mi] += wv.x * xv.x + wv.y * xv.y + wv.z * xv.z + wv.w * xv.w;
            }
        }
    }
    #pragma unroll
    for (int mi = 0; mi < 8; ++mi) sred[kg][mi][n] = acc8[mi];
    __syncthreads();
    // reduce over kg: 512 outputs, thread handles o = t and t+256
    #pragma unroll
    for (int rep = 0; rep < 2; ++rep) {
        int o = t + rep * 256;
        int mi = o >> 6, n2 = o & 63;
        float v = sred[0][mi][n2] + sred[1][mi][n2] + sred[2][mi][n2] + sred[3][mi][n2];
        sdbc[mi][n2] = v;
        dbc[(size_t)(m0 + mi) * 64 + n2] = v;
    }
    __syncthreads();
    // phase 2: dt projection + softplus via dtwT (coalesced)
    {
        int d0 = t * 4;
        float4 bias = *(const float4*)(dtb + d0);
        float4 am[8];
        #pragma unroll
        for (int mi = 0; mi < 8; ++mi) am[mi] = bias;
        const float4* wT = (const float4*)dtwT;
        #pragma unroll
        for (int r = 0; r < 32; ++r) {
            float4 wv = wT[r * 256 + t];
            #pragma unroll
            for (int mi = 0; mi < 8; ++mi) {
                float s = sdbc[mi][r];
                am[mi].x = fmaf(s, wv.x, am[mi].x);
                am[mi].y = fmaf(s, wv.y, am[mi].y);
                am[mi].z = fmaf(s, wv.z, am[mi].z);
                am[mi].w = fmaf(s, wv.w, am[mi].w);
            }
        }
        #pragma unroll
        for (int mi = 0; mi < 8; ++mi) {
            float4 o;
            o.x = (am[mi].x > 20.f) ? am[mi].x : log1pf(__expf(am[mi].x));
            o.y = (am[mi].y > 20.f) ? am[mi].y : log1pf(__expf(am[mi].y));
            o.z = (am[mi].z > 20.f) ? am[mi].z : log1pf(__expf(am[mi].z));
            o.w = (am[mi].w > 20.f) ? am[mi].w : log1pf(__expf(am[mi].w));
            *(float4*)(delta + (size_t)(m0 + mi) * DINNER_ + d0) = o;
        }
    }
}

// ---------------- SSM pass 1: per-chunk local scan (h0=0) ----------------
__global__ __launch_bounds__(256) void ssm_part1(const float* __restrict__ delta,
                                                 const float* __restrict__ xc,
                                                 const float* __restrict__ dbc,
                                                 const float* __restrict__ A_log,
                                                 float* __restrict__ hfin,
                                                 float* __restrict__ sumd) {
    int tid = threadIdx.x;
    int d = blockIdx.x * 256 + tid;
    int c = blockIdx.y;
    int b = blockIdx.z;
    __shared__ float sB[CLEN][DSTATE_];
    {
        int l = tid >> 4, s = tid & 15;
        sB[l][s] = dbc[((size_t)(b * L_ + c * CLEN + l)) * 64 + DTRANK_ + s];
    }
    float A[16], h[16];
    {
        const float4* Ar = (const float4*)(A_log + (size_t)d * DSTATE_);
        #pragma unroll
        for (int i = 0; i < 4; ++i) {
            float4 al = Ar[i];
            A[i * 4 + 0] = -__expf(al.x); A[i * 4 + 1] = -__expf(al.y);
            A[i * 4 + 2] = -__expf(al.z); A[i * 4 + 3] = -__expf(al.w);
        }
    }
    #pragma unroll
    for (int s = 0; s < 16; ++s) h[s] = 0.f;
    __syncthreads();
    float sd = 0.f;
    size_t base = ((size_t)b * L_ + c * CLEN) * DINNER_ + d;
    #pragma unroll
    for (int l = 0; l < CLEN; ++l) {
        float dv = delta[base + (size_t)l * DINNER_];
        float xv = xc[base + (size_t)l * DINNER_];
        sd += dv;
        float dx = dv * xv;
        #pragma unroll
        for (int s = 0; s < 16; ++s) {
            float e = __expf(dv * A[s]);
            h[s] = fmaf(e, h[s], dx * sB[l][s]);
        }
    }
    float* hf = hfin + (((size_t)b * NCHUNK + c) * DINNER_ + d) * 16;
    #pragma unroll
    for (int i = 0; i < 4; ++i) {
        float4 v; v.x = h[i*4]; v.y = h[i*4+1]; v.z = h[i*4+2]; v.w = h[i*4+3];
        *(float4*)(hf + i * 4) = v;
    }
    sumd[((size_t)b * NCHUNK + c) * DINNER_ + d] = sd;
}

// ---------------- SSM pass 2: carry propagation across chunks ----------------
__global__ __launch_bounds__(256) void ssm_carry(const float* __restrict__ hfin,
                                                 const float* __restrict__ sumd,
                                                 const float* __restrict__ A_log,
                                                 float* __restrict__ h0buf) {
    int t = blockIdx.x * 256 + threadIdx.x;
    int s = t & 15;
    int dg = t >> 4;
    int d = dg & (DINNER_ - 1);
    int b = dg >> 10;
    float As = -__expf(A_log[(size_t)d * DSTATE_ + s]);
    float hc = 0.f;
    #pragma unroll 4
    for (int c = 0; c < NCHUNK; ++c) {
        size_t k = (((size_t)b * NCHUNK + c) * DINNER_ + d) * 16 + s;
        h0buf[k] = hc;
        float sdv = sumd[((size_t)b * NCHUNK + c) * DINNER_ + d];
        float hf = hfin[k];
        hc = fmaf(__expf(As * sdv), hc, hf);
    }
}

// ---------------- SSM pass 3: local scan w/ carry + y + gate -> ys(bf16) ----------------
__global__ __launch_bounds__(256) void ssm_part2(const float* __restrict__ delta,
                                                 const float* __restrict__ xc,
                                                 const float* __restrict__ dbc,
                                                 const float* __restrict__ xz,
                                                 const float* __restrict__ A_log,
                                                 const float* __restrict__ Dp,
                                                 const float* __restrict__ h0buf,
                                                 u16* __restrict__ ys) {
    int tid = threadIdx.x;
    int d = blockIdx.x * 256 + tid;
    int c = blockIdx.y;
    int b = blockIdx.z;
    __shared__ float sBC[CLEN][32];
    {
        int l = tid >> 5, j = tid & 31;
        sBC[l][j] = dbc[((size_t)(b * L_ + c * CLEN + l)) * 64 + DTRANK_ + j];
        int e1 = tid + 256;
        l = e1 >> 5; j = e1 & 31;
        sBC[l][j] = dbc[((size_t)(b * L_ + c * CLEN + l)) * 64 + DTRANK_ + j];
    }
    float A[16], h[16];
    {
        const float4* Ar = (const float4*)(A_log + (size_t)d * DSTATE_);
        #pragma unroll
        for (int i = 0; i < 4; ++i) {
            float4 al = Ar[i];
            A[i * 4 + 0] = -__expf(al.x); A[i * 4 + 1] = -__expf(al.y);
            A[i * 4 + 2] = -__expf(al.z); A[i * 4 + 3] = -__expf(al.w);
        }
        const float4* h0 = (const float4*)(h0buf + (((size_t)b * NCHUNK + c) * DINNER_ + d) * 16);
        #pragma unroll
        for (int i = 0; i < 4; ++i) {
            float4 v = h0[i];
            h[i * 4 + 0] = v.x; h[i * 4 + 1] = v.y; h[i * 4 + 2] = v.z; h[i * 4 + 3] = v.w;
        }
    }
    float Dval = Dp[d];
    __syncthreads();
    size_t base = ((size_t)b * L_ + c * CLEN) * DINNER_ + d;
    size_t zbase = ((size_t)b * L_ + c * CLEN) * (2 * DINNER_) + DINNER_ + d;
    #pragma unroll
    for (int l = 0; l < CLEN; ++l) {
        float dv = delta[base + (size_t)l * DINNER_];
        float xv = xc[base + (size_t)l * DINNER_];
        float zv = xz[zbase + (size_t)l * (2 * DINNER_)];
        float dx = dv * xv;
        float y = 0.f;
        #pragma unroll
        for (int s = 0; s < 16; ++s) {
            float e = __expf(dv * A[s]);
            h[s] = fmaf(e, h[s], dx * sBC[l][s]);
            y = fmaf(h[s], sBC[l][16 + s], y);
        }
        y = fmaf(Dval, xv, y);
        float sg = zv / (1.0f + __expf(-zv));
        ys[base + (size_t)l * DINNER_] = f2bf(y * sg);
    }
}

extern "C" void kernel_launch(void* const* d_in, const int* in_sizes, int n_in,
                              void* d_out, int out_size, void* d_ws, size_t ws_size,
                              hipStream_t stream) {
    const int*   x       = (const int*)d_in[0];
    const float* embed   = (const float*)d_in[1];
    const float* rms_w   = (const float*)d_in[2];
    const float* in_w    = (const float*)d_in[3];
    const float* conv_w  = (const float*)d_in[4];
    const float* conv_b  = (const float*)d_in[5];
    const float* xproj_w = (const float*)d_in[6];
    const float* dt_w    = (const float*)d_in[7];
    const float* dt_b    = (const float*)d_in[8];
    const float* A_log   = (const float*)d_in[9];
    const float* Dp      = (const float*)d_in[10];
    const float* out_w   = (const float*)d_in[11];
    const float* ln_g    = (const float*)d_in[12];
    const float* ln_b    = (const float*)d_in[13];
    const float* head_w  = (const float*)d_in[14];
    const float* head_b  = (const float*)d_in[15];
    float* out = (float*)d_out;

    char* p = (char*)d_ws;
    auto take = [&](size_t n) { char* q = p; p += (n + 255) & ~(size_t)255; return q; };
    float* h    = (float*)take(2048ull * 512 * 4);
    u16*   r_bf = (u16*)  take(2048ull * 512 * 2);
    float* xz   = (float*)take(2048ull * 2048 * 4);
    float* xc   = (float*)take(2048ull * 1024 * 4);
    float* dbc  = (float*)take(2048ull * 64 * 4);
    float* dlt  = (float*)take(2048ull * 1024 * 4);
    u16*   ys   = (u16*)  take(2048ull * 1024 * 2);
    u16*   hn   = (u16*)  take(2048ull * 512 * 2);
    u16*   win  = (u16*)  take(2ull * 2048 * 512 * 2);
    u16*   wout = (u16*)  take(2ull * 512 * 1024 * 2);
    u16*   whd  = (u16*)  take(32000ull * 512 * 2);
    float* dtwT = (float*)take(2ull * 32 * 1024 * 4);
    float* hfin = (float*)take((size_t)B_ * NCHUNK * DINNER_ * 16 * 4);
    float* h0b  = (float*)take((size_t)B_ * NCHUNK * DINNER_ * 16 * 4);
    float* sumd = (float*)take((size_t)B_ * NCHUNK * DINNER_ * 4);

    prep<<<19840, 256, 0, stream>>>(in_w, out_w, head_w, dt_w, x, embed, rms_w,
                                    win, wout, whd, dtwT, h, r_bf);

    for (int l = 0; l < 2; ++l) {
        if (l > 0) rmsnorm_bf16<<<512, 256, 0, stream>>>(h, rms_w + l * DIM_, r_bf);
        // xz = r_bf(2048x512) @ win^T(2048x512) : 128^2 tiles, grid 16x16=256, swzq=32
        gemm_bt<0><<<256, 256, 0, stream>>>(r_bf, win + (size_t)l * 2048 * 512, xz, nullptr, 2048, 2048, 512, 16, 32);
        conv_xproj_dt<<<256, 256, 0, stream>>>(xz, conv_w + l * DINNER_ * 4, conv_b + l * DINNER_,
                                               xproj_w + (size_t)l * 64 * 1024,
                                               dtwT + (size_t)l * 32 * 1024, dt_b + l * DINNER_,
                                               xc, dbc, dlt);
        ssm_part1<<<dim3(4, NCHUNK, B_), 256, 0, stream>>>(dlt, xc, dbc, A_log + (size_t)l * DINNER_ * DSTATE_, hfin, sumd);
        ssm_carry<<<128, 256, 0, stream>>>(hfin, sumd, A_log + (size_t)l * DINNER_ * DSTATE_, h0b);
        ssm_part2<<<dim3(4, NCHUNK, B_), 256, 0, stream>>>(dlt, xc, dbc, xz, A_log + (size_t)l * DINNER_ * DSTATE_,
                                                           Dp + l * DINNER_, h0b, ys);
        // h += ys(2048x1024) @ wout^T(512x1024) : grid 32x8=256, swzq=32
        gemm64<1><<<256, 256, 0, stream>>>(ys, wout + (size_t)l * 512 * 1024, h, 2048, 512, 1024, 32, 32);
    }

    layernorm_bf16<<<512, 256, 0, stream>>>(h, ln_g, ln_b, hn);
    // logits = hn(2048x512) @ whd^T(32000x512) + head_b : grid 16x250=4000, swzq=500
    gemm_bt<2><<<4000, 256, 0, stream>>>(hn, whd, out, head_b, 2048, VOCAB_, 512, 16, 500);
}

// Round 7
// 373.892 us; speedup vs baseline: 2.9575x; 1.0117x over previous
//
#include <hip/hip_runtime.h>

typedef unsigned short u16;
typedef __attribute__((ext_vector_type(8))) __bf16 bf16x8;
typedef __attribute__((ext_vector_type(4))) float f32x4;

#define B_ 2
#define L_ 1024
#define DIM_ 512
#define DINNER_ 1024
#define DSTATE_ 16
#define DTRANK_ 32
#define VOCAB_ 32000
#define NCHUNK 64
#define CLEN 16

__device__ __forceinline__ u16 f2bf(float f) {
    union { float f; unsigned u; } x; x.f = f;
    unsigned r = x.u + 0x7FFFu + ((x.u >> 16) & 1u);
    return (u16)(r >> 16);
}

// ---------------- prep: weight bf16 conversions + dtw transpose + embed+rms ----------------
__global__ __launch_bounds__(256) void prep(const float* __restrict__ in_w,
                                            const float* __restrict__ out_w,
                                            const float* __restrict__ head_w,
                                            const float* __restrict__ dt_w,
                                            const int* __restrict__ x,
                                            const float* __restrict__ embed,
                                            const float* __restrict__ rw,
                                            u16* __restrict__ win,
                                            u16* __restrict__ wout,
                                            u16* __restrict__ whd,
                                            float* __restrict__ dtwT,
                                            float* __restrict__ h,
                                            u16* __restrict__ rbf) {
    int bk = blockIdx.x;
    int t = threadIdx.x;
    if (bk < 19072) {
        const int n1 = 524288;
        const int n2 = n1 + 262144;
        int i = bk * 256 + t;
        const float4* s; ushort4* d; int j;
        if (i < n1)      { s = (const float4*)in_w;   d = (ushort4*)win;  j = i; }
        else if (i < n2) { s = (const float4*)out_w;  d = (ushort4*)wout; j = i - n1; }
        else             { s = (const float4*)head_w; d = (ushort4*)whd;  j = i - n2; }
        float4 v = s[j];
        ushort4 o; o.x = f2bf(v.x); o.y = f2bf(v.y); o.z = f2bf(v.z); o.w = f2bf(v.w);
        d[j] = o;
    } else if (bk < 19328) {
        int bb = bk - 19072;
        int l = bb >> 7;
        int e = (bb & 127) * 256 + t;
        int r = e >> 10, d = e & 1023;
        dtwT[(size_t)l * 32768 + r * 1024 + d] = dt_w[(size_t)l * 32768 + d * 32 + r];
    } else {
        int wave = t >> 6, lane = t & 63;
        int row = (bk - 19328) * 4 + wave;
        int tok = x[row];
        const float4* s = (const float4*)(embed + (size_t)tok * DIM_);
        float4 v0 = s[lane], v1 = s[lane + 64];
        float4* hd = (float4*)(h + (size_t)row * DIM_);
        hd[lane] = v0;
        hd[lane + 64] = v1;
        float ss = v0.x*v0.x + v0.y*v0.y + v0.z*v0.z + v0.w*v0.w
                 + v1.x*v1.x + v1.y*v1.y + v1.z*v1.z + v1.w*v1.w;
        for (int m = 1; m < 64; m <<= 1) ss += __shfl_xor(ss, m);
        float rms = rsqrtf(ss * (1.0f / DIM_) + 1e-5f);
        const float4* w4 = (const float4*)rw;
        float4 w0 = w4[lane], w1 = w4[lane + 64];
        u16* o = rbf + (size_t)row * DIM_;
        ushort4 a, b;
        a.x = f2bf(v0.x * rms * w0.x); a.y = f2bf(v0.y * rms * w0.y);
        a.z = f2bf(v0.z * rms * w0.z); a.w = f2bf(v0.w * rms * w0.w);
        b.x = f2bf(v1.x * rms * w1.x); b.y = f2bf(v1.y * rms * w1.y);
        b.z = f2bf(v1.z * rms * w1.z); b.w = f2bf(v1.w * rms * w1.w);
        *(ushort4*)(o + lane * 4) = a;
        *(ushort4*)(o + 256 + lane * 4) = b;
    }
}

// ---------------- RMSNorm -> bf16 ----------------
__global__ __launch_bounds__(256) void rmsnorm_bf16(const float* __restrict__ h,
                                                    const float* __restrict__ w,
                                                    u16* __restrict__ out) {
    int wave = threadIdx.x >> 6, lane = threadIdx.x & 63;
    int row = blockIdx.x * 4 + wave;
    const float4* r4 = (const float4*)(h + (size_t)row * DIM_);
    float4 v0 = r4[lane], v1 = r4[lane + 64];
    float ss = v0.x*v0.x + v0.y*v0.y + v0.z*v0.z + v0.w*v0.w
             + v1.x*v1.x + v1.y*v1.y + v1.z*v1.z + v1.w*v1.w;
    for (int m = 1; m < 64; m <<= 1) ss += __shfl_xor(ss, m);
    float rms = rsqrtf(ss * (1.0f / DIM_) + 1e-5f);
    const float4* w4 = (const float4*)w;
    float4 w0 = w4[lane], w1 = w4[lane + 64];
    u16* o = out + (size_t)row * DIM_;
    ushort4 a, b;
    a.x = f2bf(v0.x * rms * w0.x); a.y = f2bf(v0.y * rms * w0.y);
    a.z = f2bf(v0.z * rms * w0.z); a.w = f2bf(v0.w * rms * w0.w);
    b.x = f2bf(v1.x * rms * w1.x); b.y = f2bf(v1.y * rms * w1.y);
    b.z = f2bf(v1.z * rms * w1.z); b.w = f2bf(v1.w * rms * w1.w);
    *(ushort4*)(o + lane * 4) = a;
    *(ushort4*)(o + 256 + lane * 4) = b;
}

// ---------------- LayerNorm -> bf16 ----------------
__global__ __launch_bounds__(256) void layernorm_bf16(const float* __restrict__ h,
                                                      const float* __restrict__ g,
                                                      const float* __restrict__ bta,
                                                      u16* __restrict__ out) {
    int wave = threadIdx.x >> 6, lane = threadIdx.x & 63;
    int row = blockIdx.x * 4 + wave;
    const float4* r4 = (const float4*)(h + (size_t)row * DIM_);
    float4 v0 = r4[lane], v1 = r4[lane + 64];
    float s = v0.x + v0.y + v0.z + v0.w + v1.x + v1.y + v1.z + v1.w;
    float ss = v0.x*v0.x + v0.y*v0.y + v0.z*v0.z + v0.w*v0.w
             + v1.x*v1.x + v1.y*v1.y + v1.z*v1.z + v1.w*v1.w;
    for (int m = 1; m < 64; m <<= 1) { s += __shfl_xor(s, m); ss += __shfl_xor(ss, m); }
    float mu = s * (1.0f / DIM_);
    float var = ss * (1.0f / DIM_) - mu * mu;
    float rs = rsqrtf(var + 1e-5f);
    const float4* g4 = (const float4*)g;
    const float4* b4 = (const float4*)bta;
    float4 g0 = g4[lane], g1 = g4[lane + 64];
    float4 b0 = b4[lane], b1 = b4[lane + 64];
    u16* o = out + (size_t)row * DIM_;
    ushort4 a, b;
    a.x = f2bf((v0.x - mu) * rs * g0.x + b0.x); a.y = f2bf((v0.y - mu) * rs * g0.y + b0.y);
    a.z = f2bf((v0.z - mu) * rs * g0.z + b0.z); a.w = f2bf((v0.w - mu) * rs * g0.w + b0.w);
    b.x = f2bf((v1.x - mu) * rs * g1.x + b1.x); b.y = f2bf((v1.y - mu) * rs * g1.y + b1.y);
    b.z = f2bf((v1.z - mu) * rs * g1.z + b1.z); b.w = f2bf((v1.w - mu) * rs * g1.w + b1.w);
    *(ushort4*)(o + lane * 4) = a;
    *(ushort4*)(o + 256 + lane * 4) = b;
}

// ---------------- MFMA GEMM 128x128, BK=32, depth-4 rotation, counted vmcnt ----------------
// MODE 0: C = acc ; MODE 2: C = acc + bias[col]
template <int MODE>
__global__ __launch_bounds__(256) void gemm_bt(const u16* __restrict__ A,
                                               const u16* __restrict__ B,
                                               float* __restrict__ C,
                                               const float* __restrict__ bias,
                                               int M, int N, int K,
                                               int nbx, int swzq) {
    __shared__ u16 As[4][128 * 32];
    __shared__ u16 Bs[4][128 * 32];
    const int tid = threadIdx.x;
    const int wave = tid >> 6;
    const int lane = tid & 63;
    int lin = blockIdx.x;
    if (swzq) lin = (lin & 7) * swzq + (lin >> 3);
    const int m0 = (lin % nbx) * 128;
    const int n0 = (lin / nbx) * 128;
    const int wr = wave >> 1, wc = wave & 1;
    f32x4 acc[4][4] = {};

    // staging: chunk = 16 rows x 32 cols (1KB). lane: sub = row, slotL = 16B slot.
    // both-sides XOR swizzle: f(r) = (r&3)^((r>>2)&3); LDS linear, source pre-swizzled.
    const int sub = lane >> 2;
    const int slotL = lane & 3;
    const int fsub = (sub & 3) ^ ((sub >> 2) & 3);
    const int scol = (slotL ^ fsub) * 8;

    auto stage = [&](int buf, int kt) {
        int k0 = kt * 32;
        #pragma unroll
        for (int i = 0; i < 4; ++i) {
            int c = wave * 4 + i;
            const u16* src;
            u16* dst;
            if (c < 8) {
                int row = c * 16 + sub;
                src = A + (size_t)(m0 + row) * K + k0 + scol;
                dst = &As[buf][c * 512];
            } else {
                int cc = c - 8;
                int row = cc * 16 + sub;
                src = B + (size_t)(n0 + row) * K + k0 + scol;
                dst = &Bs[buf][cc * 512];
            }
            __builtin_amdgcn_global_load_lds((const __attribute__((address_space(1))) void*)src,
                                             (__attribute__((address_space(3))) void*)dst,
                                             16, 0, 0);
        }
    };

    const int nt = K / 32;           // >= 4 for all uses (K=512 -> 16)
    stage(0, 0); stage(1, 1); stage(2, 2);

    const int fr = lane & 15;
    const int q = lane >> 4;
    const int fswz = (fr & 3) ^ ((fr >> 2) & 3);
    const int rdoff = ((q ^ fswz) * 8);

    for (int t = 0; t < nt; ++t) {
        if (t + 2 < nt)      asm volatile("s_waitcnt vmcnt(8)" ::: "memory");
        else if (t + 1 < nt) asm volatile("s_waitcnt vmcnt(4)" ::: "memory");
        else                 asm volatile("s_waitcnt vmcnt(0)" ::: "memory");
        __builtin_amdgcn_sched_barrier(0);
        __builtin_amdgcn_s_barrier();
        asm volatile("" ::: "memory");
        __builtin_amdgcn_sched_barrier(0);
        if (t + 3 < nt) stage((t + 3) & 3, t + 3);
        const u16* Ab = &As[t & 3][0];
        const u16* Bb = &Bs[t & 3][0];
        bf16x8 a[4], b[4];
        #pragma unroll
        for (int mi = 0; mi < 4; ++mi)
            a[mi] = *(const bf16x8*)(Ab + (wr * 64 + mi * 16 + fr) * 32 + rdoff);
        #pragma unroll
        for (int ni = 0; ni < 4; ++ni)
            b[ni] = *(const bf16x8*)(Bb + (wc * 64 + ni * 16 + fr) * 32 + rdoff);
        __builtin_amdgcn_s_setprio(1);
        #pragma unroll
        for (int mi = 0; mi < 4; ++mi)
            #pragma unroll
            for (int ni = 0; ni < 4; ++ni)
                acc[mi][ni] = __builtin_amdgcn_mfma_f32_16x16x32_bf16(a[mi], b[ni], acc[mi][ni], 0, 0, 0);
        __builtin_amdgcn_s_setprio(0);
    }

    const int cl = lane & 15;
    const int rq = (lane >> 4) * 4;
    #pragma unroll
    for (int mi = 0; mi < 4; ++mi) {
        #pragma unroll
        for (int ni = 0; ni < 4; ++ni) {
            int col = n0 + wc * 64 + ni * 16 + cl;
            #pragma unroll
            for (int rr = 0; rr < 4; ++rr) {
                int row = m0 + wr * 64 + mi * 16 + rq + rr;
                size_t idx = (size_t)row * N + col;
                float v = acc[mi][ni][rr];
                if (MODE == 2)      C[idx] = v + bias[col];
                else                C[idx] = v;
            }
        }
    }
}

// ---------------- MFMA GEMM 64x64, BK=64, depth-4 rotation, counted vmcnt ----------------
template <int MODE>
__global__ __launch_bounds__(256) void gemm64(const u16* __restrict__ A,
                                              const u16* __restrict__ B,
                                              float* __restrict__ C,
                                              int M, int N, int K,
                                              int nbx, int swzq) {
    __shared__ u16 As[4][64 * 64];
    __shared__ u16 Bs[4][64 * 64];
    const int tid = threadIdx.x;
    const int wave = tid >> 6;
    const int lane = tid & 63;
    int lin = blockIdx.x;
    if (swzq) lin = (lin & 7) * swzq + (lin >> 3);
    const int m0 = (lin % nbx) * 64;
    const int n0 = (lin / nbx) * 64;
    const int wr = wave >> 1, wc = wave & 1;
    f32x4 acc[2][2] = {};

    const int crow = lane >> 3;
    const int scol = ((lane & 7) ^ crow) * 8;

    auto stage = [&](int buf, int kt) {
        int k0 = kt * 64;
        #pragma unroll
        for (int i = 0; i < 4; ++i) {
            int c = wave * 4 + i;
            const u16* src;
            u16* dst;
            if (c < 8) {
                int row = c * 8 + crow;
                src = A + (size_t)(m0 + row) * K + k0 + scol;
                dst = &As[buf][c * 512];
            } else {
                int cc = c - 8;
                int row = cc * 8 + crow;
                src = B + (size_t)(n0 + row) * K + k0 + scol;
                dst = &Bs[buf][cc * 512];
            }
            __builtin_amdgcn_global_load_lds((const __attribute__((address_space(1))) void*)src,
                                             (__attribute__((address_space(3))) void*)dst,
                                             16, 0, 0);
        }
    };

    const int nt = K / 64;           // 8 (in-proj unused) / 16 (out-proj)
    stage(0, 0); stage(1, 1); stage(2, 2);

    const int fr = lane & 15;
    const int q = lane >> 4;

    for (int t = 0; t < nt; ++t) {
        if (t + 2 < nt)      asm volatile("s_waitcnt vmcnt(8)" ::: "memory");
        else if (t + 1 < nt) asm volatile("s_waitcnt vmcnt(4)" ::: "memory");
        else                 asm volatile("s_waitcnt vmcnt(0)" ::: "memory");
        __builtin_amdgcn_sched_barrier(0);
        __builtin_amdgcn_s_barrier();
        asm volatile("" ::: "memory");
        __builtin_amdgcn_sched_barrier(0);
        if (t + 3 < nt) stage((t + 3) & 3, t + 3);
        const u16* Ab = &As[t & 3][0];
        const u16* Bb = &Bs[t & 3][0];
        bf16x8 a[2][2], b[2][2];
        #pragma unroll
        for (int ki = 0; ki < 2; ++ki) {
            #pragma unroll
            for (int mi = 0; mi < 2; ++mi) {
                int row = wr * 32 + mi * 16 + fr;
                a[ki][mi] = *(const bf16x8*)(Ab + row * 64 + ((((ki << 2) + q) ^ (fr & 7)) * 8));
            }
            #pragma unroll
            for (int ni = 0; ni < 2; ++ni) {
                int row = wc * 32 + ni * 16 + fr;
                b[ki][ni] = *(const bf16x8*)(Bb + row * 64 + ((((ki << 2) + q) ^ (fr & 7)) * 8));
            }
        }
        __builtin_amdgcn_s_setprio(1);
        #pragma unroll
        for (int ki = 0; ki < 2; ++ki)
            #pragma unroll
            for (int mi = 0; mi < 2; ++mi)
                #pragma unroll
                for (int ni = 0; ni < 2; ++ni)
                    acc[mi][ni] = __builtin_amdgcn_mfma_f32_16x16x32_bf16(a[ki][mi], b[ki][ni], acc[mi][ni], 0, 0, 0);
        __builtin_amdgcn_s_setprio(0);
    }

    const int cl = lane & 15;
    const int rq = (lane >> 4) * 4;
    #pragma unroll
    for (int mi = 0; mi < 2; ++mi) {
        #pragma unroll
        for (int ni = 0; ni < 2; ++ni) {
            int col = n0 + wc * 32 + ni * 16 + cl;
            #pragma unroll
            for (int rr = 0; rr < 4; ++rr) {
                int row = m0 + wr * 32 + mi * 16 + rq + rr;
                size_t idx = (size_t)row * N + col;
                float v = acc[mi][ni][rr];
                if (MODE == 1)      C[idx] += v;
                else                C[idx] = v;
            }
        }
    }
}

// ---------------- fused conv+silu -> xproj -> dt+softplus (8 rows/block) ----------------
__global__ __launch_bounds__(256) void conv_xproj_dt(const float* __restrict__ xz,
                                                     const float* __restrict__ cw,
                                                     const float* __restrict__ cb,
                                                     const float* __restrict__ xw,
                                                     const float* __restrict__ dtwT,
                                                     const float* __restrict__ dtb,
                                                     float* __restrict__ xc,
                                                     float* __restrict__ dbc,
                                                     float* __restrict__ delta) {
    __shared__ float sxc[8 * 1024];
    __shared__ float sxw[64 * 132];
    __shared__ float sred[4][8][68];
    __shared__ float sdbc[8][64];
    int t = threadIdx.x;
    int m0 = blockIdx.x * 8;
    #pragma unroll
    for (int i = 0; i < 32; ++i) {
        int idx = t + i * 256;
        int mi = idx >> 10, d = idx & 1023;
        int m = m0 + mi;
        int l = m & (L_ - 1);
        float acc = cb[d];
        #pragma unroll
        for (int j = 0; j < 4; ++j) {
            int ll = l - 3 + j;
            if (ll >= 0) acc = fmaf(cw[d * 4 + j], xz[(size_t)(m - 3 + j) * (2 * DINNER_) + d], acc);
        }
        float sv = acc / (1.0f + __expf(-acc));
        sxc[mi * 1024 + d] = sv;
        xc[(size_t)m * DINNER_ + d] = sv;
    }
    const int n = t & 63, kg = t >> 6;
    float acc8[8] = {};
    for (int kc = 0; kc < 8; ++kc) {
        __syncthreads();
        #pragma unroll
        for (int i = 0; i < 8; ++i) {
            int f = t + i * 256;
            int row = f >> 5, col4 = f & 31;
            *(float4*)(&sxw[row * 132 + col4 * 4]) =
                *(const float4*)(xw + (size_t)row * DINNER_ + kc * 128 + col4 * 4);
        }
        __syncthreads();
        #pragma unroll
        for (int k4i = 0; k4i < 8; ++k4i) {
            int k4 = kg * 8 + k4i;
            float4 wv = *(const float4*)(&sxw[n * 132 + k4 * 4]);
            #pragma unroll
            for (int mi = 0; mi < 8; ++mi) {
                float4 xv = *(const float4*)(&sxc[mi * 1024 + kc * 128 + k4 * 4]);
                acc8[mi] += wv.x * xv.x + wv.y * xv.y + wv.z * xv.z + wv.w * xv.w;
            }
        }
    }
    #pragma unroll
    for (int mi = 0; mi < 8; ++mi) sred[kg][mi][n] = acc8[mi];
    __syncthreads();
    #pragma unroll
    for (int rep = 0; rep < 2; ++rep) {
        int o = t + rep * 256;
        int mi = o >> 6, n2 = o & 63;
        float v = sred[0][mi][n2] + sred[1][mi][n2] + sred[2][mi][n2] + sred[3][mi][n2];
        sdbc[mi][n2] = v;
        dbc[(size_t)(m0 + mi) * 64 + n2] = v;
    }
    __syncthreads();
    {
        int d0 = t * 4;
        float4 bias = *(const float4*)(dtb + d0);
        float4 am[8];
        #pragma unroll
        for (int mi = 0; mi < 8; ++mi) am[mi] = bias;
        const float4* wT = (const float4*)dtwT;
        #pragma unroll
        for (int r = 0; r < 32; ++r) {
            float4 wv = wT[r * 256 + t];
            #pragma unroll
            for (int mi = 0; mi < 8; ++mi) {
                float s = sdbc[mi][r];
                am[mi].x = fmaf(s, wv.x, am[mi].x);
                am[mi].y = fmaf(s, wv.y, am[mi].y);
                am[mi].z = fmaf(s, wv.z, am[mi].z);
                am[mi].w = fmaf(s, wv.w, am[mi].w);
            }
        }
        #pragma unroll
        for (int mi = 0; mi < 8; ++mi) {
            float4 o;
            o.x = (am[mi].x > 20.f) ? am[mi].x : log1pf(__expf(am[mi].x));
            o.y = (am[mi].y > 20.f) ? am[mi].y : log1pf(__expf(am[mi].y));
            o.z = (am[mi].z > 20.f) ? am[mi].z : log1pf(__expf(am[mi].z));
            o.w = (am[mi].w > 20.f) ? am[mi].w : log1pf(__expf(am[mi].w));
            *(float4*)(delta + (size_t)(m0 + mi) * DINNER_ + d0) = o;
        }
    }
}

// ---------------- SSM pass 1: per-chunk local scan (h0=0) ----------------
__global__ __launch_bounds__(256) void ssm_part1(const float* __restrict__ delta,
                                                 const float* __restrict__ xc,
                                                 const float* __restrict__ dbc,
                                                 const float* __restrict__ A_log,
                                                 float* __restrict__ hfin,
                                                 float* __restrict__ sumd) {
    int tid = threadIdx.x;
    int d = blockIdx.x * 256 + tid;
    int c = blockIdx.y;
    int b = blockIdx.z;
    __shared__ float sB[CLEN][DSTATE_];
    {
        int l = tid >> 4, s = tid & 15;
        sB[l][s] = dbc[((size_t)(b * L_ + c * CLEN + l)) * 64 + DTRANK_ + s];
    }
    float A[16], h[16];
    {
        const float4* Ar = (const float4*)(A_log + (size_t)d * DSTATE_);
        #pragma unroll
        for (int i = 0; i < 4; ++i) {
            float4 al = Ar[i];
            A[i * 4 + 0] = -__expf(al.x); A[i * 4 + 1] = -__expf(al.y);
            A[i * 4 + 2] = -__expf(al.z); A[i * 4 + 3] = -__expf(al.w);
        }
    }
    #pragma unroll
    for (int s = 0; s < 16; ++s) h[s] = 0.f;
    __syncthreads();
    float sd = 0.f;
    size_t base = ((size_t)b * L_ + c * CLEN) * DINNER_ + d;
    #pragma unroll
    for (int l = 0; l < CLEN; ++l) {
        float dv = delta[base + (size_t)l * DINNER_];
        float xv = xc[base + (size_t)l * DINNER_];
        sd += dv;
        float dx = dv * xv;
        #pragma unroll
        for (int s = 0; s < 16; ++s) {
            float e = __expf(dv * A[s]);
            h[s] = fmaf(e, h[s], dx * sB[l][s]);
        }
    }
    float* hf = hfin + (((size_t)b * NCHUNK + c) * DINNER_ + d) * 16;
    #pragma unroll
    for (int i = 0; i < 4; ++i) {
        float4 v; v.x = h[i*4]; v.y = h[i*4+1]; v.z = h[i*4+2]; v.w = h[i*4+3];
        *(float4*)(hf + i * 4) = v;
    }
    sumd[((size_t)b * NCHUNK + c) * DINNER_ + d] = sd;
}

// ---------------- SSM pass 2: carry propagation across chunks ----------------
__global__ __launch_bounds__(256) void ssm_carry(const float* __restrict__ hfin,
                                                 const float* __restrict__ sumd,
                                                 const float* __restrict__ A_log,
                                                 float* __restrict__ h0buf) {
    int t = blockIdx.x * 256 + threadIdx.x;
    int s = t & 15;
    int dg = t >> 4;
    int d = dg & (DINNER_ - 1);
    int b = dg >> 10;
    float As = -__expf(A_log[(size_t)d * DSTATE_ + s]);
    float hc = 0.f;
    #pragma unroll 4
    for (int c = 0; c < NCHUNK; ++c) {
        size_t k = (((size_t)b * NCHUNK + c) * DINNER_ + d) * 16 + s;
        h0buf[k] = hc;
        float sdv = sumd[((size_t)b * NCHUNK + c) * DINNER_ + d];
        float hf = hfin[k];
        hc = fmaf(__expf(As * sdv), hc, hf);
    }
}

// ---------------- SSM pass 3: local scan w/ carry + y + gate -> ys(bf16) ----------------
__global__ __launch_bounds__(256) void ssm_part2(const float* __restrict__ delta,
                                                 const float* __restrict__ xc,
                                                 const float* __restrict__ dbc,
                                                 const float* __restrict__ xz,
                                                 const float* __restrict__ A_log,
                                                 const float* __restrict__ Dp,
                                                 const float* __restrict__ h0buf,
                                                 u16* __restrict__ ys) {
    int tid = threadIdx.x;
    int d = blockIdx.x * 256 + tid;
    int c = blockIdx.y;
    int b = blockIdx.z;
    __shared__ float sBC[CLEN][32];
    {
        int l = tid >> 5, j = tid & 31;
        sBC[l][j] = dbc[((size_t)(b * L_ + c * CLEN + l)) * 64 + DTRANK_ + j];
        int e1 = tid + 256;
        l = e1 >> 5; j = e1 & 31;
        sBC[l][j] = dbc[((size_t)(b * L_ + c * CLEN + l)) * 64 + DTRANK_ + j];
    }
    float A[16], h[16];
    {
        const float4* Ar = (const float4*)(A_log + (size_t)d * DSTATE_);
        #pragma unroll
        for (int i = 0; i < 4; ++i) {
            float4 al = Ar[i];
            A[i * 4 + 0] = -__expf(al.x); A[i * 4 + 1] = -__expf(al.y);
            A[i * 4 + 2] = -__expf(al.z); A[i * 4 + 3] = -__expf(al.w);
        }
        const float4* h0 = (const float4*)(h0buf + (((size_t)b * NCHUNK + c) * DINNER_ + d) * 16);
        #pragma unroll
        for (int i = 0; i < 4; ++i) {
            float4 v = h0[i];
            h[i * 4 + 0] = v.x; h[i * 4 + 1] = v.y; h[i * 4 + 2] = v.z; h[i * 4 + 3] = v.w;
        }
    }
    float Dval = Dp[d];
    __syncthreads();
    size_t base = ((size_t)b * L_ + c * CLEN) * DINNER_ + d;
    size_t zbase = ((size_t)b * L_ + c * CLEN) * (2 * DINNER_) + DINNER_ + d;
    #pragma unroll
    for (int l = 0; l < CLEN; ++l) {
        float dv = delta[base + (size_t)l * DINNER_];
        float xv = xc[base + (size_t)l * DINNER_];
        float zv = xz[zbase + (size_t)l * (2 * DINNER_)];
        float dx = dv * xv;
        float y = 0.f;
        #pragma unroll
        for (int s = 0; s < 16; ++s) {
            float e = __expf(dv * A[s]);
            h[s] = fmaf(e, h[s], dx * sBC[l][s]);
            y = fmaf(h[s], sBC[l][16 + s], y);
        }
        y = fmaf(Dval, xv, y);
        float sg = zv / (1.0f + __expf(-zv));
        ys[base + (size_t)l * DINNER_] = f2bf(y * sg);
    }
}

extern "C" void kernel_launch(void* const* d_in, const int* in_sizes, int n_in,
                              void* d_out, int out_size, void* d_ws, size_t ws_size,
                              hipStream_t stream) {
    const int*   x       = (const int*)d_in[0];
    const float* embed   = (const float*)d_in[1];
    const float* rms_w   = (const float*)d_in[2];
    const float* in_w    = (const float*)d_in[3];
    const float* conv_w  = (const float*)d_in[4];
    const float* conv_b  = (const float*)d_in[5];
    const float* xproj_w = (const float*)d_in[6];
    const float* dt_w    = (const float*)d_in[7];
    const float* dt_b    = (const float*)d_in[8];
    const float* A_log   = (const float*)d_in[9];
    const float* Dp      = (const float*)d_in[10];
    const float* out_w   = (const float*)d_in[11];
    const float* ln_g    = (const float*)d_in[12];
    const float* ln_b    = (const float*)d_in[13];
    const float* head_w  = (const float*)d_in[14];
    const float* head_b  = (const float*)d_in[15];
    float* out = (float*)d_out;

    char* p = (char*)d_ws;
    auto take = [&](size_t n) { char* q = p; p += (n + 255) & ~(size_t)255; return q; };
    float* h    = (float*)take(2048ull * 512 * 4);
    u16*   r_bf = (u16*)  take(2048ull * 512 * 2);
    float* xz   = (float*)take(2048ull * 2048 * 4);
    float* xc   = (float*)take(2048ull * 1024 * 4);
    float* dbc  = (float*)take(2048ull * 64 * 4);
    float* dlt  = (float*)take(2048ull * 1024 * 4);
    u16*   ys   = (u16*)  take(2048ull * 1024 * 2);
    u16*   hn   = (u16*)  take(2048ull * 512 * 2);
    u16*   win  = (u16*)  take(2ull * 2048 * 512 * 2);
    u16*   wout = (u16*)  take(2ull * 512 * 1024 * 2);
    u16*   whd  = (u16*)  take(32000ull * 512 * 2);
    float* dtwT = (float*)take(2ull * 32 * 1024 * 4);
    float* hfin = (float*)take((size_t)B_ * NCHUNK * DINNER_ * 16 * 4);
    float* h0b  = (float*)take((size_t)B_ * NCHUNK * DINNER_ * 16 * 4);
    float* sumd = (float*)take((size_t)B_ * NCHUNK * DINNER_ * 4);

    prep<<<19840, 256, 0, stream>>>(in_w, out_w, head_w, dt_w, x, embed, rms_w,
                                    win, wout, whd, dtwT, h, r_bf);

    for (int l = 0; l < 2; ++l) {
        if (l > 0) rmsnorm_bf16<<<512, 256, 0, stream>>>(h, rms_w + l * DIM_, r_bf);
        // xz = r_bf(2048x512) @ win^T(2048x512) : 128^2 tiles, grid 16x16=256, swzq=32
        gemm_bt<0><<<256, 256, 0, stream>>>(r_bf, win + (size_t)l * 2048 * 512, xz, nullptr, 2048, 2048, 512, 16, 32);
        conv_xproj_dt<<<256, 256, 0, stream>>>(xz, conv_w + l * DINNER_ * 4, conv_b + l * DINNER_,
                                               xproj_w + (size_t)l * 64 * 1024,
                                               dtwT + (size_t)l * 32 * 1024, dt_b + l * DINNER_,
                                               xc, dbc, dlt);
        ssm_part1<<<dim3(4, NCHUNK, B_), 256, 0, stream>>>(dlt, xc, dbc, A_log + (size_t)l * DINNER_ * DSTATE_, hfin, sumd);
        ssm_carry<<<128, 256, 0, stream>>>(hfin, sumd, A_log + (size_t)l * DINNER_ * DSTATE_, h0b);
        ssm_part2<<<dim3(4, NCHUNK, B_), 256, 0, stream>>>(dlt, xc, dbc, xz, A_log + (size_t)l * DINNER_ * DSTATE_,
                                                           Dp + l * DINNER_, h0b, ys);
        // h += ys(2048x1024) @ wout^T(512x1024) : grid 32x8=256, swzq=32
        gemm64<1><<<256, 256, 0, stream>>>(ys, wout + (size_t)l * 512 * 1024, h, 2048, 512, 1024, 32, 32);
    }

    layernorm_bf16<<<512, 256, 0, stream>>>(h, ln_g, ln_b, hn);
    // logits = hn(2048x512) @ whd^T(32000x512) + head_b : grid 16x250=4000, swzq=500
    gemm_bt<2><<<4000, 256, 0, stream>>>(hn, whd, out, head_b, 2048, VOCAB_, 512, 16, 500);
}

// Round 8
// 361.731 us; speedup vs baseline: 3.0569x; 1.0336x over previous
//
#include <hip/hip_runtime.h>

typedef unsigned short u16;
typedef __attribute__((ext_vector_type(8))) __bf16 bf16x8;
typedef __attribute__((ext_vector_type(4))) float f32x4;

#define B_ 2
#define L_ 1024
#define DIM_ 512
#define DINNER_ 1024
#define DSTATE_ 16
#define DTRANK_ 32
#define VOCAB_ 32000
#define NCHUNK 64
#define CLEN 16

__device__ __forceinline__ u16 f2bf(float f) {
    union { float f; unsigned u; } x; x.f = f;
    unsigned r = x.u + 0x7FFFu + ((x.u >> 16) & 1u);
    return (u16)(r >> 16);
}

// ---------------- prep: weight bf16 conversions + dtw transpose + embed+rms ----------------
__global__ __launch_bounds__(256) void prep(const float* __restrict__ in_w,
                                            const float* __restrict__ out_w,
                                            const float* __restrict__ head_w,
                                            const float* __restrict__ dt_w,
                                            const int* __restrict__ x,
                                            const float* __restrict__ embed,
                                            const float* __restrict__ rw,
                                            u16* __restrict__ win,
                                            u16* __restrict__ wout,
                                            u16* __restrict__ whd,
                                            float* __restrict__ dtwT,
                                            float* __restrict__ h,
                                            u16* __restrict__ rbf) {
    int bk = blockIdx.x;
    int t = threadIdx.x;
    if (bk < 19072) {
        const int n1 = 524288;
        const int n2 = n1 + 262144;
        int i = bk * 256 + t;
        const float4* s; ushort4* d; int j;
        if (i < n1)      { s = (const float4*)in_w;   d = (ushort4*)win;  j = i; }
        else if (i < n2) { s = (const float4*)out_w;  d = (ushort4*)wout; j = i - n1; }
        else             { s = (const float4*)head_w; d = (ushort4*)whd;  j = i - n2; }
        float4 v = s[j];
        ushort4 o; o.x = f2bf(v.x); o.y = f2bf(v.y); o.z = f2bf(v.z); o.w = f2bf(v.w);
        d[j] = o;
    } else if (bk < 19328) {
        int bb = bk - 19072;
        int l = bb >> 7;
        int e = (bb & 127) * 256 + t;
        int r = e >> 10, d = e & 1023;
        dtwT[(size_t)l * 32768 + r * 1024 + d] = dt_w[(size_t)l * 32768 + d * 32 + r];
    } else {
        int wave = t >> 6, lane = t & 63;
        int row = (bk - 19328) * 4 + wave;
        int tok = x[row];
        const float4* s = (const float4*)(embed + (size_t)tok * DIM_);
        float4 v0 = s[lane], v1 = s[lane + 64];
        float4* hd = (float4*)(h + (size_t)row * DIM_);
        hd[lane] = v0;
        hd[lane + 64] = v1;
        float ss = v0.x*v0.x + v0.y*v0.y + v0.z*v0.z + v0.w*v0.w
                 + v1.x*v1.x + v1.y*v1.y + v1.z*v1.z + v1.w*v1.w;
        for (int m = 1; m < 64; m <<= 1) ss += __shfl_xor(ss, m);
        float rms = rsqrtf(ss * (1.0f / DIM_) + 1e-5f);
        const float4* w4 = (const float4*)rw;
        float4 w0 = w4[lane], w1 = w4[lane + 64];
        u16* o = rbf + (size_t)row * DIM_;
        ushort4 a, b;
        a.x = f2bf(v0.x * rms * w0.x); a.y = f2bf(v0.y * rms * w0.y);
        a.z = f2bf(v0.z * rms * w0.z); a.w = f2bf(v0.w * rms * w0.w);
        b.x = f2bf(v1.x * rms * w1.x); b.y = f2bf(v1.y * rms * w1.y);
        b.z = f2bf(v1.z * rms * w1.z); b.w = f2bf(v1.w * rms * w1.w);
        *(ushort4*)(o + lane * 4) = a;
        *(ushort4*)(o + 256 + lane * 4) = b;
    }
}

// ---------------- RMSNorm -> bf16 ----------------
__global__ __launch_bounds__(256) void rmsnorm_bf16(const float* __restrict__ h,
                                                    const float* __restrict__ w,
                                                    u16* __restrict__ out) {
    int wave = threadIdx.x >> 6, lane = threadIdx.x & 63;
    int row = blockIdx.x * 4 + wave;
    const float4* r4 = (const float4*)(h + (size_t)row * DIM_);
    float4 v0 = r4[lane], v1 = r4[lane + 64];
    float ss = v0.x*v0.x + v0.y*v0.y + v0.z*v0.z + v0.w*v0.w
             + v1.x*v1.x + v1.y*v1.y + v1.z*v1.z + v1.w*v1.w;
    for (int m = 1; m < 64; m <<= 1) ss += __shfl_xor(ss, m);
    float rms = rsqrtf(ss * (1.0f / DIM_) + 1e-5f);
    const float4* w4 = (const float4*)w;
    float4 w0 = w4[lane], w1 = w4[lane + 64];
    u16* o = out + (size_t)row * DIM_;
    ushort4 a, b;
    a.x = f2bf(v0.x * rms * w0.x); a.y = f2bf(v0.y * rms * w0.y);
    a.z = f2bf(v0.z * rms * w0.z); a.w = f2bf(v0.w * rms * w0.w);
    b.x = f2bf(v1.x * rms * w1.x); b.y = f2bf(v1.y * rms * w1.y);
    b.z = f2bf(v1.z * rms * w1.z); b.w = f2bf(v1.w * rms * w1.w);
    *(ushort4*)(o + lane * 4) = a;
    *(ushort4*)(o + 256 + lane * 4) = b;
}

// ---------------- LayerNorm -> bf16 ----------------
__global__ __launch_bounds__(256) void layernorm_bf16(const float* __restrict__ h,
                                                      const float* __restrict__ g,
                                                      const float* __restrict__ bta,
                                                      u16* __restrict__ out) {
    int wave = threadIdx.x >> 6, lane = threadIdx.x & 63;
    int row = blockIdx.x * 4 + wave;
    const float4* r4 = (const float4*)(h + (size_t)row * DIM_);
    float4 v0 = r4[lane], v1 = r4[lane + 64];
    float s = v0.x + v0.y + v0.z + v0.w + v1.x + v1.y + v1.z + v1.w;
    float ss = v0.x*v0.x + v0.y*v0.y + v0.z*v0.z + v0.w*v0.w
             + v1.x*v1.x + v1.y*v1.y + v1.z*v1.z + v1.w*v1.w;
    for (int m = 1; m < 64; m <<= 1) { s += __shfl_xor(s, m); ss += __shfl_xor(ss, m); }
    float mu = s * (1.0f / DIM_);
    float var = ss * (1.0f / DIM_) - mu * mu;
    float rs = rsqrtf(var + 1e-5f);
    const float4* g4 = (const float4*)g;
    const float4* b4 = (const float4*)bta;
    float4 g0 = g4[lane], g1 = g4[lane + 64];
    float4 b0 = b4[lane], b1 = b4[lane + 64];
    u16* o = out + (size_t)row * DIM_;
    ushort4 a, b;
    a.x = f2bf((v0.x - mu) * rs * g0.x + b0.x); a.y = f2bf((v0.y - mu) * rs * g0.y + b0.y);
    a.z = f2bf((v0.z - mu) * rs * g0.z + b0.z); a.w = f2bf((v0.w - mu) * rs * g0.w + b0.w);
    b.x = f2bf((v1.x - mu) * rs * g1.x + b1.x); b.y = f2bf((v1.y - mu) * rs * g1.y + b1.y);
    b.z = f2bf((v1.z - mu) * rs * g1.z + b1.z); b.w = f2bf((v1.w - mu) * rs * g1.w + b1.w);
    *(ushort4*)(o + lane * 4) = a;
    *(ushort4*)(o + 256 + lane * 4) = b;
}

// ---------------- MFMA GEMM 128x128, BK=32, depth-4 rotation, counted vmcnt ----------------
template <int MODE>
__global__ __launch_bounds__(256) void gemm_bt(const u16* __restrict__ A,
                                               const u16* __restrict__ B,
                                               float* __restrict__ C,
                                               const float* __restrict__ bias,
                                               int M, int N, int K,
                                               int nbx, int swzq) {
    __shared__ u16 As[4][128 * 32];
    __shared__ u16 Bs[4][128 * 32];
    const int tid = threadIdx.x;
    const int wave = tid >> 6;
    const int lane = tid & 63;
    int lin = blockIdx.x;
    if (swzq) lin = (lin & 7) * swzq + (lin >> 3);
    const int m0 = (lin % nbx) * 128;
    const int n0 = (lin / nbx) * 128;
    const int wr = wave >> 1, wc = wave & 1;
    f32x4 acc[4][4] = {};

    const int sub = lane >> 2;
    const int slotL = lane & 3;
    const int fsub = (sub & 3) ^ ((sub >> 2) & 3);
    const int scol = (slotL ^ fsub) * 8;

    auto stage = [&](int buf, int kt) {
        int k0 = kt * 32;
        #pragma unroll
        for (int i = 0; i < 4; ++i) {
            int c = wave * 4 + i;
            const u16* src;
            u16* dst;
            if (c < 8) {
                int row = c * 16 + sub;
                src = A + (size_t)(m0 + row) * K + k0 + scol;
                dst = &As[buf][c * 512];
            } else {
                int cc = c - 8;
                int row = cc * 16 + sub;
                src = B + (size_t)(n0 + row) * K + k0 + scol;
                dst = &Bs[buf][cc * 512];
            }
            __builtin_amdgcn_global_load_lds((const __attribute__((address_space(1))) void*)src,
                                             (__attribute__((address_space(3))) void*)dst,
                                             16, 0, 0);
        }
    };

    const int nt = K / 32;
    stage(0, 0); stage(1, 1); stage(2, 2);

    const int fr = lane & 15;
    const int q = lane >> 4;
    const int fswz = (fr & 3) ^ ((fr >> 2) & 3);
    const int rdoff = ((q ^ fswz) * 8);

    for (int t = 0; t < nt; ++t) {
        if (t + 2 < nt)      asm volatile("s_waitcnt vmcnt(8)" ::: "memory");
        else if (t + 1 < nt) asm volatile("s_waitcnt vmcnt(4)" ::: "memory");
        else                 asm volatile("s_waitcnt vmcnt(0)" ::: "memory");
        __builtin_amdgcn_sched_barrier(0);
        __builtin_amdgcn_s_barrier();
        asm volatile("" ::: "memory");
        __builtin_amdgcn_sched_barrier(0);
        if (t + 3 < nt) stage((t + 3) & 3, t + 3);
        const u16* Ab = &As[t & 3][0];
        const u16* Bb = &Bs[t & 3][0];
        bf16x8 a[4], b[4];
        #pragma unroll
        for (int mi = 0; mi < 4; ++mi)
            a[mi] = *(const bf16x8*)(Ab + (wr * 64 + mi * 16 + fr) * 32 + rdoff);
        #pragma unroll
        for (int ni = 0; ni < 4; ++ni)
            b[ni] = *(const bf16x8*)(Bb + (wc * 64 + ni * 16 + fr) * 32 + rdoff);
        __builtin_amdgcn_s_setprio(1);
        #pragma unroll
        for (int mi = 0; mi < 4; ++mi)
            #pragma unroll
            for (int ni = 0; ni < 4; ++ni)
                acc[mi][ni] = __builtin_amdgcn_mfma_f32_16x16x32_bf16(a[mi], b[ni], acc[mi][ni], 0, 0, 0);
        __builtin_amdgcn_s_setprio(0);
    }

    const int cl = lane & 15;
    const int rq = (lane >> 4) * 4;
    #pragma unroll
    for (int mi = 0; mi < 4; ++mi) {
        #pragma unroll
        for (int ni = 0; ni < 4; ++ni) {
            int col = n0 + wc * 64 + ni * 16 + cl;
            #pragma unroll
            for (int rr = 0; rr < 4; ++rr) {
                int row = m0 + wr * 64 + mi * 16 + rq + rr;
                size_t idx = (size_t)row * N + col;
                float v = acc[mi][ni][rr];
                if (MODE == 2)      C[idx] = v + bias[col];
                else                C[idx] = v;
            }
        }
    }
}

// ---------------- MFMA GEMM 256x256 (head), BK=32, 512 thr, depth-4 rotation ----------------
__global__ __launch_bounds__(512) void gemm256(const u16* __restrict__ A,
                                               const u16* __restrict__ B,
                                               float* __restrict__ C,
                                               const float* __restrict__ bias,
                                               int M, int N, int K,
                                               int nbx, int swzq) {
    __shared__ u16 As[4][256 * 32];
    __shared__ u16 Bs[4][256 * 32];
    const int tid = threadIdx.x;
    const int wave = tid >> 6;
    const int lane = tid & 63;
    int lin = blockIdx.x;
    if (swzq) lin = (lin & 7) * swzq + (lin >> 3);
    const int m0 = (lin % nbx) * 256;
    const int n0 = (lin / nbx) * 256;
    const int wrM = wave >> 2;          // 0..1 -> 128-row half
    const int wcN = wave & 3;           // 0..3 -> 64-col slice
    f32x4 acc[8][4] = {};

    const int sub = lane >> 2;
    const int slotL = lane & 3;
    const int fsub = (sub & 3) ^ ((sub >> 2) & 3);
    const int scol = (slotL ^ fsub) * 8;

    auto stage = [&](int buf, int kt) {
        int k0 = kt * 32;
        #pragma unroll
        for (int i = 0; i < 4; ++i) {
            int c = wave * 4 + i;                    // 0..31
            const u16* src;
            u16* dst;
            if (c < 16) {
                int row = c * 16 + sub;
                src = A + (size_t)(m0 + row) * K + k0 + scol;
                dst = &As[buf][c * 512];
            } else {
                int cc = c - 16;
                int row = cc * 16 + sub;
                src = B + (size_t)(n0 + row) * K + k0 + scol;
                dst = &Bs[buf][cc * 512];
            }
            __builtin_amdgcn_global_load_lds((const __attribute__((address_space(1))) void*)src,
                                             (__attribute__((address_space(3))) void*)dst,
                                             16, 0, 0);
        }
    };

    const int nt = K / 32;
    stage(0, 0); stage(1, 1); stage(2, 2);

    const int fr = lane & 15;
    const int q = lane >> 4;
    const int fswz = (fr & 3) ^ ((fr >> 2) & 3);
    const int rdoff = ((q ^ fswz) * 8);

    for (int t = 0; t < nt; ++t) {
        if (t + 2 < nt)      asm volatile("s_waitcnt vmcnt(8)" ::: "memory");
        else if (t + 1 < nt) asm volatile("s_waitcnt vmcnt(4)" ::: "memory");
        else                 asm volatile("s_waitcnt vmcnt(0)" ::: "memory");
        __builtin_amdgcn_sched_barrier(0);
        __builtin_amdgcn_s_barrier();
        asm volatile("" ::: "memory");
        __builtin_amdgcn_sched_barrier(0);
        if (t + 3 < nt) stage((t + 3) & 3, t + 3);
        const u16* Ab = &As[t & 3][0];
        const u16* Bb = &Bs[t & 3][0];
        bf16x8 a[8], b[4];
        #pragma unroll
        for (int mi = 0; mi < 8; ++mi)
            a[mi] = *(const bf16x8*)(Ab + (wrM * 128 + mi * 16 + fr) * 32 + rdoff);
        #pragma unroll
        for (int ni = 0; ni < 4; ++ni)
            b[ni] = *(const bf16x8*)(Bb + (wcN * 64 + ni * 16 + fr) * 32 + rdoff);
        __builtin_amdgcn_s_setprio(1);
        #pragma unroll
        for (int mi = 0; mi < 8; ++mi)
            #pragma unroll
            for (int ni = 0; ni < 4; ++ni)
                acc[mi][ni] = __builtin_amdgcn_mfma_f32_16x16x32_bf16(a[mi], b[ni], acc[mi][ni], 0, 0, 0);
        __builtin_amdgcn_s_setprio(0);
    }

    const int cl = lane & 15;
    const int rq = (lane >> 4) * 4;
    #pragma unroll
    for (int mi = 0; mi < 8; ++mi) {
        #pragma unroll
        for (int ni = 0; ni < 4; ++ni) {
            int col = n0 + wcN * 64 + ni * 16 + cl;
            float bv = bias[col];
            #pragma unroll
            for (int rr = 0; rr < 4; ++rr) {
                int row = m0 + wrM * 128 + mi * 16 + rq + rr;
                C[(size_t)row * N + col] = acc[mi][ni][rr] + bv;
            }
        }
    }
}

// ---------------- MFMA GEMM 64x64, BK=64, depth-4 rotation, counted vmcnt ----------------
template <int MODE>
__global__ __launch_bounds__(256) void gemm64(const u16* __restrict__ A,
                                              const u16* __restrict__ B,
                                              float* __restrict__ C,
                                              int M, int N, int K,
                                              int nbx, int swzq) {
    __shared__ u16 As[4][64 * 64];
    __shared__ u16 Bs[4][64 * 64];
    const int tid = threadIdx.x;
    const int wave = tid >> 6;
    const int lane = tid & 63;
    int lin = blockIdx.x;
    if (swzq) lin = (lin & 7) * swzq + (lin >> 3);
    const int m0 = (lin % nbx) * 64;
    const int n0 = (lin / nbx) * 64;
    const int wr = wave >> 1, wc = wave & 1;
    f32x4 acc[2][2] = {};

    const int crow = lane >> 3;
    const int scol = ((lane & 7) ^ crow) * 8;

    auto stage = [&](int buf, int kt) {
        int k0 = kt * 64;
        #pragma unroll
        for (int i = 0; i < 4; ++i) {
            int c = wave * 4 + i;
            const u16* src;
            u16* dst;
            if (c < 8) {
                int row = c * 8 + crow;
                src = A + (size_t)(m0 + row) * K + k0 + scol;
                dst = &As[buf][c * 512];
            } else {
                int cc = c - 8;
                int row = cc * 8 + crow;
                src = B + (size_t)(n0 + row) * K + k0 + scol;
                dst = &Bs[buf][cc * 512];
            }
            __builtin_amdgcn_global_load_lds((const __attribute__((address_space(1))) void*)src,
                                             (__attribute__((address_space(3))) void*)dst,
                                             16, 0, 0);
        }
    };

    const int nt = K / 64;
    stage(0, 0); stage(1, 1); stage(2, 2);

    const int fr = lane & 15;
    const int q = lane >> 4;

    for (int t = 0; t < nt; ++t) {
        if (t + 2 < nt)      asm volatile("s_waitcnt vmcnt(8)" ::: "memory");
        else if (t + 1 < nt) asm volatile("s_waitcnt vmcnt(4)" ::: "memory");
        else                 asm volatile("s_waitcnt vmcnt(0)" ::: "memory");
        __builtin_amdgcn_sched_barrier(0);
        __builtin_amdgcn_s_barrier();
        asm volatile("" ::: "memory");
        __builtin_amdgcn_sched_barrier(0);
        if (t + 3 < nt) stage((t + 3) & 3, t + 3);
        const u16* Ab = &As[t & 3][0];
        const u16* Bb = &Bs[t & 3][0];
        bf16x8 a[2][2], b[2][2];
        #pragma unroll
        for (int ki = 0; ki < 2; ++ki) {
            #pragma unroll
            for (int mi = 0; mi < 2; ++mi) {
                int row = wr * 32 + mi * 16 + fr;
                a[ki][mi] = *(const bf16x8*)(Ab + row * 64 + ((((ki << 2) + q) ^ (fr & 7)) * 8));
            }
            #pragma unroll
            for (int ni = 0; ni < 2; ++ni) {
                int row = wc * 32 + ni * 16 + fr;
                b[ki][ni] = *(const bf16x8*)(Bb + row * 64 + ((((ki << 2) + q) ^ (fr & 7)) * 8));
            }
        }
        __builtin_amdgcn_s_setprio(1);
        #pragma unroll
        for (int ki = 0; ki < 2; ++ki)
            #pragma unroll
            for (int mi = 0; mi < 2; ++mi)
                #pragma unroll
                for (int ni = 0; ni < 2; ++ni)
                    acc[mi][ni] = __builtin_amdgcn_mfma_f32_16x16x32_bf16(a[ki][mi], b[ki][ni], acc[mi][ni], 0, 0, 0);
        __builtin_amdgcn_s_setprio(0);
    }

    const int cl = lane & 15;
    const int rq = (lane >> 4) * 4;
    #pragma unroll
    for (int mi = 0; mi < 2; ++mi) {
        #pragma unroll
        for (int ni = 0; ni < 2; ++ni) {
            int col = n0 + wc * 32 + ni * 16 + cl;
            #pragma unroll
            for (int rr = 0; rr < 4; ++rr) {
                int row = m0 + wr * 32 + mi * 16 + rq + rr;
                size_t idx = (size_t)row * N + col;
                float v = acc[mi][ni][rr];
                if (MODE == 1)      C[idx] += v;
                else                C[idx] = v;
            }
        }
    }
}

// ---------------- fused conv+silu -> xproj -> dt+softplus (8 rows/block) ----------------
__global__ __launch_bounds__(256) void conv_xproj_dt(const float* __restrict__ xz,
                                                     const float* __restrict__ cw,
                                                     const float* __restrict__ cb,
                                                     const float* __restrict__ xw,
                                                     const float* __restrict__ dtwT,
                                                     const float* __restrict__ dtb,
                                                     float* __restrict__ xc,
                                                     float* __restrict__ dbc,
                                                     float* __restrict__ delta) {
    __shared__ float sxc[8 * 1024];
    __shared__ float sxw[64 * 132];
    __shared__ float sred[4][8][68];
    __shared__ float sdbc[8][64];
    int t = threadIdx.x;
    int m0 = blockIdx.x * 8;
    #pragma unroll
    for (int i = 0; i < 32; ++i) {
        int idx = t + i * 256;
        int mi = idx >> 10, d = idx & 1023;
        int m = m0 + mi;
        int l = m & (L_ - 1);
        float acc = cb[d];
        #pragma unroll
        for (int j = 0; j < 4; ++j) {
            int ll = l - 3 + j;
            if (ll >= 0) acc = fmaf(cw[d * 4 + j], xz[(size_t)(m - 3 + j) * (2 * DINNER_) + d], acc);
        }
        float sv = acc / (1.0f + __expf(-acc));
        sxc[mi * 1024 + d] = sv;
        xc[(size_t)m * DINNER_ + d] = sv;
    }
    const int n = t & 63, kg = t >> 6;
    float acc8[8] = {};
    for (int kc = 0; kc < 8; ++kc) {
        __syncthreads();
        #pragma unroll
        for (int i = 0; i < 8; ++i) {
            int f = t + i * 256;
            int row = f >> 5, col4 = f & 31;
            *(float4*)(&sxw[row * 132 + col4 * 4]) =
                *(const float4*)(xw + (size_t)row * DINNER_ + kc * 128 + col4 * 4);
        }
        __syncthreads();
        #pragma unroll
        for (int k4i = 0; k4i < 8; ++k4i) {
            int k4 = kg * 8 + k4i;
            float4 wv = *(const float4*)(&sxw[n * 132 + k4 * 4]);
            #pragma unroll
            for (int mi = 0; mi < 8; ++mi) {
                float4 xv = *(const float4*)(&sxc[mi * 1024 + kc * 128 + k4 * 4]);
                acc8[mi] += wv.x * xv.x + wv.y * xv.y + wv.z * xv.z + wv.w * xv.w;
            }
        }
    }
    #pragma unroll
    for (int mi = 0; mi < 8; ++mi) sred[kg][mi][n] = acc8[mi];
    __syncthreads();
    #pragma unroll
    for (int rep = 0; rep < 2; ++rep) {
        int o = t + rep * 256;
        int mi = o >> 6, n2 = o & 63;
        float v = sred[0][mi][n2] + sred[1][mi][n2] + sred[2][mi][n2] + sred[3][mi][n2];
        sdbc[mi][n2] = v;
        dbc[(size_t)(m0 + mi) * 64 + n2] = v;
    }
    __syncthreads();
    {
        int d0 = t * 4;
        float4 bias = *(const float4*)(dtb + d0);
        float4 am[8];
        #pragma unroll
        for (int mi = 0; mi < 8; ++mi) am[mi] = bias;
        const float4* wT = (const float4*)dtwT;
        #pragma unroll
        for (int r = 0; r < 32; ++r) {
            float4 wv = wT[r * 256 + t];
            #pragma unroll
            for (int mi = 0; mi < 8; ++mi) {
                float s = sdbc[mi][r];
                am[mi].x = fmaf(s, wv.x, am[mi].x);
                am[mi].y = fmaf(s, wv.y, am[mi].y);
                am[mi].z = fmaf(s, wv.z, am[mi].z);
                am[mi].w = fmaf(s, wv.w, am[mi].w);
            }
        }
        #pragma unroll
        for (int mi = 0; mi < 8; ++mi) {
            float4 o;
            o.x = (am[mi].x > 20.f) ? am[mi].x : log1pf(__expf(am[mi].x));
            o.y = (am[mi].y > 20.f) ? am[mi].y : log1pf(__expf(am[mi].y));
            o.z = (am[mi].z > 20.f) ? am[mi].z : log1pf(__expf(am[mi].z));
            o.w = (am[mi].w > 20.f) ? am[mi].w : log1pf(__expf(am[mi].w));
            *(float4*)(delta + (size_t)(m0 + mi) * DINNER_ + d0) = o;
        }
    }
}

// ---------------- SSM pass 1: per-chunk local scan (h0=0) ----------------
__global__ __launch_bounds__(256) void ssm_part1(const float* __restrict__ delta,
                                                 const float* __restrict__ xc,
                                                 const float* __restrict__ dbc,
                                                 const float* __restrict__ A_log,
                                                 float* __restrict__ hfin,
                                                 float* __restrict__ sumd) {
    int tid = threadIdx.x;
    int d = blockIdx.x * 256 + tid;
    int c = blockIdx.y;
    int b = blockIdx.z;
    __shared__ float sB[CLEN][DSTATE_];
    {
        int l = tid >> 4, s = tid & 15;
        sB[l][s] = dbc[((size_t)(b * L_ + c * CLEN + l)) * 64 + DTRANK_ + s];
    }
    float A[16], h[16];
    {
        const float4* Ar = (const float4*)(A_log + (size_t)d * DSTATE_);
        #pragma unroll
        for (int i = 0; i < 4; ++i) {
            float4 al = Ar[i];
            A[i * 4 + 0] = -__expf(al.x); A[i * 4 + 1] = -__expf(al.y);
            A[i * 4 + 2] = -__expf(al.z); A[i * 4 + 3] = -__expf(al.w);
        }
    }
    #pragma unroll
    for (int s = 0; s < 16; ++s) h[s] = 0.f;
    __syncthreads();
    float sd = 0.f;
    size_t base = ((size_t)b * L_ + c * CLEN) * DINNER_ + d;
    #pragma unroll
    for (int l = 0; l < CLEN; ++l) {
        float dv = delta[base + (size_t)l * DINNER_];
        float xv = xc[base + (size_t)l * DINNER_];
        sd += dv;
        float dx = dv * xv;
        #pragma unroll
        for (int s = 0; s < 16; ++s) {
            float e = __expf(dv * A[s]);
            h[s] = fmaf(e, h[s], dx * sB[l][s]);
        }
    }
    float* hf = hfin + (((size_t)b * NCHUNK + c) * DINNER_ + d) * 16;
    #pragma unroll
    for (int i = 0; i < 4; ++i) {
        float4 v; v.x = h[i*4]; v.y = h[i*4+1]; v.z = h[i*4+2]; v.w = h[i*4+3];
        *(float4*)(hf + i * 4) = v;
    }
    sumd[((size_t)b * NCHUNK + c) * DINNER_ + d] = sd;
}

// ---------------- SSM pass 2: carry propagation across chunks ----------------
__global__ __launch_bounds__(256) void ssm_carry(const float* __restrict__ hfin,
                                                 const float* __restrict__ sumd,
                                                 const float* __restrict__ A_log,
                                                 float* __restrict__ h0buf) {
    int t = blockIdx.x * 256 + threadIdx.x;
    int s = t & 15;
    int dg = t >> 4;
    int d = dg & (DINNER_ - 1);
    int b = dg >> 10;
    float As = -__expf(A_log[(size_t)d * DSTATE_ + s]);
    float hc = 0.f;
    #pragma unroll 4
    for (int c = 0; c < NCHUNK; ++c) {
        size_t k = (((size_t)b * NCHUNK + c) * DINNER_ + d) * 16 + s;
        h0buf[k] = hc;
        float sdv = sumd[((size_t)b * NCHUNK + c) * DINNER_ + d];
        float hf = hfin[k];
        hc = fmaf(__expf(As * sdv), hc, hf);
    }
}

// ---------------- SSM pass 3: local scan w/ carry + y + gate -> ys(bf16) ----------------
__global__ __launch_bounds__(256) void ssm_part2(const float* __restrict__ delta,
                                                 const float* __restrict__ xc,
                                                 const float* __restrict__ dbc,
                                                 const float* __restrict__ xz,
                                                 const float* __restrict__ A_log,
                                                 const float* __restrict__ Dp,
                                                 const float* __restrict__ h0buf,
                                                 u16* __restrict__ ys) {
    int tid = threadIdx.x;
    int d = blockIdx.x * 256 + tid;
    int c = blockIdx.y;
    int b = blockIdx.z;
    __shared__ float sBC[CLEN][32];
    {
        int l = tid >> 5, j = tid & 31;
        sBC[l][j] = dbc[((size_t)(b * L_ + c * CLEN + l)) * 64 + DTRANK_ + j];
        int e1 = tid + 256;
        l = e1 >> 5; j = e1 & 31;
        sBC[l][j] = dbc[((size_t)(b * L_ + c * CLEN + l)) * 64 + DTRANK_ + j];
    }
    float A[16], h[16];
    {
        const float4* Ar = (const float4*)(A_log + (size_t)d * DSTATE_);
        #pragma unroll
        for (int i = 0; i < 4; ++i) {
            float4 al = Ar[i];
            A[i * 4 + 0] = -__expf(al.x); A[i * 4 + 1] = -__expf(al.y);
            A[i * 4 + 2] = -__expf(al.z); A[i * 4 + 3] = -__expf(al.w);
        }
        const float4* h0 = (const float4*)(h0buf + (((size_t)b * NCHUNK + c) * DINNER_ + d) * 16);
        #pragma unroll
        for (int i = 0; i < 4; ++i) {
            float4 v = h0[i];
            h[i * 4 + 0] = v.x; h[i * 4 + 1] = v.y; h[i * 4 + 2] = v.z; h[i * 4 + 3] = v.w;
        }
    }
    float Dval = Dp[d];
    __syncthreads();
    size_t base = ((size_t)b * L_ + c * CLEN) * DINNER_ + d;
    size_t zbase = ((size_t)b * L_ + c * CLEN) * (2 * DINNER_) + DINNER_ + d;
    #pragma unroll
    for (int l = 0; l < CLEN; ++l) {
        float dv = delta[base + (size_t)l * DINNER_];
        float xv = xc[base + (size_t)l * DINNER_];
        float zv = xz[zbase + (size_t)l * (2 * DINNER_)];
        float dx = dv * xv;
        float y = 0.f;
        #pragma unroll
        for (int s = 0; s < 16; ++s) {
            float e = __expf(dv * A[s]);
            h[s] = fmaf(e, h[s], dx * sBC[l][s]);
            y = fmaf(h[s], sBC[l][16 + s], y);
        }
        y = fmaf(Dval, xv, y);
        float sg = zv / (1.0f + __expf(-zv));
        ys[base + (size_t)l * DINNER_] = f2bf(y * sg);
    }
}

extern "C" void kernel_launch(void* const* d_in, const int* in_sizes, int n_in,
                              void* d_out, int out_size, void* d_ws, size_t ws_size,
                              hipStream_t stream) {
    const int*   x       = (const int*)d_in[0];
    const float* embed   = (const float*)d_in[1];
    const float* rms_w   = (const float*)d_in[2];
    const float* in_w    = (const float*)d_in[3];
    const float* conv_w  = (const float*)d_in[4];
    const float* conv_b  = (const float*)d_in[5];
    const float* xproj_w = (const float*)d_in[6];
    const float* dt_w    = (const float*)d_in[7];
    const float* dt_b    = (const float*)d_in[8];
    const float* A_log   = (const float*)d_in[9];
    const float* Dp      = (const float*)d_in[10];
    const float* out_w   = (const float*)d_in[11];
    const float* ln_g    = (const float*)d_in[12];
    const float* ln_b    = (const float*)d_in[13];
    const float* head_w  = (const float*)d_in[14];
    const float* head_b  = (const float*)d_in[15];
    float* out = (float*)d_out;

    char* p = (char*)d_ws;
    auto take = [&](size_t n) { char* q = p; p += (n + 255) & ~(size_t)255; return q; };
    float* h    = (float*)take(2048ull * 512 * 4);
    u16*   r_bf = (u16*)  take(2048ull * 512 * 2);
    float* xz   = (float*)take(2048ull * 2048 * 4);
    float* xc   = (float*)take(2048ull * 1024 * 4);
    float* dbc  = (float*)take(2048ull * 64 * 4);
    float* dlt  = (float*)take(2048ull * 1024 * 4);
    u16*   ys   = (u16*)  take(2048ull * 1024 * 2);
    u16*   hn   = (u16*)  take(2048ull * 512 * 2);
    u16*   win  = (u16*)  take(2ull * 2048 * 512 * 2);
    u16*   wout = (u16*)  take(2ull * 512 * 1024 * 2);
    u16*   whd  = (u16*)  take(32000ull * 512 * 2);
    float* dtwT = (float*)take(2ull * 32 * 1024 * 4);
    float* hfin = (float*)take((size_t)B_ * NCHUNK * DINNER_ * 16 * 4);
    float* h0b  = (float*)take((size_t)B_ * NCHUNK * DINNER_ * 16 * 4);
    float* sumd = (float*)take((size_t)B_ * NCHUNK * DINNER_ * 4);

    prep<<<19840, 256, 0, stream>>>(in_w, out_w, head_w, dt_w, x, embed, rms_w,
                                    win, wout, whd, dtwT, h, r_bf);

    for (int l = 0; l < 2; ++l) {
        if (l > 0) rmsnorm_bf16<<<512, 256, 0, stream>>>(h, rms_w + l * DIM_, r_bf);
        // xz = r_bf(2048x512) @ win^T(2048x512) : 128^2 tiles, grid 16x16=256, swzq=32
        gemm_bt<0><<<256, 256, 0, stream>>>(r_bf, win + (size_t)l * 2048 * 512, xz, nullptr, 2048, 2048, 512, 16, 32);
        conv_xproj_dt<<<256, 256, 0, stream>>>(xz, conv_w + l * DINNER_ * 4, conv_b + l * DINNER_,
                                               xproj_w + (size_t)l * 64 * 1024,
                                               dtwT + (size_t)l * 32 * 1024, dt_b + l * DINNER_,
                                               xc, dbc, dlt);
        ssm_part1<<<dim3(4, NCHUNK, B_), 256, 0, stream>>>(dlt, xc, dbc, A_log + (size_t)l * DINNER_ * DSTATE_, hfin, sumd);
        ssm_carry<<<128, 256, 0, stream>>>(hfin, sumd, A_log + (size_t)l * DINNER_ * DSTATE_, h0b);
        ssm_part2<<<dim3(4, NCHUNK, B_), 256, 0, stream>>>(dlt, xc, dbc, xz, A_log + (size_t)l * DINNER_ * DSTATE_,
                                                           Dp + l * DINNER_, h0b, ys);
        // h += ys(2048x1024) @ wout^T(512x1024) : grid 32x8=256, swzq=32
        gemm64<1><<<256, 256, 0, stream>>>(ys, wout + (size_t)l * 512 * 1024, h, 2048, 512, 1024, 32, 32);
    }

    layernorm_bf16<<<512, 256, 0, stream>>>(h, ln_g, ln_b, hn);
    // logits = hn(2048x512) @ whd^T(32000x512) + head_b : 256^2 tiles, grid 8x125=1000, swzq=125
    gemm256<<<1000, 512, 0, stream>>>(hn, whd, out, head_b, 2048, VOCAB_, 512, 8, 125);
}